// Round 18
// baseline (971.663 us; speedup 1.0000x reference)
//
#include <hip/hip_runtime.h>
#include <hip/hip_bf16.h>
#include <math.h>

typedef unsigned short u16;
typedef __attribute__((ext_vector_type(8))) short bhalf8;
typedef __attribute__((ext_vector_type(4))) float floatx4;

#define MFMA16(a,b,c) __builtin_amdgcn_mfma_f32_16x16x32_bf16((a),(b),(c),0,0,0)

__device__ __forceinline__ float bf2f(u16 u){ return __uint_as_float(((unsigned)u)<<16); }
__device__ __forceinline__ u16 f2bf(float f){
  unsigned u = __float_as_uint(f);
  u += 0x7fffu + ((u>>16)&1u);
  return (u16)(u>>16);
}
__device__ __forceinline__ float gelu_f(float x){ return 0.5f*x*(1.0f+erff(x*0.70710678118654752f)); }
__device__ __forceinline__ float sigm(float x){ return 1.0f/(1.0f+__expf(-x)); }

__global__ __launch_bounds__(256) void init_counts(int* cnt){
  if (threadIdx.x == 0 && blockIdx.x == 0) *cnt = 0;
}

__global__ __launch_bounds__(256) void cvt_f32_bf16(const float* __restrict__ src,
                                                    u16* __restrict__ dst, int n){
  int i = (blockIdx.x*256 + threadIdx.x)*4;
  if (i >= n) return;
  const float4 v = *(const float4*)(src + i);
  ushort4 o;
  o.x = f2bf(v.x); o.y = f2bf(v.y); o.z = f2bf(v.z); o.w = f2bf(v.w);
  *(ushort4*)(dst + i) = o;
}

// ---------------- hi/lo split convert: v -> (bf16 hi, bf16 lo) ----------------
__global__ __launch_bounds__(256) void cvt_split(const float* __restrict__ src,
                                                 u16* __restrict__ dsth,
                                                 u16* __restrict__ dstl, int n){
  int i = (blockIdx.x*256 + threadIdx.x)*4;
  if (i >= n) return;
  const float4 v = *(const float4*)(src + i);
  float vv[4] = {v.x, v.y, v.z, v.w};
  ushort4 oh, ol;
  u16 h;
  h = f2bf(vv[0]); oh.x = h; ol.x = f2bf(vv[0] - bf2f(h));
  h = f2bf(vv[1]); oh.y = h; ol.y = f2bf(vv[1] - bf2f(h));
  h = f2bf(vv[2]); oh.z = h; ol.z = f2bf(vv[2] - bf2f(h));
  h = f2bf(vv[3]); oh.w = h; ol.w = f2bf(vv[3] - bf2f(h));
  *(ushort4*)(dsth + i) = oh;
  *(ushort4*)(dstl + i) = ol;
}

// ---------------- QKV projection with register-prefetch pipeline ----------------
// SPLIT=1: Q/K blocks (3-term split MFMA, f32 out). SPLIT=0: V blocks (1-term, bf16 out).
template<int SPLIT>
__global__ __launch_bounds__(256) void gemm_qkvT(
    const u16* __restrict__ xh, const u16* __restrict__ xl,
    const u16* __restrict__ Whh, const u16* __restrict__ Whl,
    const float* __restrict__ bq, const float* __restrict__ bk, const float* __restrict__ bv,
    float* __restrict__ Qf, float* __restrict__ Kf, u16* __restrict__ Vb)
{
  __shared__ __align__(16) u16 Ah[128][72];
  __shared__ __align__(16) u16 Bh[128][72];
  __shared__ __align__(16) u16 Al[SPLIT?128:1][72];
  __shared__ __align__(16) u16 Bl[SPLIT?128:1][72];
  const int tid = threadIdx.x;
  const int lane = tid & 63, wid = tid >> 6;
  const int l15 = lane & 15, lg = lane >> 4;
  const int wr = wid >> 1, wc = wid & 1;
  const int m0 = blockIdx.y * 128;
  const int n0 = blockIdx.x * 128 + (SPLIT ? 0 : 1024);
  const int which = n0 >> 9;
  const int nb = n0 & 511;
  const float* bias = (which==0) ? bq : (which==1) ? bk : bv;

  floatx4 acc[4][4] = {};

  bhalf8 RAh[4], RBh[4], RAl[4], RBl[4];
  auto loadT = [&](int k0){
    #pragma unroll
    for (int it = 0; it < 4; ++it){
      int e = (tid + it*256)*8;
      int r = e >> 6, c = e & 63;
      size_t ao = (size_t)(m0+r)*1024 + k0 + c;
      size_t bo = (size_t)(n0+r)*1024 + k0 + c;
      RAh[it] = *(const bhalf8*)(xh + ao);
      RBh[it] = *(const bhalf8*)(Whh + bo);
      if (SPLIT){
        RAl[it] = *(const bhalf8*)(xl + ao);
        RBl[it] = *(const bhalf8*)(Whl + bo);
      }
    }
  };
  auto writeT = [&](){
    #pragma unroll
    for (int it = 0; it < 4; ++it){
      int e = (tid + it*256)*8;
      int r = e >> 6, c = e & 63;
      *(bhalf8*)&Ah[r][c] = RAh[it];
      *(bhalf8*)&Bh[r][c] = RBh[it];
      if (SPLIT){
        *(bhalf8*)&Al[r][c] = RAl[it];
        *(bhalf8*)&Bl[r][c] = RBl[it];
      }
    }
  };

  loadT(0);
  writeT();
  __syncthreads();
  for (int k0 = 0; k0 < 1024; k0 += 64){
    if (k0 < 960) loadT(k0 + 64);      // prefetch next tile while MFMA runs
    #pragma unroll
    for (int kk = 0; kk < 2; ++kk){
      bhalf8 ah[4], bh8[4];
      #pragma unroll
      for (int xx=0; xx<4; xx++){
        ah[xx]  = *(const bhalf8*)&Ah[wr*64 + xx*16 + l15][kk*32 + lg*8];
        bh8[xx] = *(const bhalf8*)&Bh[wc*64 + xx*16 + l15][kk*32 + lg*8];
      }
      if (SPLIT){
        bhalf8 al[4], bl8[4];
        #pragma unroll
        for (int xx=0; xx<4; xx++){
          al[xx]  = *(const bhalf8*)&Al[wr*64 + xx*16 + l15][kk*32 + lg*8];
          bl8[xx] = *(const bhalf8*)&Bl[wc*64 + xx*16 + l15][kk*32 + lg*8];
        }
        #pragma unroll
        for (int mi=0;mi<4;mi++)
          #pragma unroll
          for (int ni=0;ni<4;ni++){
            acc[mi][ni] = MFMA16(ah[mi], bh8[ni], acc[mi][ni]);
            acc[mi][ni] = MFMA16(ah[mi], bl8[ni], acc[mi][ni]);
            acc[mi][ni] = MFMA16(al[mi], bh8[ni], acc[mi][ni]);
          }
      } else {
        #pragma unroll
        for (int mi=0;mi<4;mi++)
          #pragma unroll
          for (int ni=0;ni<4;ni++)
            acc[mi][ni] = MFMA16(ah[mi], bh8[ni], acc[mi][ni]);
      }
    }
    __syncthreads();
    if (k0 < 960){
      writeT();
      __syncthreads();
    }
  }

  #pragma unroll
  for (int mi=0;mi<4;mi++)
    #pragma unroll
    for (int ni=0;ni<4;ni++){
      int cc = nb + wc*64 + ni*16 + l15;
      float bias_v = bias[cc];
      #pragma unroll
      for (int i=0;i<4;i++){
        int row = m0 + wr*64 + mi*16 + lg*4 + i;
        float v = acc[mi][ni][i] + bias_v;
        size_t off = (size_t)row*512 + cc;
        if (which==0){ Qf[off] = v; }
        else if (which==1){ Kf[off] = v; }
        else { Vb[off] = f2bf(v); }
      }
    }
}

// ---------------- token-temp GEMM, both paths, register-prefetch pipeline ---------------
__global__ __launch_bounds__(256) void gemm_tanh2(
    const float* __restrict__ Af, const u16* __restrict__ Ab,
    const u16* __restrict__ Bq, const u16* __restrict__ Bv,
    u16* __restrict__ oq, u16* __restrict__ ov)
{
  __shared__ __align__(16) u16 As[128][72];
  __shared__ __align__(16) u16 Bs[128][72];
  const int tid = threadIdx.x;
  const int lane = tid & 63, wid = tid >> 6;
  const int l15 = lane & 15, lg = lane >> 4;
  const int wr = wid >> 1, wc = wid & 1;
  const int m0 = blockIdx.y * 128, n0 = blockIdx.x * 128;
  const int zp = blockIdx.z;
  const u16* B = zp ? Bv : Bq;
  u16* o0 = zp ? ov : oq;

  floatx4 acc[4][4] = {};

  float4 RAf[8]; bhalf8 RAb[4]; bhalf8 RB[4];
  auto loadT = [&](int k0){
    #pragma unroll
    for (int it=0; it<4; ++it){
      int e = (tid + it*256)*8;
      int r = e >> 6, c = e & 63;
      if (zp == 0){
        const float* src = Af + (size_t)(m0+r)*512 + k0 + c;
        RAf[it*2]   = *(const float4*)src;
        RAf[it*2+1] = *(const float4*)(src+4);
      } else {
        RAb[it] = *(const bhalf8*)(Ab + (size_t)(m0+r)*512 + k0 + c);
      }
      RB[it] = *(const bhalf8*)(B + (size_t)(n0+r)*512 + k0 + c);
    }
  };
  auto writeT = [&](){
    #pragma unroll
    for (int it=0; it<4; ++it){
      int e = (tid + it*256)*8;
      int r = e >> 6, c = e & 63;
      bhalf8 g;
      if (zp == 0){
        float vv[8] = {RAf[it*2].x,RAf[it*2].y,RAf[it*2].z,RAf[it*2].w,
                       RAf[it*2+1].x,RAf[it*2+1].y,RAf[it*2+1].z,RAf[it*2+1].w};
        #pragma unroll
        for (int j=0;j<8;j++) g[j] = (short)f2bf(gelu_f(vv[j]));
      } else {
        #pragma unroll
        for (int j=0;j<8;j++) g[j] = (short)f2bf(gelu_f(bf2f((u16)RAb[it][j])));
      }
      *(bhalf8*)&As[r][c] = g;
      *(bhalf8*)&Bs[r][c] = RB[it];
    }
  };

  loadT(0);
  writeT();
  __syncthreads();
  for (int k0 = 0; k0 < 512; k0 += 64){
    if (k0 < 448) loadT(k0 + 64);
    #pragma unroll
    for (int kk = 0; kk < 2; ++kk){
      bhalf8 af[4], bfr[4];
      #pragma unroll
      for (int xx=0;xx<4;xx++) af[xx]  = *(const bhalf8*)&As[wr*64 + xx*16 + l15][kk*32 + lg*8];
      #pragma unroll
      for (int xx=0;xx<4;xx++) bfr[xx] = *(const bhalf8*)&Bs[wc*64 + xx*16 + l15][kk*32 + lg*8];
      #pragma unroll
      for (int mi=0;mi<4;mi++)
        #pragma unroll
        for (int ni=0;ni<4;ni++)
          acc[mi][ni] = MFMA16(af[mi], bfr[ni], acc[mi][ni]);
    }
    __syncthreads();
    if (k0 < 448){
      writeT();
      __syncthreads();
    }
  }

  #pragma unroll
  for (int mi=0;mi<4;mi++)
    #pragma unroll
    for (int ni=0;ni<4;ni++){
      int coln = n0 + wc*64 + ni*16 + l15;
      #pragma unroll
      for (int i=0;i<4;i++){
        int row = m0 + wr*64 + mi*16 + lg*4 + i;
        o0[(size_t)row*512 + coln] = f2bf(tanhf(acc[mi][ni][i]));
      }
    }
}

// ---------------- argmax screen: 3-term split MFMA, XCD-chunked + reg prefetch ----------
__global__ __launch_bounds__(256) void gemm_argmax(
    const float* __restrict__ Qf, const float* __restrict__ Kf,
    float4* __restrict__ part)
{
  __shared__ __align__(16) u16 Ah[128][40];
  __shared__ __align__(16) u16 Al[128][40];
  __shared__ __align__(16) u16 Bh[128][40];
  __shared__ __align__(16) u16 Bl[128][40];
  const int tid = threadIdx.x;
  const int lane = tid & 63, wid = tid >> 6;
  const int l15 = lane & 15, lg = lane >> 4;
  const int wr = wid >> 1, wc = wid & 1;
  const int lin = blockIdx.x + 16*blockIdx.y + 256*blockIdx.z;
  const int swz = (lin & 7)*256 + (lin >> 3);
  const int zb  = swz >> 8;
  const int rem = swz & 255;
  const int m0 = (rem >> 4) * 128;
  const int n0 = (rem & 15) * 128;
  const size_t bo = (size_t)zb * 2048 * 512;

  floatx4 acc[4][4] = {};

  float4 RQ[4], RK[4];
  auto loadT = [&](int k0){
    #pragma unroll
    for (int it = 0; it < 2; ++it){
      int e = (tid + it*256)*8;
      int r = e >> 5, c = e & 31;
      const float* sq = Qf + bo + (size_t)(m0+r)*512 + k0 + c;
      const float* sk = Kf + bo + (size_t)(n0+r)*512 + k0 + c;
      RQ[it*2+0] = *(const float4*)sq;
      RQ[it*2+1] = *(const float4*)(sq+4);
      RK[it*2+0] = *(const float4*)sk;
      RK[it*2+1] = *(const float4*)(sk+4);
    }
  };
  auto writeT = [&](){
    #pragma unroll
    for (int it = 0; it < 2; ++it){
      int e = (tid + it*256)*8;
      int r = e >> 5, c = e & 31;
      {
        float vv[8] = {RQ[it*2].x,RQ[it*2].y,RQ[it*2].z,RQ[it*2].w,
                       RQ[it*2+1].x,RQ[it*2+1].y,RQ[it*2+1].z,RQ[it*2+1].w};
        bhalf8 h8, l8;
        #pragma unroll
        for (int j=0;j<8;j++){
          u16 h = f2bf(vv[j]); h8[j] = (short)h;
          l8[j] = (short)f2bf(vv[j] - bf2f(h));
        }
        *(bhalf8*)&Ah[r][c] = h8;
        *(bhalf8*)&Al[r][c] = l8;
      }
      {
        float vv[8] = {RK[it*2].x,RK[it*2].y,RK[it*2].z,RK[it*2].w,
                       RK[it*2+1].x,RK[it*2+1].y,RK[it*2+1].z,RK[it*2+1].w};
        bhalf8 h8, l8;
        #pragma unroll
        for (int j=0;j<8;j++){
          u16 h = f2bf(vv[j]); h8[j] = (short)h;
          l8[j] = (short)f2bf(vv[j] - bf2f(h));
        }
        *(bhalf8*)&Bh[r][c] = h8;
        *(bhalf8*)&Bl[r][c] = l8;
      }
    }
  };

  loadT(0);
  writeT();
  __syncthreads();
  for (int k0 = 0; k0 < 512; k0 += 32){
    if (k0 < 480) loadT(k0 + 32);
    {
      bhalf8 ah[4], al[4], bh[4], bl[4];
      #pragma unroll
      for (int xx=0;xx<4;xx++){
        ah[xx] = *(const bhalf8*)&Ah[wr*64 + xx*16 + l15][lg*8];
        al[xx] = *(const bhalf8*)&Al[wr*64 + xx*16 + l15][lg*8];
        bh[xx] = *(const bhalf8*)&Bh[wc*64 + xx*16 + l15][lg*8];
        bl[xx] = *(const bhalf8*)&Bl[wc*64 + xx*16 + l15][lg*8];
      }
      #pragma unroll
      for (int mi=0;mi<4;mi++)
        #pragma unroll
        for (int ni=0;ni<4;ni++){
          acc[mi][ni] = MFMA16(ah[mi], bh[ni], acc[mi][ni]);
          acc[mi][ni] = MFMA16(ah[mi], bl[ni], acc[mi][ni]);
          acc[mi][ni] = MFMA16(al[mi], bh[ni], acc[mi][ni]);
        }
    }
    __syncthreads();
    if (k0 < 480){
      writeT();
      __syncthreads();
    }
  }

  #pragma unroll
  for (int mi=0;mi<4;mi++)
    #pragma unroll
    for (int i=0;i<4;i++){
      float v1 = -INFINITY, v2 = -INFINITY; int i1 = 0x7fffffff;
      #pragma unroll
      for (int ni=0;ni<4;ni++){
        float v = acc[mi][ni][i];
        int col = n0 + wc*64 + ni*16 + l15;
        if (v > v1 || (v == v1 && col < i1)){ v2 = v1; v1 = v; i1 = col; }
        else v2 = fmaxf(v2, v);
      }
      #pragma unroll
      for (int ms=1; ms<16; ms<<=1){
        float w1 = __shfl_xor(v1, ms, 64);
        int   j1 = __shfl_xor(i1, ms, 64);
        float w2 = __shfl_xor(v2, ms, 64);
        if (w1 > v1 || (w1 == v1 && j1 < i1)){ v2 = fmaxf(v1, w2); v1 = w1; i1 = j1; }
        else { v2 = fmaxf(v2, w1); }
      }
      if (l15 == 0){
        int row = m0 + wr*64 + mi*16 + lg*4 + i;
        size_t gm = (size_t)zb*2048 + row;
        part[gm*32 + ((n0>>7)<<1) + wc] = make_float4(v1, __int_as_float(i1), v2, 0.0f);
      }
    }
}

// ---------------- reduce top2 over 32 col-stripes; flag narrow-gap rows -----------------
__global__ __launch_bounds__(256) void argmax_reduce(const float4* __restrict__ part,
                                                     int* __restrict__ ids,
                                                     int* __restrict__ list1,
                                                     int* __restrict__ cnt){
  int r = blockIdx.x*256 + threadIdx.x;
  if (r >= 16384) return;
  float v1 = -INFINITY, v2 = -INFINITY; int i1 = 0x7fffffff;
  #pragma unroll
  for (int t=0;t<32;t++){
    float4 p = part[(size_t)r*32 + t];
    float w1 = p.x, w2 = p.z; int j1 = __float_as_int(p.y);
    if (w1 > v1 || (w1 == v1 && j1 < i1)){ v2 = fmaxf(v1, w2); v1 = w1; i1 = j1; }
    else { v2 = fmaxf(v2, w1); }
  }
  ids[r] = i1;
  if (v1 - v2 < 0.02f){
    int k = atomicAdd(cnt, 1);
    if (k < 16384) list1[k] = r;
  }
}

// ---------------- exact fix: verified f64-on-f32 argmax for flagged rows -----------------
__global__ __launch_bounds__(256) void argmax_fix(
    const float* __restrict__ Qf, const float* __restrict__ Kf,
    const int* __restrict__ list1, const int* __restrict__ cnt,
    int* __restrict__ ids)
{
  __shared__ float q[512];
  __shared__ double rbest[256];
  __shared__ int ridx[256];
  const int tid = threadIdx.x;
  const int n = *cnt;
  for (int j = blockIdx.x; j < n; j += gridDim.x){
    const int r = list1[j];
    const int b = r >> 11;
    __syncthreads();
    for (int d = tid; d < 512; d += 256) q[d] = Qf[(size_t)r*512 + d];
    __syncthreads();
    double best = -1e300; int bi = 0x7fffffff;
    for (int c = 0; c < 8; ++c){
      int key = tid + c*256;
      const float* kr = Kf + ((size_t)b*2048 + key)*512;
      double acc = 0.0;
      for (int e = 0; e < 512; ++e) acc += (double)q[e]*(double)kr[e];
      if (acc > best || (acc == best && key < bi)){ best = acc; bi = key; }
    }
    rbest[tid] = best; ridx[tid] = bi;
    __syncthreads();
    for (int st=128; st>0; st>>=1){
      if (tid < st){
        double ov = rbest[tid+st]; int oi = ridx[tid+st];
        if (ov > rbest[tid] || (ov == rbest[tid] && oi < ridx[tid])){ rbest[tid]=ov; ridx[tid]=oi; }
      }
      __syncthreads();
    }
    if (tid == 0) ids[r] = ridx[0];
    __syncthreads();
  }
}

// ---------------- K column sums: two-phase deterministic ----------------
__global__ __launch_bounds__(256) void ksum_part(const float* __restrict__ Kf,
                                                 float* __restrict__ kpart){
  const int b = blockIdx.x, chunk = blockIdx.y;
  const int tid = threadIdx.x;
  const float* base = Kf + (size_t)b*2048*512 + (size_t)chunk*128*512;
  #pragma unroll
  for (int h = 0; h < 2; ++h){
    int col = tid + h*256;
    double s = 0.0;
    for (int r = 0; r < 128; ++r) s += (double)base[(size_t)r*512 + col];
    kpart[((size_t)b*16 + chunk)*512 + col] = (float)s;
  }
}
__global__ __launch_bounds__(256) void ksum_final(const float* __restrict__ kpart,
                                                  float* __restrict__ Ksum){
  const int b = blockIdx.x >> 1;
  const int col = (blockIdx.x & 1)*256 + threadIdx.x;
  double s = 0.0;
  #pragma unroll
  for (int c = 0; c < 16; ++c) s += (double)kpart[((size_t)b*16 + c)*512 + col];
  Ksum[b*512 + col] = (float)s;
}

// ---------------- gating: emits gQ hi/lo bf16 (pre-scaled) + f32 gated-V ----------------
__global__ __launch_bounds__(256) void gating_kernel(
    const float* Qf, const float* __restrict__ Kf,
    const u16* __restrict__ V,
    const u16* __restrict__ ttq, const u16* __restrict__ ttv,
    const int* __restrict__ ids, const float* __restrict__ Ksum,
    const float* __restrict__ alphaq, const float* __restrict__ alphav,
    u16* __restrict__ gQh, u16* __restrict__ gQl, float* gVf)
{
  const int m = blockIdx.x;
  const int b = m >> 11, s = m & 2047;
  const int mid = ids[m];
  const float lp = __logf((float)(s+1));
  const float aq = alphaq[s];
  const float pv = 1.0f + sigm(alphav[s])*lp;
  const float qscale = 0.044194173824159220f;
  const size_t ro = (size_t)m*512;
  const size_t ko = ((size_t)b*2048 + mid)*512;
  const int k0 = threadIdx.x*2;

  float2 ks2 = *(const float2*)(Ksum + b*512 + k0);
  float2 q2  = *(const float2*)(Qf + ro + k0);
  float2 km2 = *(const float2*)(Kf + ko + k0);
  ushort2 v2 = *(const ushort2*)(V + ro + k0);
  ushort2 tq2 = *(const ushort2*)(ttq + ro + k0);
  ushort2 tv2 = *(const ushort2*)(ttv + ro + k0);
  ushort2 oqh, oql;
  float2 ov;
  {
    float knob = fabsf(q2.x*(ks2.x - 2048.0f*km2.x));
    float ptq = 1.0f + sigm(aq - knob)*lp;
    float oq = (ptq + bf2f(tq2.x))*q2.x*qscale;
    u16 h = f2bf(oq); oqh.x = h; oql.x = f2bf(oq - bf2f(h));
    ov.x = (pv + bf2f(tv2.x))*bf2f(v2.x);
  }
  {
    float knob = fabsf(q2.y*(ks2.y - 2048.0f*km2.y));
    float ptq = 1.0f + sigm(aq - knob)*lp;
    float oq = (ptq + bf2f(tq2.y))*q2.y*qscale;
    u16 h = f2bf(oq); oqh.y = h; oql.y = f2bf(oq - bf2f(h));
    ov.y = (pv + bf2f(tv2.y))*bf2f(v2.y);
  }
  *(ushort2*)(gQh + ro + k0) = oqh;
  *(ushort2*)(gQl + ro + k0) = oql;
  *(float2*)(gVf + ro + k0) = ov;
}

// ---------------- transpose gV: f32 [b][s][v] -> bf16 [b][v][s] ----------------
__global__ __launch_bounds__(256) void transpose_v(const float* __restrict__ src,
                                                   u16* __restrict__ dst){
  __shared__ __align__(16) u16 t[64][72];
  const int b = blockIdx.z;
  const int s0 = blockIdx.x*64, v0 = blockIdx.y*64;
  const float* S = src + (size_t)b*2048*512;
  u16* D = dst + (size_t)b*512*2048;
  const int tid = threadIdx.x;
  #pragma unroll
  for (int it=0; it<2; ++it){
    int e = (tid + it*256)*8;
    int r = e>>6, c = e&63;
    const float* p = S + (size_t)(s0+r)*512 + v0 + c;
    float4 u0 = *(const float4*)p;
    float4 u1 = *(const float4*)(p+4);
    float vv[8] = {u0.x,u0.y,u0.z,u0.w,u1.x,u1.y,u1.z,u1.w};
    bhalf8 o;
    #pragma unroll
    for (int j=0;j<8;j++) o[j] = (short)f2bf(vv[j]);
    *(bhalf8*)&t[r][c] = o;
  }
  __syncthreads();
  #pragma unroll
  for (int it=0; it<2; ++it){
    int e = (tid + it*256)*8;
    int r = e>>6, c = e&63;
    bhalf8 o;
    #pragma unroll
    for (int j=0;j<8;j++) o[j] = (short)t[c+j][r];
    *(bhalf8*)(D + (size_t)(v0+r)*2048 + s0 + c) = o;
  }
}

// ---------------- flash3: MFMA causal attention (verified, R16 mapping) ----------------
#define QSW(r,g) ((((g) ^ ((r)&7))) << 3)
__global__ __launch_bounds__(256, 2) void flash3(
    const u16* __restrict__ gQh, const u16* __restrict__ gQl,
    const float* __restrict__ Kf, const u16* __restrict__ gVT,
    float* __restrict__ Out)
{
  const int bx = blockIdx.x;
  const int by = blockIdx.y;
  const int b  = by;
  const int hh = (bx & 1) ? (63 - (bx >> 1)) : (bx >> 1);
  const int qt = (by < 4) ? hh : (63 - hh);
  const int q0 = qt * 32;
  const int tid = threadIdx.x, lane = tid & 63, wid = tid >> 6;
  const int l15 = lane & 15, lg = lane >> 4;
  const int wr = wid >> 1, wc = wid & 1;

  __shared__ __align__(16) char smem[74112];
  u16*   qhs = (u16*)smem;
  u16*   khs = (u16*)(smem + 32768);
  u16*   kls = (u16*)(smem + 40960);
  u16*   vss = (u16*)(smem + 49152);
  float* sf  = (float*)(smem + 49152);
  u16*   phs = (u16*)(smem + 65536);
  u16*   pls = (u16*)(smem + 69632);
  float* mstat = (float*)(smem + 73728);
  float* lstat = mstat + 32;
  float* osc   = mstat + 64;

  const u16* Qhb = gQh + ((size_t)b*2048 + q0)*512;
  const float* Kb = Kf + (size_t)b*2048*512;
  const u16* Vtb = gVT + (size_t)b*512*2048;

  #pragma unroll
  for (int it=0; it<8; ++it){
    int e = (tid + it*256)*8;
    int r = e >> 9, c = e & 511;
    bhalf8 hv = *(const bhalf8*)(Qhb + (size_t)r*512 + c);
    *(bhalf8*)&qhs[r*512 + QSW(r, c>>3)] = hv;
  }
  bhalf8 qlr[16];
  {
    const u16* Qlb = gQl + ((size_t)b*2048 + q0 + wr*16 + l15)*512;
    #pragma unroll
    for (int c=0;c<8;c++)
      #pragma unroll
      for (int kk=0;kk<2;kk++)
        qlr[c*2+kk] = *(const bhalf8*)(Qlb + c*64 + kk*32 + lg*8);
  }
  if (tid < 32){ mstat[tid] = -INFINITY; lstat[tid] = 0.0f; }

  floatx4 O[4][2][2] = {};
  __syncthreads();

  auto loadK = [&](int kt, int c, float4* dst){
    #pragma unroll
    for (int it=0; it<2; ++it){
      int e = (tid + it*256)*8;
      int r = e>>6, cc = e&63;
      const float* s = Kb + (size_t)(kt*64+r)*512 + c*64 + cc;
      dst[it*2+0] = *(const float4*)s;
      dst[it*2+1] = *(const float4*)(s+4);
    }
  };
  auto writeK = [&](const float4* src){
    #pragma unroll
    for (int it=0; it<2; ++it){
      int e = (tid + it*256)*8;
      int r = e>>6, cc = e&63;
      float vv[8] = {src[it*2].x,src[it*2].y,src[it*2].z,src[it*2].w,
                     src[it*2+1].x,src[it*2+1].y,src[it*2+1].z,src[it*2+1].w};
      bhalf8 h8, l8;
      #pragma unroll
      for (int jx=0;jx<8;jx++){
        u16 h = f2bf(vv[jx]); h8[jx] = (short)h;
        l8[jx] = (short)f2bf(vv[jx] - bf2f(h));
      }
      int o = r*64 + QSW(r, cc>>3);
      *(bhalf8*)&khs[o] = h8;
      *(bhalf8*)&kls[o] = l8;
    }
  };
  auto loadV = [&](int kt, int vc, bhalf8* dst){
    #pragma unroll
    for (int it=0; it<4; ++it){
      int e = (tid + it*256)*8;
      int r = e>>6, cc = e&63;
      dst[it] = *(const bhalf8*)(Vtb + (size_t)(vc*128+r)*2048 + kt*64 + cc);
    }
  };
  auto writeV = [&](const bhalf8* src){
    #pragma unroll
    for (int it=0; it<4; ++it){
      int e = (tid + it*256)*8;
      int r = e>>6, cc = e&63;
      *(bhalf8*)&vss[r*64 + QSW(r, cc>>3)] = src[it];
    }
  };

  const int qrow = wr*16 + l15;
  const int srow = tid >> 3, seg = tid & 7;

  const int nkt = (q0 + 31)/64 + 1;
  for (int kt = 0; kt < nkt; ++kt){
    floatx4 sacc[2] = {};
    float4 ka[4];
    loadK(kt, 0, ka);
    writeK(ka);
    __syncthreads();
    for (int c = 0; c < 8; ++c){
      float4 kb[4];
      if (c < 7) loadK(kt, c+1, kb);
      #pragma unroll
      for (int kk=0; kk<2; ++kk){
        bhalf8 ah = *(const bhalf8*)&qhs[qrow*512 + QSW(qrow, c*8 + kk*4 + lg)];
        bhalf8 al = qlr[c*2+kk];
        #pragma unroll
        for (int ni=0; ni<2; ++ni){
          int krow = wc*32 + ni*16 + l15;
          int o = krow*64 + QSW(krow, kk*4 + lg);
          bhalf8 bh = *(const bhalf8*)&khs[o];
          bhalf8 bl = *(const bhalf8*)&kls[o];
          sacc[ni] = MFMA16(ah, bh, sacc[ni]);
          sacc[ni] = MFMA16(ah, bl, sacc[ni]);
          sacc[ni] = MFMA16(al, bh, sacc[ni]);
        }
      }
      __syncthreads();
      if (c < 7){
        writeK(kb);
        __syncthreads();
      }
    }
    #pragma unroll
    for (int ni=0; ni<2; ++ni)
      #pragma unroll
      for (int i=0;i<4;i++){
        int row = wr*16 + lg*4 + i;
        int col = wc*32 + ni*16 + l15;
        sf[row*66 + col] = (kt*64 + col <= q0 + row) ? sacc[ni][i] : -INFINITY;
      }
    __syncthreads();
    bhalf8 va[4];
    loadV(kt, 0, va);
    {
      float pv8[8];
      float tmax = -INFINITY;
      #pragma unroll
      for (int jx=0;jx<8;jx++){ pv8[jx] = sf[srow*66 + seg*8 + jx]; tmax = fmaxf(tmax, pv8[jx]); }
      tmax = fmaxf(tmax, __shfl_xor(tmax,1,64));
      tmax = fmaxf(tmax, __shfl_xor(tmax,2,64));
      tmax = fmaxf(tmax, __shfl_xor(tmax,4,64));
      float mo = mstat[srow];
      float mn = fmaxf(mo, tmax);
      float ss = 0.0f;
      bhalf8 h8, l8;
      #pragma unroll
      for (int jx=0;jx<8;jx++){
        float p = __expf(pv8[jx] - mn);
        ss += p;
        u16 hh2 = f2bf(p);
        h8[jx] = (short)hh2;
        l8[jx] = (short)f2bf(p - bf2f(hh2));
      }
      ss += __shfl_xor(ss,1,64);
      ss += __shfl_xor(ss,2,64);
      ss += __shfl_xor(ss,4,64);
      int o = srow*64 + QSW(srow, seg);
      *(bhalf8*)&phs[o] = h8;
      *(bhalf8*)&pls[o] = l8;
      if (seg == 0){
        float sc = __expf(mo - mn);
        lstat[srow] = lstat[srow]*sc + ss;
        mstat[srow] = mn;
        osc[srow] = sc;
      }
    }
    __syncthreads();
    #pragma unroll
    for (int mi=0;mi<2;mi++)
      #pragma unroll
      for (int i=0;i<4;i++){
        float s = osc[mi*16 + lg*4 + i];
        #pragma unroll
        for (int vc=0; vc<4; ++vc)
          #pragma unroll
          for (int ni=0;ni<2;ni++)
            O[vc][mi][ni][i] *= s;
      }
    writeV(va);
    __syncthreads();
    for (int vc = 0; vc < 4; ++vc){
      bhalf8 vb_[4];
      if (vc < 3) loadV(kt, vc+1, vb_);
      #pragma unroll
      for (int kk=0; kk<2; ++kk){
        int gp = kk*4 + lg;
        bhalf8 pah0 = *(const bhalf8*)&phs[l15*64 + QSW(l15, gp)];
        bhalf8 pal0 = *(const bhalf8*)&pls[l15*64 + QSW(l15, gp)];
        bhalf8 pah1 = *(const bhalf8*)&phs[(16+l15)*64 + QSW(16+l15, gp)];
        bhalf8 pal1 = *(const bhalf8*)&pls[(16+l15)*64 + QSW(16+l15, gp)];
        #pragma unroll
        for (int ni=0; ni<2; ++ni){
          int vrow = wid*32 + ni*16 + l15;
          bhalf8 bv_ = *(const bhalf8*)&vss[vrow*64 + QSW(vrow, gp)];
          O[vc][0][ni] = MFMA16(pah0, bv_, O[vc][0][ni]);
          O[vc][0][ni] = MFMA16(pal0, bv_, O[vc][0][ni]);
          O[vc][1][ni] = MFMA16(pah1, bv_, O[vc][1][ni]);
          O[vc][1][ni] = MFMA16(pal1, bv_, O[vc][1][ni]);
        }
      }
      __syncthreads();
      if (vc < 3){
        writeV(vb_);
        __syncthreads();
      }
    }
  }

  #pragma unroll
  for (int vc=0; vc<4; ++vc)
    #pragma unroll
    for (int mi=0;mi<2;mi++)
      #pragma unroll
      for (int i=0;i<4;i++){
        int r = mi*16 + lg*4 + i;
        float inv = 1.0f / lstat[r];
        #pragma unroll
        for (int ni=0;ni<2;ni++){
          int v = vc*128 + wid*32 + ni*16 + l15;
          Out[((size_t)b*2048 + q0 + r)*512 + v] = O[vc][mi][ni][i] * inv;
        }
      }
}

extern "C" void kernel_launch(void* const* d_in, const int* in_sizes, int n_in,
                              void* d_out, int out_size, void* d_ws, size_t ws_size,
                              hipStream_t stream)
{
  const float* x   = (const float*)d_in[0];
  const float* Wq  = (const float*)d_in[1];
  const float* bq  = (const float*)d_in[2];
  const float* Wk  = (const float*)d_in[3];
  const float* bk  = (const float*)d_in[4];
  const float* Wv  = (const float*)d_in[5];
  const float* bv  = (const float*)d_in[6];
  const float* alphaq = (const float*)d_in[7];
  const float* alphav = (const float*)d_in[8];
  const float* tokq = (const float*)d_in[9];
  const float* tokv = (const float*)d_in[10];
  float* out = (float*)d_out;
  char* ws = (char*)d_ws;

  float* Qf  = (float*)(ws + 0);                 // 32 MB (gVf overlays after gating)
  float* gVf = Qf;
  float* Kf  = (float*)(ws + 33554432);          // 32 MB
  u16* Vb    = (u16*)(ws + 67108864);            // 16 MB
  u16* ttq   = (u16*)(ws + 83886080);            // 16 MB (xl first half; gVT after gating)
  u16* gVT   = ttq;
  u16* ttv   = (u16*)(ws + 100663296);           // 16 MB (xl second half)
  u16* xl    = (u16*)(ws + 83886080);            // 32 MB, dead after gemm_qkv
  u16* gQh   = (u16*)(ws + 117440512);           // 16 MB (xh first half)
  u16* gQl   = (u16*)(ws + 134217728);           // 16 MB (xh second half)
  u16* xh    = (u16*)(ws + 117440512);           // 32 MB, dead after gemm_qkv
  u16* tq_b  = (u16*)(ws + 150994944);           // 0.5 MB
  u16* tv_b  = (u16*)(ws + 151519232);           // 0.5 MB
  int* ids   = (int*)(ws + 152043520);           // 64 KB
  float* ksum = (float*)(ws + 152109056);        // 16 KB
  float4* part = (float4*)(ws + 152125440);      // 8 MB [16384][32] (Whh/Whl first)
  u16* Whh   = (u16*)(ws + 152125440);           // 3 MB, dead after gemm_qkv
  u16* Whl   = (u16*)(ws + 155271168);           // 3 MB
  int* list1 = (int*)(ws + 160514048);           // 64 KB
  int* cnt   = (int*)(ws + 160579584);           // 4 B
  float* kpart = (float*)(ws + 160579840);       // 256 KB
  (void)ws_size; (void)in_sizes; (void)n_in; (void)out_size;

  init_counts<<<1,256,0,stream>>>(cnt);
  cvt_f32_bf16<<<256,256,0,stream>>>(tokq, tq_b, 262144);
  cvt_f32_bf16<<<256,256,0,stream>>>(tokv, tv_b, 262144);

  // pre-split x and W into hi/lo bf16
  cvt_split<<<16384,256,0,stream>>>(x,  xh, xl, 16777216);
  cvt_split<<<512,256,0,stream>>>(Wq, Whh,            Whl,            524288);
  cvt_split<<<512,256,0,stream>>>(Wk, Whh + 524288,   Whl + 524288,   524288);
  cvt_split<<<512,256,0,stream>>>(Wv, Whh + 1048576,  Whl + 1048576,  524288);

  // QKV projection with register-prefetch pipeline (split QK blocks, then V blocks)
  gemm_qkvT<1><<<dim3(8,128),256,0,stream>>>(xh, xl, Whh, Whl, bq, bk, bv, Qf, Kf, Vb);
  gemm_qkvT<0><<<dim3(4,128),256,0,stream>>>(xh, xl, Whh, Whl, bq, bk, bv, Qf, Kf, Vb);

  // token temps: both paths in ONE launch, register-prefetch pipeline
  gemm_tanh2<<<dim3(4,128,2),256,0,stream>>>(Qf, Vb, tq_b, tv_b, ttq, ttv);

  // argmax: 3-term MFMA screen (XCD-chunked, prefetch) -> flag -> exact f64 fix
  gemm_argmax<<<dim3(16,16,8),256,0,stream>>>(Qf, Kf, part);   // overwrites Whh/Whl (dead)
  argmax_reduce<<<64,256,0,stream>>>(part, ids, list1, cnt);
  argmax_fix<<<64,256,0,stream>>>(Qf, Kf, list1, cnt, ids);

  // K column sums (two-phase deterministic)
  ksum_part<<<dim3(8,16),256,0,stream>>>(Kf, kpart);
  ksum_final<<<16,256,0,stream>>>(kpart, ksum);

  // gating: gQ hi/lo bf16 + f32 gated-V (overwrites xh region — dead; gVf over Qf)
  gating_kernel<<<16384,256,0,stream>>>(Qf, Kf, Vb, ttq, ttv, ids, ksum,
                                        alphaq, alphav, gQh, gQl, gVf);

  // transpose gV -> bf16 [b][v][s] (over ttq)
  transpose_v<<<dim3(32,8,8),256,0,stream>>>(gVf, gVT);

  // MFMA causal attention (verified flash3, R16 pairing-robust mapping)
  flash3<<<dim3(64,8),256,0,stream>>>(gQh, gQl, Kf, gVT, out);
}

// Round 19
// 944.396 us; speedup vs baseline: 1.0289x; 1.0289x over previous
//
#include <hip/hip_runtime.h>
#include <hip/hip_bf16.h>
#include <math.h>

typedef unsigned short u16;
typedef __attribute__((ext_vector_type(8))) short bhalf8;
typedef __attribute__((ext_vector_type(4))) float floatx4;

#define MFMA16(a,b,c) __builtin_amdgcn_mfma_f32_16x16x32_bf16((a),(b),(c),0,0,0)

__device__ __forceinline__ float bf2f(u16 u){ return __uint_as_float(((unsigned)u)<<16); }
__device__ __forceinline__ u16 f2bf(float f){
  unsigned u = __float_as_uint(f);
  u += 0x7fffu + ((u>>16)&1u);
  return (u16)(u>>16);
}
__device__ __forceinline__ float gelu_f(float x){ return 0.5f*x*(1.0f+erff(x*0.70710678118654752f)); }
__device__ __forceinline__ float sigm(float x){ return 1.0f/(1.0f+__expf(-x)); }

__global__ __launch_bounds__(256) void init_counts(int* cnt){
  if (threadIdx.x == 0 && blockIdx.x == 0) *cnt = 0;
}

__global__ __launch_bounds__(256) void cvt_f32_bf16(const float* __restrict__ src,
                                                    u16* __restrict__ dst, int n){
  int i = (blockIdx.x*256 + threadIdx.x)*4;
  if (i >= n) return;
  const float4 v = *(const float4*)(src + i);
  ushort4 o;
  o.x = f2bf(v.x); o.y = f2bf(v.y); o.z = f2bf(v.z); o.w = f2bf(v.w);
  *(ushort4*)(dst + i) = o;
}

// ---------------- hi/lo split convert: v -> (bf16 hi, bf16 lo) ----------------
__global__ __launch_bounds__(256) void cvt_split(const float* __restrict__ src,
                                                 u16* __restrict__ dsth,
                                                 u16* __restrict__ dstl, int n){
  int i = (blockIdx.x*256 + threadIdx.x)*4;
  if (i >= n) return;
  const float4 v = *(const float4*)(src + i);
  float vv[4] = {v.x, v.y, v.z, v.w};
  ushort4 oh, ol;
  u16 h;
  h = f2bf(vv[0]); oh.x = h; ol.x = f2bf(vv[0] - bf2f(h));
  h = f2bf(vv[1]); oh.y = h; ol.y = f2bf(vv[1] - bf2f(h));
  h = f2bf(vv[2]); oh.z = h; ol.z = f2bf(vv[2] - bf2f(h));
  h = f2bf(vv[3]); oh.w = h; ol.w = f2bf(vv[3] - bf2f(h));
  *(ushort4*)(dsth + i) = oh;
  *(ushort4*)(dstl + i) = ol;
}

// ---------------- QKV projection with register-prefetch pipeline ----------------
template<int SPLIT>
__global__ __launch_bounds__(256) void gemm_qkvT(
    const u16* __restrict__ xh, const u16* __restrict__ xl,
    const u16* __restrict__ Whh, const u16* __restrict__ Whl,
    const float* __restrict__ bq, const float* __restrict__ bk, const float* __restrict__ bv,
    float* __restrict__ Qf, float* __restrict__ Kf, u16* __restrict__ Vb)
{
  __shared__ __align__(16) u16 Ah[128][72];
  __shared__ __align__(16) u16 Bh[128][72];
  __shared__ __align__(16) u16 Al[SPLIT?128:1][72];
  __shared__ __align__(16) u16 Bl[SPLIT?128:1][72];
  const int tid = threadIdx.x;
  const int lane = tid & 63, wid = tid >> 6;
  const int l15 = lane & 15, lg = lane >> 4;
  const int wr = wid >> 1, wc = wid & 1;
  const int m0 = blockIdx.y * 128;
  const int n0 = blockIdx.x * 128 + (SPLIT ? 0 : 1024);
  const int which = n0 >> 9;
  const int nb = n0 & 511;
  const float* bias = (which==0) ? bq : (which==1) ? bk : bv;

  floatx4 acc[4][4] = {};

  bhalf8 RAh[4], RBh[4], RAl[4], RBl[4];
  auto loadT = [&](int k0){
    #pragma unroll
    for (int it = 0; it < 4; ++it){
      int e = (tid + it*256)*8;
      int r = e >> 6, c = e & 63;
      size_t ao = (size_t)(m0+r)*1024 + k0 + c;
      size_t bo = (size_t)(n0+r)*1024 + k0 + c;
      RAh[it] = *(const bhalf8*)(xh + ao);
      RBh[it] = *(const bhalf8*)(Whh + bo);
      if (SPLIT){
        RAl[it] = *(const bhalf8*)(xl + ao);
        RBl[it] = *(const bhalf8*)(Whl + bo);
      }
    }
  };
  auto writeT = [&](){
    #pragma unroll
    for (int it = 0; it < 4; ++it){
      int e = (tid + it*256)*8;
      int r = e >> 6, c = e & 63;
      *(bhalf8*)&Ah[r][c] = RAh[it];
      *(bhalf8*)&Bh[r][c] = RBh[it];
      if (SPLIT){
        *(bhalf8*)&Al[r][c] = RAl[it];
        *(bhalf8*)&Bl[r][c] = RBl[it];
      }
    }
  };

  loadT(0);
  writeT();
  __syncthreads();
  for (int k0 = 0; k0 < 1024; k0 += 64){
    if (k0 < 960) loadT(k0 + 64);
    #pragma unroll
    for (int kk = 0; kk < 2; ++kk){
      bhalf8 ah[4], bh8[4];
      #pragma unroll
      for (int xx=0; xx<4; xx++){
        ah[xx]  = *(const bhalf8*)&Ah[wr*64 + xx*16 + l15][kk*32 + lg*8];
        bh8[xx] = *(const bhalf8*)&Bh[wc*64 + xx*16 + l15][kk*32 + lg*8];
      }
      if (SPLIT){
        bhalf8 al[4], bl8[4];
        #pragma unroll
        for (int xx=0; xx<4; xx++){
          al[xx]  = *(const bhalf8*)&Al[wr*64 + xx*16 + l15][kk*32 + lg*8];
          bl8[xx] = *(const bhalf8*)&Bl[wc*64 + xx*16 + l15][kk*32 + lg*8];
        }
        #pragma unroll
        for (int mi=0;mi<4;mi++)
          #pragma unroll
          for (int ni=0;ni<4;ni++){
            acc[mi][ni] = MFMA16(ah[mi], bh8[ni], acc[mi][ni]);
            acc[mi][ni] = MFMA16(ah[mi], bl8[ni], acc[mi][ni]);
            acc[mi][ni] = MFMA16(al[mi], bh8[ni], acc[mi][ni]);
          }
      } else {
        #pragma unroll
        for (int mi=0;mi<4;mi++)
          #pragma unroll
          for (int ni=0;ni<4;ni++)
            acc[mi][ni] = MFMA16(ah[mi], bh8[ni], acc[mi][ni]);
      }
    }
    __syncthreads();
    if (k0 < 960){
      writeT();
      __syncthreads();
    }
  }

  #pragma unroll
  for (int mi=0;mi<4;mi++)
    #pragma unroll
    for (int ni=0;ni<4;ni++){
      int cc = nb + wc*64 + ni*16 + l15;
      float bias_v = bias[cc];
      #pragma unroll
      for (int i=0;i<4;i++){
        int row = m0 + wr*64 + mi*16 + lg*4 + i;
        float v = acc[mi][ni][i] + bias_v;
        size_t off = (size_t)row*512 + cc;
        if (which==0){ Qf[off] = v; }
        else if (which==1){ Kf[off] = v; }
        else { Vb[off] = f2bf(v); }
      }
    }
}

// ---------------- token-temp GEMM, both paths, register-prefetch pipeline ---------------
__global__ __launch_bounds__(256) void gemm_tanh2(
    const float* __restrict__ Af, const u16* __restrict__ Ab,
    const u16* __restrict__ Bq, const u16* __restrict__ Bv,
    u16* __restrict__ oq, u16* __restrict__ ov)
{
  __shared__ __align__(16) u16 As[128][72];
  __shared__ __align__(16) u16 Bs[128][72];
  const int tid = threadIdx.x;
  const int lane = tid & 63, wid = tid >> 6;
  const int l15 = lane & 15, lg = lane >> 4;
  const int wr = wid >> 1, wc = wid & 1;
  const int m0 = blockIdx.y * 128, n0 = blockIdx.x * 128;
  const int zp = blockIdx.z;
  const u16* B = zp ? Bv : Bq;
  u16* o0 = zp ? ov : oq;

  floatx4 acc[4][4] = {};

  float4 RAf[8]; bhalf8 RAb[4]; bhalf8 RB[4];
  auto loadT = [&](int k0){
    #pragma unroll
    for (int it=0; it<4; ++it){
      int e = (tid + it*256)*8;
      int r = e >> 6, c = e & 63;
      if (zp == 0){
        const float* src = Af + (size_t)(m0+r)*512 + k0 + c;
        RAf[it*2]   = *(const float4*)src;
        RAf[it*2+1] = *(const float4*)(src+4);
      } else {
        RAb[it] = *(const bhalf8*)(Ab + (size_t)(m0+r)*512 + k0 + c);
      }
      RB[it] = *(const bhalf8*)(B + (size_t)(n0+r)*512 + k0 + c);
    }
  };
  auto writeT = [&](){
    #pragma unroll
    for (int it=0; it<4; ++it){
      int e = (tid + it*256)*8;
      int r = e >> 6, c = e & 63;
      bhalf8 g;
      if (zp == 0){
        float vv[8] = {RAf[it*2].x,RAf[it*2].y,RAf[it*2].z,RAf[it*2].w,
                       RAf[it*2+1].x,RAf[it*2+1].y,RAf[it*2+1].z,RAf[it*2+1].w};
        #pragma unroll
        for (int j=0;j<8;j++) g[j] = (short)f2bf(gelu_f(vv[j]));
      } else {
        #pragma unroll
        for (int j=0;j<8;j++) g[j] = (short)f2bf(gelu_f(bf2f((u16)RAb[it][j])));
      }
      *(bhalf8*)&As[r][c] = g;
      *(bhalf8*)&Bs[r][c] = RB[it];
    }
  };

  loadT(0);
  writeT();
  __syncthreads();
  for (int k0 = 0; k0 < 512; k0 += 64){
    if (k0 < 448) loadT(k0 + 64);
    #pragma unroll
    for (int kk = 0; kk < 2; ++kk){
      bhalf8 af[4], bfr[4];
      #pragma unroll
      for (int xx=0;xx<4;xx++) af[xx]  = *(const bhalf8*)&As[wr*64 + xx*16 + l15][kk*32 + lg*8];
      #pragma unroll
      for (int xx=0;xx<4;xx++) bfr[xx] = *(const bhalf8*)&Bs[wc*64 + xx*16 + l15][kk*32 + lg*8];
      #pragma unroll
      for (int mi=0;mi<4;mi++)
        #pragma unroll
        for (int ni=0;ni<4;ni++)
          acc[mi][ni] = MFMA16(af[mi], bfr[ni], acc[mi][ni]);
    }
    __syncthreads();
    if (k0 < 448){
      writeT();
      __syncthreads();
    }
  }

  #pragma unroll
  for (int mi=0;mi<4;mi++)
    #pragma unroll
    for (int ni=0;ni<4;ni++){
      int coln = n0 + wc*64 + ni*16 + l15;
      #pragma unroll
      for (int i=0;i<4;i++){
        int row = m0 + wr*64 + mi*16 + lg*4 + i;
        o0[(size_t)row*512 + coln] = f2bf(tanhf(acc[mi][ni][i]));
      }
    }
}

// ---------------- argmax screen: 3-term split MFMA, XCD-chunked + reg prefetch ----------
__global__ __launch_bounds__(256) void gemm_argmax(
    const float* __restrict__ Qf, const float* __restrict__ Kf,
    float4* __restrict__ part)
{
  __shared__ __align__(16) u16 Ah[128][40];
  __shared__ __align__(16) u16 Al[128][40];
  __shared__ __align__(16) u16 Bh[128][40];
  __shared__ __align__(16) u16 Bl[128][40];
  const int tid = threadIdx.x;
  const int lane = tid & 63, wid = tid >> 6;
  const int l15 = lane & 15, lg = lane >> 4;
  const int wr = wid >> 1, wc = wid & 1;
  const int lin = blockIdx.x + 16*blockIdx.y + 256*blockIdx.z;
  const int swz = (lin & 7)*256 + (lin >> 3);
  const int zb  = swz >> 8;
  const int rem = swz & 255;
  const int m0 = (rem >> 4) * 128;
  const int n0 = (rem & 15) * 128;
  const size_t bo = (size_t)zb * 2048 * 512;

  floatx4 acc[4][4] = {};

  float4 RQ[4], RK[4];
  auto loadT = [&](int k0){
    #pragma unroll
    for (int it = 0; it < 2; ++it){
      int e = (tid + it*256)*8;
      int r = e >> 5, c = e & 31;
      const float* sq = Qf + bo + (size_t)(m0+r)*512 + k0 + c;
      const float* sk = Kf + bo + (size_t)(n0+r)*512 + k0 + c;
      RQ[it*2+0] = *(const float4*)sq;
      RQ[it*2+1] = *(const float4*)(sq+4);
      RK[it*2+0] = *(const float4*)sk;
      RK[it*2+1] = *(const float4*)(sk+4);
    }
  };
  auto writeT = [&](){
    #pragma unroll
    for (int it = 0; it < 2; ++it){
      int e = (tid + it*256)*8;
      int r = e >> 5, c = e & 31;
      {
        float vv[8] = {RQ[it*2].x,RQ[it*2].y,RQ[it*2].z,RQ[it*2].w,
                       RQ[it*2+1].x,RQ[it*2+1].y,RQ[it*2+1].z,RQ[it*2+1].w};
        bhalf8 h8, l8;
        #pragma unroll
        for (int j=0;j<8;j++){
          u16 h = f2bf(vv[j]); h8[j] = (short)h;
          l8[j] = (short)f2bf(vv[j] - bf2f(h));
        }
        *(bhalf8*)&Ah[r][c] = h8;
        *(bhalf8*)&Al[r][c] = l8;
      }
      {
        float vv[8] = {RK[it*2].x,RK[it*2].y,RK[it*2].z,RK[it*2].w,
                       RK[it*2+1].x,RK[it*2+1].y,RK[it*2+1].z,RK[it*2+1].w};
        bhalf8 h8, l8;
        #pragma unroll
        for (int j=0;j<8;j++){
          u16 h = f2bf(vv[j]); h8[j] = (short)h;
          l8[j] = (short)f2bf(vv[j] - bf2f(h));
        }
        *(bhalf8*)&Bh[r][c] = h8;
        *(bhalf8*)&Bl[r][c] = l8;
      }
    }
  };

  loadT(0);
  writeT();
  __syncthreads();
  for (int k0 = 0; k0 < 512; k0 += 32){
    if (k0 < 480) loadT(k0 + 32);
    {
      bhalf8 ah[4], al[4], bh[4], bl[4];
      #pragma unroll
      for (int xx=0;xx<4;xx++){
        ah[xx] = *(const bhalf8*)&Ah[wr*64 + xx*16 + l15][lg*8];
        al[xx] = *(const bhalf8*)&Al[wr*64 + xx*16 + l15][lg*8];
        bh[xx] = *(const bhalf8*)&Bh[wc*64 + xx*16 + l15][lg*8];
        bl[xx] = *(const bhalf8*)&Bl[wc*64 + xx*16 + l15][lg*8];
      }
      #pragma unroll
      for (int mi=0;mi<4;mi++)
        #pragma unroll
        for (int ni=0;ni<4;ni++){
          acc[mi][ni] = MFMA16(ah[mi], bh[ni], acc[mi][ni]);
          acc[mi][ni] = MFMA16(ah[mi], bl[ni], acc[mi][ni]);
          acc[mi][ni] = MFMA16(al[mi], bh[ni], acc[mi][ni]);
        }
    }
    __syncthreads();
    if (k0 < 480){
      writeT();
      __syncthreads();
    }
  }

  #pragma unroll
  for (int mi=0;mi<4;mi++)
    #pragma unroll
    for (int i=0;i<4;i++){
      float v1 = -INFINITY, v2 = -INFINITY; int i1 = 0x7fffffff;
      #pragma unroll
      for (int ni=0;ni<4;ni++){
        float v = acc[mi][ni][i];
        int col = n0 + wc*64 + ni*16 + l15;
        if (v > v1 || (v == v1 && col < i1)){ v2 = v1; v1 = v; i1 = col; }
        else v2 = fmaxf(v2, v);
      }
      #pragma unroll
      for (int ms=1; ms<16; ms<<=1){
        float w1 = __shfl_xor(v1, ms, 64);
        int   j1 = __shfl_xor(i1, ms, 64);
        float w2 = __shfl_xor(v2, ms, 64);
        if (w1 > v1 || (w1 == v1 && j1 < i1)){ v2 = fmaxf(v1, w2); v1 = w1; i1 = j1; }
        else { v2 = fmaxf(v2, w1); }
      }
      if (l15 == 0){
        int row = m0 + wr*64 + mi*16 + lg*4 + i;
        size_t gm = (size_t)zb*2048 + row;
        part[gm*32 + ((n0>>7)<<1) + wc] = make_float4(v1, __int_as_float(i1), v2, 0.0f);
      }
    }
}

// ---------------- reduce top2 over 32 col-stripes; flag narrow-gap rows -----------------
__global__ __launch_bounds__(256) void argmax_reduce(const float4* __restrict__ part,
                                                     int* __restrict__ ids,
                                                     int* __restrict__ list1,
                                                     int* __restrict__ cnt){
  int r = blockIdx.x*256 + threadIdx.x;
  if (r >= 16384) return;
  float v1 = -INFINITY, v2 = -INFINITY; int i1 = 0x7fffffff;
  #pragma unroll
  for (int t=0;t<32;t++){
    float4 p = part[(size_t)r*32 + t];
    float w1 = p.x, w2 = p.z; int j1 = __float_as_int(p.y);
    if (w1 > v1 || (w1 == v1 && j1 < i1)){ v2 = fmaxf(v1, w2); v1 = w1; i1 = j1; }
    else { v2 = fmaxf(v2, w1); }
  }
  ids[r] = i1;
  if (v1 - v2 < 0.02f){
    int k = atomicAdd(cnt, 1);
    if (k < 16384) list1[k] = r;
  }
}

// ---------------- exact fix: verified f64-on-f32 argmax for flagged rows -----------------
__global__ __launch_bounds__(256) void argmax_fix(
    const float* __restrict__ Qf, const float* __restrict__ Kf,
    const int* __restrict__ list1, const int* __restrict__ cnt,
    int* __restrict__ ids)
{
  __shared__ float q[512];
  __shared__ double rbest[256];
  __shared__ int ridx[256];
  const int tid = threadIdx.x;
  const int n = *cnt;
  for (int j = blockIdx.x; j < n; j += gridDim.x){
    const int r = list1[j];
    const int b = r >> 11;
    __syncthreads();
    for (int d = tid; d < 512; d += 256) q[d] = Qf[(size_t)r*512 + d];
    __syncthreads();
    double best = -1e300; int bi = 0x7fffffff;
    for (int c = 0; c < 8; ++c){
      int key = tid + c*256;
      const float* kr = Kf + ((size_t)b*2048 + key)*512;
      double acc = 0.0;
      for (int e = 0; e < 512; ++e) acc += (double)q[e]*(double)kr[e];
      if (acc > best || (acc == best && key < bi)){ best = acc; bi = key; }
    }
    rbest[tid] = best; ridx[tid] = bi;
    __syncthreads();
    for (int st=128; st>0; st>>=1){
      if (tid < st){
        double ov = rbest[tid+st]; int oi = ridx[tid+st];
        if (ov > rbest[tid] || (ov == rbest[tid] && oi < ridx[tid])){ rbest[tid]=ov; ridx[tid]=oi; }
      }
      __syncthreads();
    }
    if (tid == 0) ids[r] = ridx[0];
    __syncthreads();
  }
}

// ---------------- K column sums: two-phase deterministic ----------------
__global__ __launch_bounds__(256) void ksum_part(const float* __restrict__ Kf,
                                                 float* __restrict__ kpart){
  const int b = blockIdx.x, chunk = blockIdx.y;
  const int tid = threadIdx.x;
  const float* base = Kf + (size_t)b*2048*512 + (size_t)chunk*128*512;
  #pragma unroll
  for (int h = 0; h < 2; ++h){
    int col = tid + h*256;
    double s = 0.0;
    for (int r = 0; r < 128; ++r) s += (double)base[(size_t)r*512 + col];
    kpart[((size_t)b*16 + chunk)*512 + col] = (float)s;
  }
}
__global__ __launch_bounds__(256) void ksum_final(const float* __restrict__ kpart,
                                                  float* __restrict__ Ksum){
  const int b = blockIdx.x >> 1;
  const int col = (blockIdx.x & 1)*256 + threadIdx.x;
  double s = 0.0;
  #pragma unroll
  for (int c = 0; c < 16; ++c) s += (double)kpart[((size_t)b*16 + c)*512 + col];
  Ksum[b*512 + col] = (float)s;
}

// ---------------- gating: emits gQ hi/lo bf16 (pre-scaled) + f32 gated-V ----------------
__global__ __launch_bounds__(256) void gating_kernel(
    const float* Qf, const float* __restrict__ Kf,
    const u16* __restrict__ V,
    const u16* __restrict__ ttq, const u16* __restrict__ ttv,
    const int* __restrict__ ids, const float* __restrict__ Ksum,
    const float* __restrict__ alphaq, const float* __restrict__ alphav,
    u16* __restrict__ gQh, u16* __restrict__ gQl, float* gVf)
{
  const int m = blockIdx.x;
  const int b = m >> 11, s = m & 2047;
  const int mid = ids[m];
  const float lp = __logf((float)(s+1));
  const float aq = alphaq[s];
  const float pv = 1.0f + sigm(alphav[s])*lp;
  const float qscale = 0.044194173824159220f;
  const size_t ro = (size_t)m*512;
  const size_t ko = ((size_t)b*2048 + mid)*512;
  const int k0 = threadIdx.x*2;

  float2 ks2 = *(const float2*)(Ksum + b*512 + k0);
  float2 q2  = *(const float2*)(Qf + ro + k0);
  float2 km2 = *(const float2*)(Kf + ko + k0);
  ushort2 v2 = *(const ushort2*)(V + ro + k0);
  ushort2 tq2 = *(const ushort2*)(ttq + ro + k0);
  ushort2 tv2 = *(const ushort2*)(ttv + ro + k0);
  ushort2 oqh, oql;
  float2 ov;
  {
    float knob = fabsf(q2.x*(ks2.x - 2048.0f*km2.x));
    float ptq = 1.0f + sigm(aq - knob)*lp;
    float oq = (ptq + bf2f(tq2.x))*q2.x*qscale;
    u16 h = f2bf(oq); oqh.x = h; oql.x = f2bf(oq - bf2f(h));
    ov.x = (pv + bf2f(tv2.x))*bf2f(v2.x);
  }
  {
    float knob = fabsf(q2.y*(ks2.y - 2048.0f*km2.y));
    float ptq = 1.0f + sigm(aq - knob)*lp;
    float oq = (ptq + bf2f(tq2.y))*q2.y*qscale;
    u16 h = f2bf(oq); oqh.y = h; oql.y = f2bf(oq - bf2f(h));
    ov.y = (pv + bf2f(tv2.y))*bf2f(v2.y);
  }
  *(ushort2*)(gQh + ro + k0) = oqh;
  *(ushort2*)(gQl + ro + k0) = oql;
  *(float2*)(gVf + ro + k0) = ov;
}

// ---------------- transpose gV: f32 [b][s][v] -> bf16 [b][v][s] ----------------
__global__ __launch_bounds__(256) void transpose_v(const float* __restrict__ src,
                                                   u16* __restrict__ dst){
  __shared__ __align__(16) u16 t[64][72];
  const int b = blockIdx.z;
  const int s0 = blockIdx.x*64, v0 = blockIdx.y*64;
  const float* S = src + (size_t)b*2048*512;
  u16* D = dst + (size_t)b*512*2048;
  const int tid = threadIdx.x;
  #pragma unroll
  for (int it=0; it<2; ++it){
    int e = (tid + it*256)*8;
    int r = e>>6, c = e&63;
    const float* p = S + (size_t)(s0+r)*512 + v0 + c;
    float4 u0 = *(const float4*)p;
    float4 u1 = *(const float4*)(p+4);
    float vv[8] = {u0.x,u0.y,u0.z,u0.w,u1.x,u1.y,u1.z,u1.w};
    bhalf8 o;
    #pragma unroll
    for (int j=0;j<8;j++) o[j] = (short)f2bf(vv[j]);
    *(bhalf8*)&t[r][c] = o;
  }
  __syncthreads();
  #pragma unroll
  for (int it=0; it<2; ++it){
    int e = (tid + it*256)*8;
    int r = e>>6, c = e&63;
    bhalf8 o;
    #pragma unroll
    for (int j=0;j<8;j++) o[j] = (short)t[c+j][r];
    *(bhalf8*)(D + (size_t)(v0+r)*2048 + s0 + c) = o;
  }
}

// ---------------- flash5: MFMA causal attention, PRE-SPLIT K (pure-copy staging) --------
// Identical math/bits to flash3; K hi/lo read directly from Khb/Klb.
#define QSW(r,g) ((((g) ^ ((r)&7))) << 3)
__global__ __launch_bounds__(256, 2) void flash5(
    const u16* __restrict__ gQh, const u16* __restrict__ gQl,
    const u16* __restrict__ Khb, const u16* __restrict__ Klb,
    const u16* __restrict__ gVT, float* __restrict__ Out)
{
  const int bx = blockIdx.x;
  const int by = blockIdx.y;
  const int b  = by;
  const int hh = (bx & 1) ? (63 - (bx >> 1)) : (bx >> 1);
  const int qt = (by < 4) ? hh : (63 - hh);
  const int q0 = qt * 32;
  const int tid = threadIdx.x, lane = tid & 63, wid = tid >> 6;
  const int l15 = lane & 15, lg = lane >> 4;
  const int wr = wid >> 1, wc = wid & 1;

  __shared__ __align__(16) char smem[74112];
  u16*   qhs = (u16*)smem;
  u16*   khs = (u16*)(smem + 32768);
  u16*   kls = (u16*)(smem + 40960);
  u16*   vss = (u16*)(smem + 49152);
  float* sf  = (float*)(smem + 49152);
  u16*   phs = (u16*)(smem + 65536);
  u16*   pls = (u16*)(smem + 69632);
  float* mstat = (float*)(smem + 73728);
  float* lstat = mstat + 32;
  float* osc   = mstat + 64;

  const u16* Qhb = gQh + ((size_t)b*2048 + q0)*512;
  const u16* Khbb = Khb + (size_t)b*2048*512;
  const u16* Klbb = Klb + (size_t)b*2048*512;
  const u16* Vtb = gVT + (size_t)b*512*2048;

  #pragma unroll
  for (int it=0; it<8; ++it){
    int e = (tid + it*256)*8;
    int r = e >> 9, c = e & 511;
    bhalf8 hv = *(const bhalf8*)(Qhb + (size_t)r*512 + c);
    *(bhalf8*)&qhs[r*512 + QSW(r, c>>3)] = hv;
  }
  bhalf8 qlr[16];
  {
    const u16* Qlb = gQl + ((size_t)b*2048 + q0 + wr*16 + l15)*512;
    #pragma unroll
    for (int c=0;c<8;c++)
      #pragma unroll
      for (int kk=0;kk<2;kk++)
        qlr[c*2+kk] = *(const bhalf8*)(Qlb + c*64 + kk*32 + lg*8);
  }
  if (tid < 32){ mstat[tid] = -INFINITY; lstat[tid] = 0.0f; }

  floatx4 O[4][2][2] = {};
  __syncthreads();

  auto loadK = [&](int kt, int c, bhalf8* dh, bhalf8* dl){
    #pragma unroll
    for (int it=0; it<2; ++it){
      int e = (tid + it*256)*8;
      int r = e>>6, cc = e&63;
      size_t off = (size_t)(kt*64+r)*512 + c*64 + cc;
      dh[it] = *(const bhalf8*)(Khbb + off);
      dl[it] = *(const bhalf8*)(Klbb + off);
    }
  };
  auto writeK = [&](const bhalf8* sh, const bhalf8* sl){
    #pragma unroll
    for (int it=0; it<2; ++it){
      int e = (tid + it*256)*8;
      int r = e>>6, cc = e&63;
      int o = r*64 + QSW(r, cc>>3);
      *(bhalf8*)&khs[o] = sh[it];
      *(bhalf8*)&kls[o] = sl[it];
    }
  };
  auto loadV = [&](int kt, int vc, bhalf8* dst){
    #pragma unroll
    for (int it=0; it<4; ++it){
      int e = (tid + it*256)*8;
      int r = e>>6, cc = e&63;
      dst[it] = *(const bhalf8*)(Vtb + (size_t)(vc*128+r)*2048 + kt*64 + cc);
    }
  };
  auto writeV = [&](const bhalf8* src){
    #pragma unroll
    for (int it=0; it<4; ++it){
      int e = (tid + it*256)*8;
      int r = e>>6, cc = e&63;
      *(bhalf8*)&vss[r*64 + QSW(r, cc>>3)] = src[it];
    }
  };

  const int qrow = wr*16 + l15;
  const int srow = tid >> 3, seg = tid & 7;

  const int nkt = (q0 + 31)/64 + 1;
  for (int kt = 0; kt < nkt; ++kt){
    floatx4 sacc[2] = {};
    bhalf8 kha[2], kla[2];
    loadK(kt, 0, kha, kla);
    writeK(kha, kla);
    __syncthreads();
    for (int c = 0; c < 8; ++c){
      bhalf8 khb2[2], klb2[2];
      if (c < 7) loadK(kt, c+1, khb2, klb2);
      #pragma unroll
      for (int kk=0; kk<2; ++kk){
        bhalf8 ah = *(const bhalf8*)&qhs[qrow*512 + QSW(qrow, c*8 + kk*4 + lg)];
        bhalf8 al = qlr[c*2+kk];
        #pragma unroll
        for (int ni=0; ni<2; ++ni){
          int krow = wc*32 + ni*16 + l15;
          int o = krow*64 + QSW(krow, kk*4 + lg);
          bhalf8 bh = *(const bhalf8*)&khs[o];
          bhalf8 bl = *(const bhalf8*)&kls[o];
          sacc[ni] = MFMA16(ah, bh, sacc[ni]);
          sacc[ni] = MFMA16(ah, bl, sacc[ni]);
          sacc[ni] = MFMA16(al, bh, sacc[ni]);
        }
      }
      __syncthreads();
      if (c < 7){
        writeK(khb2, klb2);
        __syncthreads();
      }
    }
    #pragma unroll
    for (int ni=0; ni<2; ++ni)
      #pragma unroll
      for (int i=0;i<4;i++){
        int row = wr*16 + lg*4 + i;
        int col = wc*32 + ni*16 + l15;
        sf[row*66 + col] = (kt*64 + col <= q0 + row) ? sacc[ni][i] : -INFINITY;
      }
    __syncthreads();
    bhalf8 va[4];
    loadV(kt, 0, va);
    {
      float pv8[8];
      float tmax = -INFINITY;
      #pragma unroll
      for (int jx=0;jx<8;jx++){ pv8[jx] = sf[srow*66 + seg*8 + jx]; tmax = fmaxf(tmax, pv8[jx]); }
      tmax = fmaxf(tmax, __shfl_xor(tmax,1,64));
      tmax = fmaxf(tmax, __shfl_xor(tmax,2,64));
      tmax = fmaxf(tmax, __shfl_xor(tmax,4,64));
      float mo = mstat[srow];
      float mn = fmaxf(mo, tmax);
      float ss = 0.0f;
      bhalf8 h8, l8;
      #pragma unroll
      for (int jx=0;jx<8;jx++){
        float p = __expf(pv8[jx] - mn);
        ss += p;
        u16 hh2 = f2bf(p);
        h8[jx] = (short)hh2;
        l8[jx] = (short)f2bf(p - bf2f(hh2));
      }
      ss += __shfl_xor(ss,1,64);
      ss += __shfl_xor(ss,2,64);
      ss += __shfl_xor(ss,4,64);
      int o = srow*64 + QSW(srow, seg);
      *(bhalf8*)&phs[o] = h8;
      *(bhalf8*)&pls[o] = l8;
      if (seg == 0){
        float sc = __expf(mo - mn);
        lstat[srow] = lstat[srow]*sc + ss;
        mstat[srow] = mn;
        osc[srow] = sc;
      }
    }
    __syncthreads();
    #pragma unroll
    for (int mi=0;mi<2;mi++)
      #pragma unroll
      for (int i=0;i<4;i++){
        float s = osc[mi*16 + lg*4 + i];
        #pragma unroll
        for (int vc=0; vc<4; ++vc)
          #pragma unroll
          for (int ni=0;ni<2;ni++)
            O[vc][mi][ni][i] *= s;
      }
    writeV(va);
    __syncthreads();
    for (int vc = 0; vc < 4; ++vc){
      bhalf8 vb_[4];
      if (vc < 3) loadV(kt, vc+1, vb_);
      #pragma unroll
      for (int kk=0; kk<2; ++kk){
        int gp = kk*4 + lg;
        bhalf8 pah0 = *(const bhalf8*)&phs[l15*64 + QSW(l15, gp)];
        bhalf8 pal0 = *(const bhalf8*)&pls[l15*64 + QSW(l15, gp)];
        bhalf8 pah1 = *(const bhalf8*)&phs[(16+l15)*64 + QSW(16+l15, gp)];
        bhalf8 pal1 = *(const bhalf8*)&pls[(16+l15)*64 + QSW(16+l15, gp)];
        #pragma unroll
        for (int ni=0; ni<2; ++ni){
          int vrow = wid*32 + ni*16 + l15;
          bhalf8 bv_ = *(const bhalf8*)&vss[vrow*64 + QSW(vrow, gp)];
          O[vc][0][ni] = MFMA16(pah0, bv_, O[vc][0][ni]);
          O[vc][0][ni] = MFMA16(pal0, bv_, O[vc][0][ni]);
          O[vc][1][ni] = MFMA16(pah1, bv_, O[vc][1][ni]);
          O[vc][1][ni] = MFMA16(pal1, bv_, O[vc][1][ni]);
        }
      }
      __syncthreads();
      if (vc < 3){
        writeV(vb_);
        __syncthreads();
      }
    }
  }

  #pragma unroll
  for (int vc=0; vc<4; ++vc)
    #pragma unroll
    for (int mi=0;mi<2;mi++)
      #pragma unroll
      for (int i=0;i<4;i++){
        int r = mi*16 + lg*4 + i;
        float inv = 1.0f / lstat[r];
        #pragma unroll
        for (int ni=0;ni<2;ni++){
          int v = vc*128 + wid*32 + ni*16 + l15;
          Out[((size_t)b*2048 + q0 + r)*512 + v] = O[vc][mi][ni][i] * inv;
        }
      }
}

extern "C" void kernel_launch(void* const* d_in, const int* in_sizes, int n_in,
                              void* d_out, int out_size, void* d_ws, size_t ws_size,
                              hipStream_t stream)
{
  const float* x   = (const float*)d_in[0];
  const float* Wq  = (const float*)d_in[1];
  const float* bq  = (const float*)d_in[2];
  const float* Wk  = (const float*)d_in[3];
  const float* bk  = (const float*)d_in[4];
  const float* Wv  = (const float*)d_in[5];
  const float* bv  = (const float*)d_in[6];
  const float* alphaq = (const float*)d_in[7];
  const float* alphav = (const float*)d_in[8];
  const float* tokq = (const float*)d_in[9];
  const float* tokv = (const float*)d_in[10];
  float* out = (float*)d_out;
  char* ws = (char*)d_ws;

  float* Qf  = (float*)(ws + 0);                 // 32 MB (gVf overlays; Khb/Klb after transpose)
  float* gVf = Qf;
  u16* Khb   = (u16*)(ws + 0);                   // 16.8 MB, written after transpose_v
  u16* Klb   = (u16*)(ws + 16777216);            // 16.8 MB
  float* Kf  = (float*)(ws + 33554432);          // 32 MB
  u16* Vb    = (u16*)(ws + 67108864);            // 16 MB
  u16* ttq   = (u16*)(ws + 83886080);            // 16 MB (xl first half; gVT after gating)
  u16* gVT   = ttq;
  u16* ttv   = (u16*)(ws + 100663296);           // 16 MB (xl second half)
  u16* xl    = (u16*)(ws + 83886080);            // 32 MB, dead after gemm_qkv
  u16* gQh   = (u16*)(ws + 117440512);           // 16 MB (xh first half)
  u16* gQl   = (u16*)(ws + 134217728);           // 16 MB (xh second half)
  u16* xh    = (u16*)(ws + 117440512);           // 32 MB, dead after gemm_qkv
  u16* tq_b  = (u16*)(ws + 150994944);           // 0.5 MB
  u16* tv_b  = (u16*)(ws + 151519232);           // 0.5 MB
  int* ids   = (int*)(ws + 152043520);           // 64 KB
  float* ksum = (float*)(ws + 152109056);        // 16 KB
  float4* part = (float4*)(ws + 152125440);      // 8 MB [16384][32] (Whh/Whl first)
  u16* Whh   = (u16*)(ws + 152125440);           // 3 MB, dead after gemm_qkv
  u16* Whl   = (u16*)(ws + 155271168);           // 3 MB
  int* list1 = (int*)(ws + 160514048);           // 64 KB
  int* cnt   = (int*)(ws + 160579584);           // 4 B
  float* kpart = (float*)(ws + 160579840);       // 256 KB
  (void)ws_size; (void)in_sizes; (void)n_in; (void)out_size;

  init_counts<<<1,256,0,stream>>>(cnt);
  cvt_f32_bf16<<<256,256,0,stream>>>(tokq, tq_b, 262144);
  cvt_f32_bf16<<<256,256,0,stream>>>(tokv, tv_b, 262144);

  // pre-split x and W into hi/lo bf16
  cvt_split<<<16384,256,0,stream>>>(x,  xh, xl, 16777216);
  cvt_split<<<512,256,0,stream>>>(Wq, Whh,            Whl,            524288);
  cvt_split<<<512,256,0,stream>>>(Wk, Whh + 524288,   Whl + 524288,   524288);
  cvt_split<<<512,256,0,stream>>>(Wv, Whh + 1048576,  Whl + 1048576,  524288);

  // QKV projection with register-prefetch pipeline (split QK blocks, then V blocks)
  gemm_qkvT<1><<<dim3(8,128),256,0,stream>>>(xh, xl, Whh, Whl, bq, bk, bv, Qf, Kf, Vb);
  gemm_qkvT<0><<<dim3(4,128),256,0,stream>>>(xh, xl, Whh, Whl, bq, bk, bv, Qf, Kf, Vb);

  // token temps: both paths in ONE launch
  gemm_tanh2<<<dim3(4,128,2),256,0,stream>>>(Qf, Vb, tq_b, tv_b, ttq, ttv);

  // argmax: 3-term MFMA screen (XCD-chunked) -> flag near-ties -> exact f64 fix
  gemm_argmax<<<dim3(16,16,8),256,0,stream>>>(Qf, Kf, part);
  argmax_reduce<<<64,256,0,stream>>>(part, ids, list1, cnt);
  argmax_fix<<<64,256,0,stream>>>(Qf, Kf, list1, cnt, ids);

  // K column sums (two-phase deterministic)
  ksum_part<<<dim3(8,16),256,0,stream>>>(Kf, kpart);
  ksum_final<<<16,256,0,stream>>>(kpart, ksum);

  // gating: gQ hi/lo bf16 + f32 gated-V (gVf over Qf)
  gating_kernel<<<16384,256,0,stream>>>(Qf, Kf, Vb, ttq, ttv, ids, ksum,
                                        alphaq, alphav, gQh, gQl, gVf);

  // transpose gV -> bf16 [b][v][s] (over ttq); Qf/gVf region now dead
  transpose_v<<<dim3(32,8,8),256,0,stream>>>(gVf, gVT);

  // pre-split K into hi/lo bf16 (over dead Qf/gVf region)
  cvt_split<<<8192,256,0,stream>>>(Kf, Khb, Klb, 8388608);

  // MFMA causal attention with pure-copy K staging
  flash5<<<dim3(64,8),256,0,stream>>>(gQh, gQl, Khb, Klb, gVT, out);
}

// Round 20
// 941.778 us; speedup vs baseline: 1.0317x; 1.0028x over previous
//
#include <hip/hip_runtime.h>
#include <hip/hip_bf16.h>
#include <math.h>

typedef unsigned short u16;
typedef __attribute__((ext_vector_type(8))) short bhalf8;
typedef __attribute__((ext_vector_type(4))) float floatx4;

#define MFMA16(a,b,c) __builtin_amdgcn_mfma_f32_16x16x32_bf16((a),(b),(c),0,0,0)

__device__ __forceinline__ float bf2f(u16 u){ return __uint_as_float(((unsigned)u)<<16); }
__device__ __forceinline__ u16 f2bf(float f){
  unsigned u = __float_as_uint(f);
  u += 0x7fffu + ((u>>16)&1u);
  return (u16)(u>>16);
}
__device__ __forceinline__ float gelu_f(float x){ return 0.5f*x*(1.0f+erff(x*0.70710678118654752f)); }
__device__ __forceinline__ float sigm(float x){ return 1.0f/(1.0f+__expf(-x)); }

__global__ __launch_bounds__(256) void init_counts(int* cnt){
  if (threadIdx.x == 0 && blockIdx.x == 0) *cnt = 0;
}

__global__ __launch_bounds__(256) void cvt_f32_bf16(const float* __restrict__ src,
                                                    u16* __restrict__ dst, int n){
  int i = (blockIdx.x*256 + threadIdx.x)*4;
  if (i >= n) return;
  const float4 v = *(const float4*)(src + i);
  ushort4 o;
  o.x = f2bf(v.x); o.y = f2bf(v.y); o.z = f2bf(v.z); o.w = f2bf(v.w);
  *(ushort4*)(dst + i) = o;
}

// ---------------- hi/lo split convert: v -> (bf16 hi, bf16 lo) ----------------
__global__ __launch_bounds__(256) void cvt_split(const float* __restrict__ src,
                                                 u16* __restrict__ dsth,
                                                 u16* __restrict__ dstl, int n){
  int i = (blockIdx.x*256 + threadIdx.x)*4;
  if (i >= n) return;
  const float4 v = *(const float4*)(src + i);
  float vv[4] = {v.x, v.y, v.z, v.w};
  ushort4 oh, ol;
  u16 h;
  h = f2bf(vv[0]); oh.x = h; ol.x = f2bf(vv[0] - bf2f(h));
  h = f2bf(vv[1]); oh.y = h; ol.y = f2bf(vv[1] - bf2f(h));
  h = f2bf(vv[2]); oh.z = h; ol.z = f2bf(vv[2] - bf2f(h));
  h = f2bf(vv[3]); oh.w = h; ol.w = f2bf(vv[3] - bf2f(h));
  *(ushort4*)(dsth + i) = oh;
  *(ushort4*)(dstl + i) = ol;
}

// ---------------- QKV projection with register-prefetch pipeline ----------------
template<int SPLIT>
__global__ __launch_bounds__(256) void gemm_qkvT(
    const u16* __restrict__ xh, const u16* __restrict__ xl,
    const u16* __restrict__ Whh, const u16* __restrict__ Whl,
    const float* __restrict__ bq, const float* __restrict__ bk, const float* __restrict__ bv,
    float* __restrict__ Qf, float* __restrict__ Kf, u16* __restrict__ Vb)
{
  __shared__ __align__(16) u16 Ah[128][72];
  __shared__ __align__(16) u16 Bh[128][72];
  __shared__ __align__(16) u16 Al[SPLIT?128:1][72];
  __shared__ __align__(16) u16 Bl[SPLIT?128:1][72];
  const int tid = threadIdx.x;
  const int lane = tid & 63, wid = tid >> 6;
  const int l15 = lane & 15, lg = lane >> 4;
  const int wr = wid >> 1, wc = wid & 1;
  const int m0 = blockIdx.y * 128;
  const int n0 = blockIdx.x * 128 + (SPLIT ? 0 : 1024);
  const int which = n0 >> 9;
  const int nb = n0 & 511;
  const float* bias = (which==0) ? bq : (which==1) ? bk : bv;

  floatx4 acc[4][4] = {};

  bhalf8 RAh[4], RBh[4], RAl[4], RBl[4];
  auto loadT = [&](int k0){
    #pragma unroll
    for (int it = 0; it < 4; ++it){
      int e = (tid + it*256)*8;
      int r = e >> 6, c = e & 63;
      size_t ao = (size_t)(m0+r)*1024 + k0 + c;
      size_t bo = (size_t)(n0+r)*1024 + k0 + c;
      RAh[it] = *(const bhalf8*)(xh + ao);
      RBh[it] = *(const bhalf8*)(Whh + bo);
      if (SPLIT){
        RAl[it] = *(const bhalf8*)(xl + ao);
        RBl[it] = *(const bhalf8*)(Whl + bo);
      }
    }
  };
  auto writeT = [&](){
    #pragma unroll
    for (int it = 0; it < 4; ++it){
      int e = (tid + it*256)*8;
      int r = e >> 6, c = e & 63;
      *(bhalf8*)&Ah[r][c] = RAh[it];
      *(bhalf8*)&Bh[r][c] = RBh[it];
      if (SPLIT){
        *(bhalf8*)&Al[r][c] = RAl[it];
        *(bhalf8*)&Bl[r][c] = RBl[it];
      }
    }
  };

  loadT(0);
  writeT();
  __syncthreads();
  for (int k0 = 0; k0 < 1024; k0 += 64){
    if (k0 < 960) loadT(k0 + 64);
    #pragma unroll
    for (int kk = 0; kk < 2; ++kk){
      bhalf8 ah[4], bh8[4];
      #pragma unroll
      for (int xx=0; xx<4; xx++){
        ah[xx]  = *(const bhalf8*)&Ah[wr*64 + xx*16 + l15][kk*32 + lg*8];
        bh8[xx] = *(const bhalf8*)&Bh[wc*64 + xx*16 + l15][kk*32 + lg*8];
      }
      if (SPLIT){
        bhalf8 al[4], bl8[4];
        #pragma unroll
        for (int xx=0; xx<4; xx++){
          al[xx]  = *(const bhalf8*)&Al[wr*64 + xx*16 + l15][kk*32 + lg*8];
          bl8[xx] = *(const bhalf8*)&Bl[wc*64 + xx*16 + l15][kk*32 + lg*8];
        }
        #pragma unroll
        for (int mi=0;mi<4;mi++)
          #pragma unroll
          for (int ni=0;ni<4;ni++){
            acc[mi][ni] = MFMA16(ah[mi], bh8[ni], acc[mi][ni]);
            acc[mi][ni] = MFMA16(ah[mi], bl8[ni], acc[mi][ni]);
            acc[mi][ni] = MFMA16(al[mi], bh8[ni], acc[mi][ni]);
          }
      } else {
        #pragma unroll
        for (int mi=0;mi<4;mi++)
          #pragma unroll
          for (int ni=0;ni<4;ni++)
            acc[mi][ni] = MFMA16(ah[mi], bh8[ni], acc[mi][ni]);
      }
    }
    __syncthreads();
    if (k0 < 960){
      writeT();
      __syncthreads();
    }
  }

  #pragma unroll
  for (int mi=0;mi<4;mi++)
    #pragma unroll
    for (int ni=0;ni<4;ni++){
      int cc = nb + wc*64 + ni*16 + l15;
      float bias_v = bias[cc];
      #pragma unroll
      for (int i=0;i<4;i++){
        int row = m0 + wr*64 + mi*16 + lg*4 + i;
        float v = acc[mi][ni][i] + bias_v;
        size_t off = (size_t)row*512 + cc;
        if (which==0){ Qf[off] = v; }
        else if (which==1){ Kf[off] = v; }
        else { Vb[off] = f2bf(v); }
      }
    }
}

// ---------------- token-temp GEMM, both paths, register-prefetch pipeline ---------------
__global__ __launch_bounds__(256) void gemm_tanh2(
    const float* __restrict__ Af, const u16* __restrict__ Ab,
    const u16* __restrict__ Bq, const u16* __restrict__ Bv,
    u16* __restrict__ oq, u16* __restrict__ ov)
{
  __shared__ __align__(16) u16 As[128][72];
  __shared__ __align__(16) u16 Bs[128][72];
  const int tid = threadIdx.x;
  const int lane = tid & 63, wid = tid >> 6;
  const int l15 = lane & 15, lg = lane >> 4;
  const int wr = wid >> 1, wc = wid & 1;
  const int m0 = blockIdx.y * 128, n0 = blockIdx.x * 128;
  const int zp = blockIdx.z;
  const u16* B = zp ? Bv : Bq;
  u16* o0 = zp ? ov : oq;

  floatx4 acc[4][4] = {};

  float4 RAf[8]; bhalf8 RAb[4]; bhalf8 RB[4];
  auto loadT = [&](int k0){
    #pragma unroll
    for (int it=0; it<4; ++it){
      int e = (tid + it*256)*8;
      int r = e >> 6, c = e & 63;
      if (zp == 0){
        const float* src = Af + (size_t)(m0+r)*512 + k0 + c;
        RAf[it*2]   = *(const float4*)src;
        RAf[it*2+1] = *(const float4*)(src+4);
      } else {
        RAb[it] = *(const bhalf8*)(Ab + (size_t)(m0+r)*512 + k0 + c);
      }
      RB[it] = *(const bhalf8*)(B + (size_t)(n0+r)*512 + k0 + c);
    }
  };
  auto writeT = [&](){
    #pragma unroll
    for (int it=0; it<4; ++it){
      int e = (tid + it*256)*8;
      int r = e >> 6, c = e & 63;
      bhalf8 g;
      if (zp == 0){
        float vv[8] = {RAf[it*2].x,RAf[it*2].y,RAf[it*2].z,RAf[it*2].w,
                       RAf[it*2+1].x,RAf[it*2+1].y,RAf[it*2+1].z,RAf[it*2+1].w};
        #pragma unroll
        for (int j=0;j<8;j++) g[j] = (short)f2bf(gelu_f(vv[j]));
      } else {
        #pragma unroll
        for (int j=0;j<8;j++) g[j] = (short)f2bf(gelu_f(bf2f((u16)RAb[it][j])));
      }
      *(bhalf8*)&As[r][c] = g;
      *(bhalf8*)&Bs[r][c] = RB[it];
    }
  };

  loadT(0);
  writeT();
  __syncthreads();
  for (int k0 = 0; k0 < 512; k0 += 64){
    if (k0 < 448) loadT(k0 + 64);
    #pragma unroll
    for (int kk = 0; kk < 2; ++kk){
      bhalf8 af[4], bfr[4];
      #pragma unroll
      for (int xx=0;xx<4;xx++) af[xx]  = *(const bhalf8*)&As[wr*64 + xx*16 + l15][kk*32 + lg*8];
      #pragma unroll
      for (int xx=0;xx<4;xx++) bfr[xx] = *(const bhalf8*)&Bs[wc*64 + xx*16 + l15][kk*32 + lg*8];
      #pragma unroll
      for (int mi=0;mi<4;mi++)
        #pragma unroll
        for (int ni=0;ni<4;ni++)
          acc[mi][ni] = MFMA16(af[mi], bfr[ni], acc[mi][ni]);
    }
    __syncthreads();
    if (k0 < 448){
      writeT();
      __syncthreads();
    }
  }

  #pragma unroll
  for (int mi=0;mi<4;mi++)
    #pragma unroll
    for (int ni=0;ni<4;ni++){
      int coln = n0 + wc*64 + ni*16 + l15;
      #pragma unroll
      for (int i=0;i<4;i++){
        int row = m0 + wr*64 + mi*16 + lg*4 + i;
        o0[(size_t)row*512 + coln] = f2bf(tanhf(acc[mi][ni][i]));
      }
    }
}

// ---------------- argmax screen: 3-term split MFMA, PRE-SPLIT Q/K (pure-copy staging) ---
__global__ __launch_bounds__(256) void gemm_argmax(
    const u16* __restrict__ Qsh, const u16* __restrict__ Qsl,
    const u16* __restrict__ Ksh, const u16* __restrict__ Ksl,
    float4* __restrict__ part)
{
  __shared__ __align__(16) u16 Ah[128][40];
  __shared__ __align__(16) u16 Al[128][40];
  __shared__ __align__(16) u16 Bh[128][40];
  __shared__ __align__(16) u16 Bl[128][40];
  const int tid = threadIdx.x;
  const int lane = tid & 63, wid = tid >> 6;
  const int l15 = lane & 15, lg = lane >> 4;
  const int wr = wid >> 1, wc = wid & 1;
  const int lin = blockIdx.x + 16*blockIdx.y + 256*blockIdx.z;
  const int swz = (lin & 7)*256 + (lin >> 3);
  const int zb  = swz >> 8;
  const int rem = swz & 255;
  const int m0 = (rem >> 4) * 128;
  const int n0 = (rem & 15) * 128;
  const size_t bo = (size_t)zb * 2048 * 512;

  floatx4 acc[4][4] = {};

  bhalf8 RQh[2], RQl[2], RKh[2], RKl[2];
  auto loadT = [&](int k0){
    #pragma unroll
    for (int it = 0; it < 2; ++it){
      int e = (tid + it*256)*8;
      int r = e >> 5, c = e & 31;
      size_t qo = bo + (size_t)(m0+r)*512 + k0 + c;
      size_t ko = bo + (size_t)(n0+r)*512 + k0 + c;
      RQh[it] = *(const bhalf8*)(Qsh + qo);
      RQl[it] = *(const bhalf8*)(Qsl + qo);
      RKh[it] = *(const bhalf8*)(Ksh + ko);
      RKl[it] = *(const bhalf8*)(Ksl + ko);
    }
  };
  auto writeT = [&](){
    #pragma unroll
    for (int it = 0; it < 2; ++it){
      int e = (tid + it*256)*8;
      int r = e >> 5, c = e & 31;
      *(bhalf8*)&Ah[r][c] = RQh[it];
      *(bhalf8*)&Al[r][c] = RQl[it];
      *(bhalf8*)&Bh[r][c] = RKh[it];
      *(bhalf8*)&Bl[r][c] = RKl[it];
    }
  };

  loadT(0);
  writeT();
  __syncthreads();
  for (int k0 = 0; k0 < 512; k0 += 32){
    if (k0 < 480) loadT(k0 + 32);
    {
      bhalf8 ah[4], al[4], bh[4], bl[4];
      #pragma unroll
      for (int xx=0;xx<4;xx++){
        ah[xx] = *(const bhalf8*)&Ah[wr*64 + xx*16 + l15][lg*8];
        al[xx] = *(const bhalf8*)&Al[wr*64 + xx*16 + l15][lg*8];
        bh[xx] = *(const bhalf8*)&Bh[wc*64 + xx*16 + l15][lg*8];
        bl[xx] = *(const bhalf8*)&Bl[wc*64 + xx*16 + l15][lg*8];
      }
      #pragma unroll
      for (int mi=0;mi<4;mi++)
        #pragma unroll
        for (int ni=0;ni<4;ni++){
          acc[mi][ni] = MFMA16(ah[mi], bh[ni], acc[mi][ni]);
          acc[mi][ni] = MFMA16(ah[mi], bl[ni], acc[mi][ni]);
          acc[mi][ni] = MFMA16(al[mi], bh[ni], acc[mi][ni]);
        }
    }
    __syncthreads();
    if (k0 < 480){
      writeT();
      __syncthreads();
    }
  }

  #pragma unroll
  for (int mi=0;mi<4;mi++)
    #pragma unroll
    for (int i=0;i<4;i++){
      float v1 = -INFINITY, v2 = -INFINITY; int i1 = 0x7fffffff;
      #pragma unroll
      for (int ni=0;ni<4;ni++){
        float v = acc[mi][ni][i];
        int col = n0 + wc*64 + ni*16 + l15;
        if (v > v1 || (v == v1 && col < i1)){ v2 = v1; v1 = v; i1 = col; }
        else v2 = fmaxf(v2, v);
      }
      #pragma unroll
      for (int ms=1; ms<16; ms<<=1){
        float w1 = __shfl_xor(v1, ms, 64);
        int   j1 = __shfl_xor(i1, ms, 64);
        float w2 = __shfl_xor(v2, ms, 64);
        if (w1 > v1 || (w1 == v1 && j1 < i1)){ v2 = fmaxf(v1, w2); v1 = w1; i1 = j1; }
        else { v2 = fmaxf(v2, w1); }
      }
      if (l15 == 0){
        int row = m0 + wr*64 + mi*16 + lg*4 + i;
        size_t gm = (size_t)zb*2048 + row;
        part[gm*32 + ((n0>>7)<<1) + wc] = make_float4(v1, __int_as_float(i1), v2, 0.0f);
      }
    }
}

// ---------------- reduce top2 over 32 col-stripes; flag narrow-gap rows -----------------
__global__ __launch_bounds__(256) void argmax_reduce(const float4* __restrict__ part,
                                                     int* __restrict__ ids,
                                                     int* __restrict__ list1,
                                                     int* __restrict__ cnt){
  int r = blockIdx.x*256 + threadIdx.x;
  if (r >= 16384) return;
  float v1 = -INFINITY, v2 = -INFINITY; int i1 = 0x7fffffff;
  #pragma unroll
  for (int t=0;t<32;t++){
    float4 p = part[(size_t)r*32 + t];
    float w1 = p.x, w2 = p.z; int j1 = __float_as_int(p.y);
    if (w1 > v1 || (w1 == v1 && j1 < i1)){ v2 = fmaxf(v1, w2); v1 = w1; i1 = j1; }
    else { v2 = fmaxf(v2, w1); }
  }
  ids[r] = i1;
  if (v1 - v2 < 0.02f){
    int k = atomicAdd(cnt, 1);
    if (k < 16384) list1[k] = r;
  }
}

// ---------------- exact fix: verified f64-on-f32 argmax for flagged rows -----------------
__global__ __launch_bounds__(256) void argmax_fix(
    const float* __restrict__ Qf, const float* __restrict__ Kf,
    const int* __restrict__ list1, const int* __restrict__ cnt,
    int* __restrict__ ids)
{
  __shared__ float q[512];
  __shared__ double rbest[256];
  __shared__ int ridx[256];
  const int tid = threadIdx.x;
  const int n = *cnt;
  for (int j = blockIdx.x; j < n; j += gridDim.x){
    const int r = list1[j];
    const int b = r >> 11;
    __syncthreads();
    for (int d = tid; d < 512; d += 256) q[d] = Qf[(size_t)r*512 + d];
    __syncthreads();
    double best = -1e300; int bi = 0x7fffffff;
    for (int c = 0; c < 8; ++c){
      int key = tid + c*256;
      const float* kr = Kf + ((size_t)b*2048 + key)*512;
      double acc = 0.0;
      for (int e = 0; e < 512; ++e) acc += (double)q[e]*(double)kr[e];
      if (acc > best || (acc == best && key < bi)){ best = acc; bi = key; }
    }
    rbest[tid] = best; ridx[tid] = bi;
    __syncthreads();
    for (int st=128; st>0; st>>=1){
      if (tid < st){
        double ov = rbest[tid+st]; int oi = ridx[tid+st];
        if (ov > rbest[tid] || (ov == rbest[tid] && oi < ridx[tid])){ rbest[tid]=ov; ridx[tid]=oi; }
      }
      __syncthreads();
    }
    if (tid == 0) ids[r] = ridx[0];
    __syncthreads();
  }
}

// ---------------- K column sums: two-phase deterministic ----------------
__global__ __launch_bounds__(256) void ksum_part(const float* __restrict__ Kf,
                                                 float* __restrict__ kpart){
  const int b = blockIdx.x, chunk = blockIdx.y;
  const int tid = threadIdx.x;
  const float* base = Kf + (size_t)b*2048*512 + (size_t)chunk*128*512;
  #pragma unroll
  for (int h = 0; h < 2; ++h){
    int col = tid + h*256;
    double s = 0.0;
    for (int r = 0; r < 128; ++r) s += (double)base[(size_t)r*512 + col];
    kpart[((size_t)b*16 + chunk)*512 + col] = (float)s;
  }
}
__global__ __launch_bounds__(256) void ksum_final(const float* __restrict__ kpart,
                                                  float* __restrict__ Ksum){
  const int b = blockIdx.x >> 1;
  const int col = (blockIdx.x & 1)*256 + threadIdx.x;
  double s = 0.0;
  #pragma unroll
  for (int c = 0; c < 16; ++c) s += (double)kpart[((size_t)b*16 + c)*512 + col];
  Ksum[b*512 + col] = (float)s;
}

// ---------------- gating: emits gQ hi/lo bf16 (pre-scaled) + f32 gated-V ----------------
__global__ __launch_bounds__(256) void gating_kernel(
    const float* Qf, const float* __restrict__ Kf,
    const u16* __restrict__ V,
    const u16* __restrict__ ttq, const u16* __restrict__ ttv,
    const int* __restrict__ ids, const float* __restrict__ Ksum,
    const float* __restrict__ alphaq, const float* __restrict__ alphav,
    u16* __restrict__ gQh, u16* __restrict__ gQl, float* gVf)
{
  const int m = blockIdx.x;
  const int b = m >> 11, s = m & 2047;
  const int mid = ids[m];
  const float lp = __logf((float)(s+1));
  const float aq = alphaq[s];
  const float pv = 1.0f + sigm(alphav[s])*lp;
  const float qscale = 0.044194173824159220f;
  const size_t ro = (size_t)m*512;
  const size_t ko = ((size_t)b*2048 + mid)*512;
  const int k0 = threadIdx.x*2;

  float2 ks2 = *(const float2*)(Ksum + b*512 + k0);
  float2 q2  = *(const float2*)(Qf + ro + k0);
  float2 km2 = *(const float2*)(Kf + ko + k0);
  ushort2 v2 = *(const ushort2*)(V + ro + k0);
  ushort2 tq2 = *(const ushort2*)(ttq + ro + k0);
  ushort2 tv2 = *(const ushort2*)(ttv + ro + k0);
  ushort2 oqh, oql;
  float2 ov;
  {
    float knob = fabsf(q2.x*(ks2.x - 2048.0f*km2.x));
    float ptq = 1.0f + sigm(aq - knob)*lp;
    float oq = (ptq + bf2f(tq2.x))*q2.x*qscale;
    u16 h = f2bf(oq); oqh.x = h; oql.x = f2bf(oq - bf2f(h));
    ov.x = (pv + bf2f(tv2.x))*bf2f(v2.x);
  }
  {
    float knob = fabsf(q2.y*(ks2.y - 2048.0f*km2.y));
    float ptq = 1.0f + sigm(aq - knob)*lp;
    float oq = (ptq + bf2f(tq2.y))*q2.y*qscale;
    u16 h = f2bf(oq); oqh.y = h; oql.y = f2bf(oq - bf2f(h));
    ov.y = (pv + bf2f(tv2.y))*bf2f(v2.y);
  }
  *(ushort2*)(gQh + ro + k0) = oqh;
  *(ushort2*)(gQl + ro + k0) = oql;
  *(float2*)(gVf + ro + k0) = ov;
}

// ---------------- transpose gV: f32 [b][s][v] -> bf16 [b][v][s] ----------------
__global__ __launch_bounds__(256) void transpose_v(const float* __restrict__ src,
                                                   u16* __restrict__ dst){
  __shared__ __align__(16) u16 t[64][72];
  const int b = blockIdx.z;
  const int s0 = blockIdx.x*64, v0 = blockIdx.y*64;
  const float* S = src + (size_t)b*2048*512;
  u16* D = dst + (size_t)b*512*2048;
  const int tid = threadIdx.x;
  #pragma unroll
  for (int it=0; it<2; ++it){
    int e = (tid + it*256)*8;
    int r = e>>6, c = e&63;
    const float* p = S + (size_t)(s0+r)*512 + v0 + c;
    float4 u0 = *(const float4*)p;
    float4 u1 = *(const float4*)(p+4);
    float vv[8] = {u0.x,u0.y,u0.z,u0.w,u1.x,u1.y,u1.z,u1.w};
    bhalf8 o;
    #pragma unroll
    for (int j=0;j<8;j++) o[j] = (short)f2bf(vv[j]);
    *(bhalf8*)&t[r][c] = o;
  }
  __syncthreads();
  #pragma unroll
  for (int it=0; it<2; ++it){
    int e = (tid + it*256)*8;
    int r = e>>6, c = e&63;
    bhalf8 o;
    #pragma unroll
    for (int j=0;j<8;j++) o[j] = (short)t[c+j][r];
    *(bhalf8*)(D + (size_t)(v0+r)*2048 + s0 + c) = o;
  }
}

// ---------------- flash5: MFMA causal attention, PRE-SPLIT K (pure-copy staging) --------
#define QSW(r,g) ((((g) ^ ((r)&7))) << 3)
__global__ __launch_bounds__(256, 2) void flash5(
    const u16* __restrict__ gQh, const u16* __restrict__ gQl,
    const u16* __restrict__ Khb, const u16* __restrict__ Klb,
    const u16* __restrict__ gVT, float* __restrict__ Out)
{
  const int bx = blockIdx.x;
  const int by = blockIdx.y;
  const int b  = by;
  const int hh = (bx & 1) ? (63 - (bx >> 1)) : (bx >> 1);
  const int qt = (by < 4) ? hh : (63 - hh);
  const int q0 = qt * 32;
  const int tid = threadIdx.x, lane = tid & 63, wid = tid >> 6;
  const int l15 = lane & 15, lg = lane >> 4;
  const int wr = wid >> 1, wc = wid & 1;

  __shared__ __align__(16) char smem[74112];
  u16*   qhs = (u16*)smem;
  u16*   khs = (u16*)(smem + 32768);
  u16*   kls = (u16*)(smem + 40960);
  u16*   vss = (u16*)(smem + 49152);
  float* sf  = (float*)(smem + 49152);
  u16*   phs = (u16*)(smem + 65536);
  u16*   pls = (u16*)(smem + 69632);
  float* mstat = (float*)(smem + 73728);
  float* lstat = mstat + 32;
  float* osc   = mstat + 64;

  const u16* Qhb = gQh + ((size_t)b*2048 + q0)*512;
  const u16* Khbb = Khb + (size_t)b*2048*512;
  const u16* Klbb = Klb + (size_t)b*2048*512;
  const u16* Vtb = gVT + (size_t)b*512*2048;

  #pragma unroll
  for (int it=0; it<8; ++it){
    int e = (tid + it*256)*8;
    int r = e >> 9, c = e & 511;
    bhalf8 hv = *(const bhalf8*)(Qhb + (size_t)r*512 + c);
    *(bhalf8*)&qhs[r*512 + QSW(r, c>>3)] = hv;
  }
  bhalf8 qlr[16];
  {
    const u16* Qlb = gQl + ((size_t)b*2048 + q0 + wr*16 + l15)*512;
    #pragma unroll
    for (int c=0;c<8;c++)
      #pragma unroll
      for (int kk=0;kk<2;kk++)
        qlr[c*2+kk] = *(const bhalf8*)(Qlb + c*64 + kk*32 + lg*8);
  }
  if (tid < 32){ mstat[tid] = -INFINITY; lstat[tid] = 0.0f; }

  floatx4 O[4][2][2] = {};
  __syncthreads();

  auto loadK = [&](int kt, int c, bhalf8* dh, bhalf8* dl){
    #pragma unroll
    for (int it=0; it<2; ++it){
      int e = (tid + it*256)*8;
      int r = e>>6, cc = e&63;
      size_t off = (size_t)(kt*64+r)*512 + c*64 + cc;
      dh[it] = *(const bhalf8*)(Khbb + off);
      dl[it] = *(const bhalf8*)(Klbb + off);
    }
  };
  auto writeK = [&](const bhalf8* sh, const bhalf8* sl){
    #pragma unroll
    for (int it=0; it<2; ++it){
      int e = (tid + it*256)*8;
      int r = e>>6, cc = e&63;
      int o = r*64 + QSW(r, cc>>3);
      *(bhalf8*)&khs[o] = sh[it];
      *(bhalf8*)&kls[o] = sl[it];
    }
  };
  auto loadV = [&](int kt, int vc, bhalf8* dst){
    #pragma unroll
    for (int it=0; it<4; ++it){
      int e = (tid + it*256)*8;
      int r = e>>6, cc = e&63;
      dst[it] = *(const bhalf8*)(Vtb + (size_t)(vc*128+r)*2048 + kt*64 + cc);
    }
  };
  auto writeV = [&](const bhalf8* src){
    #pragma unroll
    for (int it=0; it<4; ++it){
      int e = (tid + it*256)*8;
      int r = e>>6, cc = e&63;
      *(bhalf8*)&vss[r*64 + QSW(r, cc>>3)] = src[it];
    }
  };

  const int qrow = wr*16 + l15;
  const int srow = tid >> 3, seg = tid & 7;

  const int nkt = (q0 + 31)/64 + 1;
  for (int kt = 0; kt < nkt; ++kt){
    floatx4 sacc[2] = {};
    bhalf8 kha[2], kla[2];
    loadK(kt, 0, kha, kla);
    writeK(kha, kla);
    __syncthreads();
    for (int c = 0; c < 8; ++c){
      bhalf8 khb2[2], klb2[2];
      if (c < 7) loadK(kt, c+1, khb2, klb2);
      #pragma unroll
      for (int kk=0; kk<2; ++kk){
        bhalf8 ah = *(const bhalf8*)&qhs[qrow*512 + QSW(qrow, c*8 + kk*4 + lg)];
        bhalf8 al = qlr[c*2+kk];
        #pragma unroll
        for (int ni=0; ni<2; ++ni){
          int krow = wc*32 + ni*16 + l15;
          int o = krow*64 + QSW(krow, kk*4 + lg);
          bhalf8 bh = *(const bhalf8*)&khs[o];
          bhalf8 bl = *(const bhalf8*)&kls[o];
          sacc[ni] = MFMA16(ah, bh, sacc[ni]);
          sacc[ni] = MFMA16(ah, bl, sacc[ni]);
          sacc[ni] = MFMA16(al, bh, sacc[ni]);
        }
      }
      __syncthreads();
      if (c < 7){
        writeK(khb2, klb2);
        __syncthreads();
      }
    }
    #pragma unroll
    for (int ni=0; ni<2; ++ni)
      #pragma unroll
      for (int i=0;i<4;i++){
        int row = wr*16 + lg*4 + i;
        int col = wc*32 + ni*16 + l15;
        sf[row*66 + col] = (kt*64 + col <= q0 + row) ? sacc[ni][i] : -INFINITY;
      }
    __syncthreads();
    bhalf8 va[4];
    loadV(kt, 0, va);
    {
      float pv8[8];
      float tmax = -INFINITY;
      #pragma unroll
      for (int jx=0;jx<8;jx++){ pv8[jx] = sf[srow*66 + seg*8 + jx]; tmax = fmaxf(tmax, pv8[jx]); }
      tmax = fmaxf(tmax, __shfl_xor(tmax,1,64));
      tmax = fmaxf(tmax, __shfl_xor(tmax,2,64));
      tmax = fmaxf(tmax, __shfl_xor(tmax,4,64));
      float mo = mstat[srow];
      float mn = fmaxf(mo, tmax);
      float ss = 0.0f;
      bhalf8 h8, l8;
      #pragma unroll
      for (int jx=0;jx<8;jx++){
        float p = __expf(pv8[jx] - mn);
        ss += p;
        u16 hh2 = f2bf(p);
        h8[jx] = (short)hh2;
        l8[jx] = (short)f2bf(p - bf2f(hh2));
      }
      ss += __shfl_xor(ss,1,64);
      ss += __shfl_xor(ss,2,64);
      ss += __shfl_xor(ss,4,64);
      int o = srow*64 + QSW(srow, seg);
      *(bhalf8*)&phs[o] = h8;
      *(bhalf8*)&pls[o] = l8;
      if (seg == 0){
        float sc = __expf(mo - mn);
        lstat[srow] = lstat[srow]*sc + ss;
        mstat[srow] = mn;
        osc[srow] = sc;
      }
    }
    __syncthreads();
    #pragma unroll
    for (int mi=0;mi<2;mi++)
      #pragma unroll
      for (int i=0;i<4;i++){
        float s = osc[mi*16 + lg*4 + i];
        #pragma unroll
        for (int vc=0; vc<4; ++vc)
          #pragma unroll
          for (int ni=0;ni<2;ni++)
            O[vc][mi][ni][i] *= s;
      }
    writeV(va);
    __syncthreads();
    for (int vc = 0; vc < 4; ++vc){
      bhalf8 vb_[4];
      if (vc < 3) loadV(kt, vc+1, vb_);
      #pragma unroll
      for (int kk=0; kk<2; ++kk){
        int gp = kk*4 + lg;
        bhalf8 pah0 = *(const bhalf8*)&phs[l15*64 + QSW(l15, gp)];
        bhalf8 pal0 = *(const bhalf8*)&pls[l15*64 + QSW(l15, gp)];
        bhalf8 pah1 = *(const bhalf8*)&phs[(16+l15)*64 + QSW(16+l15, gp)];
        bhalf8 pal1 = *(const bhalf8*)&pls[(16+l15)*64 + QSW(16+l15, gp)];
        #pragma unroll
        for (int ni=0; ni<2; ++ni){
          int vrow = wid*32 + ni*16 + l15;
          bhalf8 bv_ = *(const bhalf8*)&vss[vrow*64 + QSW(vrow, gp)];
          O[vc][0][ni] = MFMA16(pah0, bv_, O[vc][0][ni]);
          O[vc][0][ni] = MFMA16(pal0, bv_, O[vc][0][ni]);
          O[vc][1][ni] = MFMA16(pah1, bv_, O[vc][1][ni]);
          O[vc][1][ni] = MFMA16(pal1, bv_, O[vc][1][ni]);
        }
      }
      __syncthreads();
      if (vc < 3){
        writeV(vb_);
        __syncthreads();
      }
    }
  }

  #pragma unroll
  for (int vc=0; vc<4; ++vc)
    #pragma unroll
    for (int mi=0;mi<2;mi++)
      #pragma unroll
      for (int i=0;i<4;i++){
        int r = mi*16 + lg*4 + i;
        float inv = 1.0f / lstat[r];
        #pragma unroll
        for (int ni=0;ni<2;ni++){
          int v = vc*128 + wid*32 + ni*16 + l15;
          Out[((size_t)b*2048 + q0 + r)*512 + v] = O[vc][mi][ni][i] * inv;
        }
      }
}

extern "C" void kernel_launch(void* const* d_in, const int* in_sizes, int n_in,
                              void* d_out, int out_size, void* d_ws, size_t ws_size,
                              hipStream_t stream)
{
  const float* x   = (const float*)d_in[0];
  const float* Wq  = (const float*)d_in[1];
  const float* bq  = (const float*)d_in[2];
  const float* Wk  = (const float*)d_in[3];
  const float* bk  = (const float*)d_in[4];
  const float* Wv  = (const float*)d_in[5];
  const float* bv  = (const float*)d_in[6];
  const float* alphaq = (const float*)d_in[7];
  const float* alphav = (const float*)d_in[8];
  const float* tokq = (const float*)d_in[9];
  const float* tokv = (const float*)d_in[10];
  float* out = (float*)d_out;
  char* ws = (char*)d_ws;

  float* Qf  = (float*)(ws + 0);                 // 32 MB (gVf overlays; Khb/Klb after transpose)
  float* gVf = Qf;
  u16* Khb   = (u16*)(ws + 0);                   // 16.8 MB, written after transpose_v
  u16* Klb   = (u16*)(ws + 16777216);            // 16.8 MB
  float* Kf  = (float*)(ws + 33554432);          // 32 MB
  u16* Vb    = (u16*)(ws + 67108864);            // 16 MB
  u16* ttq   = (u16*)(ws + 83886080);            // 16 MB (xl 1st half; Ksh pre-tanh2; gVT after gating)
  u16* gVT   = ttq;
  u16* Ksh   = (u16*)(ws + 83886080);            // 16.78 MB (dead once tanh2 runs)
  u16* ttv   = (u16*)(ws + 100663296);           // 16 MB (xl 2nd half; Ksl pre-tanh2)
  u16* Ksl   = (u16*)(ws + 100663296);
  u16* xl    = (u16*)(ws + 83886080);            // 32 MB, dead after gemm_qkv
  u16* gQh   = (u16*)(ws + 117440512);           // 16 MB (xh 1st half; Qsh pre-gating)
  u16* Qsh   = (u16*)(ws + 117440512);
  u16* gQl   = (u16*)(ws + 134217728);           // 16 MB (xh 2nd half; Qsl pre-gating)
  u16* Qsl   = (u16*)(ws + 134217728);
  u16* xh    = (u16*)(ws + 117440512);           // 32 MB, dead after gemm_qkv
  u16* tq_b  = (u16*)(ws + 150994944);           // 0.5 MB
  u16* tv_b  = (u16*)(ws + 151519232);           // 0.5 MB
  int* ids   = (int*)(ws + 152043520);           // 64 KB
  float* ksum = (float*)(ws + 152109056);        // 16 KB
  float4* part = (float4*)(ws + 152125440);      // 8 MB [16384][32] (Whh/Whl first)
  u16* Whh   = (u16*)(ws + 152125440);           // 3 MB, dead after gemm_qkv
  u16* Whl   = (u16*)(ws + 155271168);           // 3 MB
  int* list1 = (int*)(ws + 160514048);           // 64 KB
  int* cnt   = (int*)(ws + 160579584);           // 4 B
  float* kpart = (float*)(ws + 160579840);       // 256 KB
  (void)ws_size; (void)in_sizes; (void)n_in; (void)out_size;

  init_counts<<<1,256,0,stream>>>(cnt);
  cvt_f32_bf16<<<256,256,0,stream>>>(tokq, tq_b, 262144);
  cvt_f32_bf16<<<256,256,0,stream>>>(tokv, tv_b, 262144);

  // pre-split x and W into hi/lo bf16
  cvt_split<<<16384,256,0,stream>>>(x,  xh, xl, 16777216);
  cvt_split<<<512,256,0,stream>>>(Wq, Whh,            Whl,            524288);
  cvt_split<<<512,256,0,stream>>>(Wk, Whh + 524288,   Whl + 524288,   524288);
  cvt_split<<<512,256,0,stream>>>(Wv, Whh + 1048576,  Whl + 1048576,  524288);

  // QKV projection with register-prefetch pipeline (split QK blocks, then V blocks)
  gemm_qkvT<1><<<dim3(8,128),256,0,stream>>>(xh, xl, Whh, Whl, bq, bk, bv, Qf, Kf, Vb);
  gemm_qkvT<0><<<dim3(4,128),256,0,stream>>>(xh, xl, Whh, Whl, bq, bk, bv, Qf, Kf, Vb);

  // pre-split Q and K for argmax (xh/xl regions are dead post-qkv; exact fits)
  cvt_split<<<8192,256,0,stream>>>(Qf, Qsh, Qsl, 8388608);
  cvt_split<<<8192,256,0,stream>>>(Kf, Ksh, Ksl, 8388608);

  // argmax screen FIRST (before tanh2 overwrites Ksh/Ksl region with ttq/ttv)
  gemm_argmax<<<dim3(16,16,8),256,0,stream>>>(Qsh, Qsl, Ksh, Ksl, part);

  // token temps: both paths in ONE launch (overwrites Ksh/Ksl — argmax done)
  gemm_tanh2<<<dim3(4,128,2),256,0,stream>>>(Qf, Vb, tq_b, tv_b, ttq, ttv);

  // argmax resolution: flag near-ties -> exact f64 fix
  argmax_reduce<<<64,256,0,stream>>>(part, ids, list1, cnt);
  argmax_fix<<<64,256,0,stream>>>(Qf, Kf, list1, cnt, ids);

  // K column sums (two-phase deterministic)
  ksum_part<<<dim3(8,16),256,0,stream>>>(Kf, kpart);
  ksum_final<<<16,256,0,stream>>>(kpart, ksum);

  // gating: gQ hi/lo bf16 + f32 gated-V (overwrites Qsh/Qsl — argmax done; gVf over Qf)
  gating_kernel<<<16384,256,0,stream>>>(Qf, Kf, Vb, ttq, ttv, ids, ksum,
                                        alphaq, alphav, gQh, gQl, gVf);

  // transpose gV -> bf16 [b][v][s] (over ttq); Qf/gVf region now dead
  transpose_v<<<dim3(32,8,8),256,0,stream>>>(gVf, gVT);

  // pre-split K into hi/lo bf16 (over dead Qf/gVf region)
  cvt_split<<<8192,256,0,stream>>>(Kf, Khb, Klb, 8388608);

  // MFMA causal attention with pure-copy K staging
  flash5<<<dim3(64,8),256,0,stream>>>(gQh, gQl, Khb, Klb, gVT, out);
}

// Round 21
// 932.863 us; speedup vs baseline: 1.0416x; 1.0096x over previous
//
#include <hip/hip_runtime.h>
#include <hip/hip_bf16.h>
#include <math.h>

typedef unsigned short u16;
typedef __attribute__((ext_vector_type(8))) short bhalf8;
typedef __attribute__((ext_vector_type(4))) float floatx4;

#define MFMA16(a,b,c) __builtin_amdgcn_mfma_f32_16x16x32_bf16((a),(b),(c),0,0,0)

__device__ __forceinline__ float bf2f(u16 u){ return __uint_as_float(((unsigned)u)<<16); }
__device__ __forceinline__ u16 f2bf(float f){
  unsigned u = __float_as_uint(f);
  u += 0x7fffu + ((u>>16)&1u);
  return (u16)(u>>16);
}
__device__ __forceinline__ float gelu_f(float x){ return 0.5f*x*(1.0f+erff(x*0.70710678118654752f)); }
__device__ __forceinline__ float sigm(float x){ return 1.0f/(1.0f+__expf(-x)); }

__global__ __launch_bounds__(256) void init_counts(int* cnt){
  if (threadIdx.x == 0 && blockIdx.x == 0) *cnt = 0;
}

__global__ __launch_bounds__(256) void cvt_f32_bf16(const float* __restrict__ src,
                                                    u16* __restrict__ dst, int n){
  int i = (blockIdx.x*256 + threadIdx.x)*4;
  if (i >= n) return;
  const float4 v = *(const float4*)(src + i);
  ushort4 o;
  o.x = f2bf(v.x); o.y = f2bf(v.y); o.z = f2bf(v.z); o.w = f2bf(v.w);
  *(ushort4*)(dst + i) = o;
}

// ---------------- hi/lo split convert: v -> (bf16 hi, bf16 lo) ----------------
__global__ __launch_bounds__(256) void cvt_split(const float* __restrict__ src,
                                                 u16* __restrict__ dsth,
                                                 u16* __restrict__ dstl, int n){
  int i = (blockIdx.x*256 + threadIdx.x)*4;
  if (i >= n) return;
  const float4 v = *(const float4*)(src + i);
  float vv[4] = {v.x, v.y, v.z, v.w};
  ushort4 oh, ol;
  u16 h;
  h = f2bf(vv[0]); oh.x = h; ol.x = f2bf(vv[0] - bf2f(h));
  h = f2bf(vv[1]); oh.y = h; ol.y = f2bf(vv[1] - bf2f(h));
  h = f2bf(vv[2]); oh.z = h; ol.z = f2bf(vv[2] - bf2f(h));
  h = f2bf(vv[3]); oh.w = h; ol.w = f2bf(vv[3] - bf2f(h));
  *(ushort4*)(dsth + i) = oh;
  *(ushort4*)(dstl + i) = ol;
}

// ---------------- QKV projection with register-prefetch pipeline ----------------
template<int SPLIT>
__global__ __launch_bounds__(256) void gemm_qkvT(
    const u16* __restrict__ xh, const u16* __restrict__ xl,
    const u16* __restrict__ Whh, const u16* __restrict__ Whl,
    const float* __restrict__ bq, const float* __restrict__ bk, const float* __restrict__ bv,
    float* __restrict__ Qf, float* __restrict__ Kf, u16* __restrict__ Vb)
{
  __shared__ __align__(16) u16 Ah[128][72];
  __shared__ __align__(16) u16 Bh[128][72];
  __shared__ __align__(16) u16 Al[SPLIT?128:1][72];
  __shared__ __align__(16) u16 Bl[SPLIT?128:1][72];
  const int tid = threadIdx.x;
  const int lane = tid & 63, wid = tid >> 6;
  const int l15 = lane & 15, lg = lane >> 4;
  const int wr = wid >> 1, wc = wid & 1;
  const int m0 = blockIdx.y * 128;
  const int n0 = blockIdx.x * 128 + (SPLIT ? 0 : 1024);
  const int which = n0 >> 9;
  const int nb = n0 & 511;
  const float* bias = (which==0) ? bq : (which==1) ? bk : bv;

  floatx4 acc[4][4] = {};

  bhalf8 RAh[4], RBh[4], RAl[4], RBl[4];
  auto loadT = [&](int k0){
    #pragma unroll
    for (int it = 0; it < 4; ++it){
      int e = (tid + it*256)*8;
      int r = e >> 6, c = e & 63;
      size_t ao = (size_t)(m0+r)*1024 + k0 + c;
      size_t bo = (size_t)(n0+r)*1024 + k0 + c;
      RAh[it] = *(const bhalf8*)(xh + ao);
      RBh[it] = *(const bhalf8*)(Whh + bo);
      if (SPLIT){
        RAl[it] = *(const bhalf8*)(xl + ao);
        RBl[it] = *(const bhalf8*)(Whl + bo);
      }
    }
  };
  auto writeT = [&](){
    #pragma unroll
    for (int it = 0; it < 4; ++it){
      int e = (tid + it*256)*8;
      int r = e >> 6, c = e & 63;
      *(bhalf8*)&Ah[r][c] = RAh[it];
      *(bhalf8*)&Bh[r][c] = RBh[it];
      if (SPLIT){
        *(bhalf8*)&Al[r][c] = RAl[it];
        *(bhalf8*)&Bl[r][c] = RBl[it];
      }
    }
  };

  loadT(0);
  writeT();
  __syncthreads();
  for (int k0 = 0; k0 < 1024; k0 += 64){
    if (k0 < 960) loadT(k0 + 64);
    #pragma unroll
    for (int kk = 0; kk < 2; ++kk){
      bhalf8 ah[4], bh8[4];
      #pragma unroll
      for (int xx=0; xx<4; xx++){
        ah[xx]  = *(const bhalf8*)&Ah[wr*64 + xx*16 + l15][kk*32 + lg*8];
        bh8[xx] = *(const bhalf8*)&Bh[wc*64 + xx*16 + l15][kk*32 + lg*8];
      }
      if (SPLIT){
        bhalf8 al[4], bl8[4];
        #pragma unroll
        for (int xx=0; xx<4; xx++){
          al[xx]  = *(const bhalf8*)&Al[wr*64 + xx*16 + l15][kk*32 + lg*8];
          bl8[xx] = *(const bhalf8*)&Bl[wc*64 + xx*16 + l15][kk*32 + lg*8];
        }
        #pragma unroll
        for (int mi=0;mi<4;mi++)
          #pragma unroll
          for (int ni=0;ni<4;ni++){
            acc[mi][ni] = MFMA16(ah[mi], bh8[ni], acc[mi][ni]);
            acc[mi][ni] = MFMA16(ah[mi], bl8[ni], acc[mi][ni]);
            acc[mi][ni] = MFMA16(al[mi], bh8[ni], acc[mi][ni]);
          }
      } else {
        #pragma unroll
        for (int mi=0;mi<4;mi++)
          #pragma unroll
          for (int ni=0;ni<4;ni++)
            acc[mi][ni] = MFMA16(ah[mi], bh8[ni], acc[mi][ni]);
      }
    }
    __syncthreads();
    if (k0 < 960){
      writeT();
      __syncthreads();
    }
  }

  #pragma unroll
  for (int mi=0;mi<4;mi++)
    #pragma unroll
    for (int ni=0;ni<4;ni++){
      int cc = nb + wc*64 + ni*16 + l15;
      float bias_v = bias[cc];
      #pragma unroll
      for (int i=0;i<4;i++){
        int row = m0 + wr*64 + mi*16 + lg*4 + i;
        float v = acc[mi][ni][i] + bias_v;
        size_t off = (size_t)row*512 + cc;
        if (which==0){ Qf[off] = v; }
        else if (which==1){ Kf[off] = v; }
        else { Vb[off] = f2bf(v); }
      }
    }
}

// ---------------- token-temp GEMM, both paths, register-prefetch pipeline ---------------
__global__ __launch_bounds__(256) void gemm_tanh2(
    const float* __restrict__ Af, const u16* __restrict__ Ab,
    const u16* __restrict__ Bq, const u16* __restrict__ Bv,
    u16* __restrict__ oq, u16* __restrict__ ov)
{
  __shared__ __align__(16) u16 As[128][72];
  __shared__ __align__(16) u16 Bs[128][72];
  const int tid = threadIdx.x;
  const int lane = tid & 63, wid = tid >> 6;
  const int l15 = lane & 15, lg = lane >> 4;
  const int wr = wid >> 1, wc = wid & 1;
  const int m0 = blockIdx.y * 128, n0 = blockIdx.x * 128;
  const int zp = blockIdx.z;
  const u16* B = zp ? Bv : Bq;
  u16* o0 = zp ? ov : oq;

  floatx4 acc[4][4] = {};

  float4 RAf[8]; bhalf8 RAb[4]; bhalf8 RB[4];
  auto loadT = [&](int k0){
    #pragma unroll
    for (int it=0; it<4; ++it){
      int e = (tid + it*256)*8;
      int r = e >> 6, c = e & 63;
      if (zp == 0){
        const float* src = Af + (size_t)(m0+r)*512 + k0 + c;
        RAf[it*2]   = *(const float4*)src;
        RAf[it*2+1] = *(const float4*)(src+4);
      } else {
        RAb[it] = *(const bhalf8*)(Ab + (size_t)(m0+r)*512 + k0 + c);
      }
      RB[it] = *(const bhalf8*)(B + (size_t)(n0+r)*512 + k0 + c);
    }
  };
  auto writeT = [&](){
    #pragma unroll
    for (int it=0; it<4; ++it){
      int e = (tid + it*256)*8;
      int r = e >> 6, c = e & 63;
      bhalf8 g;
      if (zp == 0){
        float vv[8] = {RAf[it*2].x,RAf[it*2].y,RAf[it*2].z,RAf[it*2].w,
                       RAf[it*2+1].x,RAf[it*2+1].y,RAf[it*2+1].z,RAf[it*2+1].w};
        #pragma unroll
        for (int j=0;j<8;j++) g[j] = (short)f2bf(gelu_f(vv[j]));
      } else {
        #pragma unroll
        for (int j=0;j<8;j++) g[j] = (short)f2bf(gelu_f(bf2f((u16)RAb[it][j])));
      }
      *(bhalf8*)&As[r][c] = g;
      *(bhalf8*)&Bs[r][c] = RB[it];
    }
  };

  loadT(0);
  writeT();
  __syncthreads();
  for (int k0 = 0; k0 < 512; k0 += 64){
    if (k0 < 448) loadT(k0 + 64);
    #pragma unroll
    for (int kk = 0; kk < 2; ++kk){
      bhalf8 af[4], bfr[4];
      #pragma unroll
      for (int xx=0;xx<4;xx++) af[xx]  = *(const bhalf8*)&As[wr*64 + xx*16 + l15][kk*32 + lg*8];
      #pragma unroll
      for (int xx=0;xx<4;xx++) bfr[xx] = *(const bhalf8*)&Bs[wc*64 + xx*16 + l15][kk*32 + lg*8];
      #pragma unroll
      for (int mi=0;mi<4;mi++)
        #pragma unroll
        for (int ni=0;ni<4;ni++)
          acc[mi][ni] = MFMA16(af[mi], bfr[ni], acc[mi][ni]);
    }
    __syncthreads();
    if (k0 < 448){
      writeT();
      __syncthreads();
    }
  }

  #pragma unroll
  for (int mi=0;mi<4;mi++)
    #pragma unroll
    for (int ni=0;ni<4;ni++){
      int coln = n0 + wc*64 + ni*16 + l15;
      #pragma unroll
      for (int i=0;i<4;i++){
        int row = m0 + wr*64 + mi*16 + lg*4 + i;
        o0[(size_t)row*512 + coln] = f2bf(tanhf(acc[mi][ni][i]));
      }
    }
}

// ---------------- argmax screen: 3-term split MFMA, PRE-SPLIT Q/K (pure-copy staging) ---
__global__ __launch_bounds__(256) void gemm_argmax(
    const u16* __restrict__ Qsh, const u16* __restrict__ Qsl,
    const u16* __restrict__ Ksh, const u16* __restrict__ Ksl,
    float4* __restrict__ part)
{
  __shared__ __align__(16) u16 Ah[128][40];
  __shared__ __align__(16) u16 Al[128][40];
  __shared__ __align__(16) u16 Bh[128][40];
  __shared__ __align__(16) u16 Bl[128][40];
  const int tid = threadIdx.x;
  const int lane = tid & 63, wid = tid >> 6;
  const int l15 = lane & 15, lg = lane >> 4;
  const int wr = wid >> 1, wc = wid & 1;
  const int lin = blockIdx.x + 16*blockIdx.y + 256*blockIdx.z;
  const int swz = (lin & 7)*256 + (lin >> 3);
  const int zb  = swz >> 8;
  const int rem = swz & 255;
  const int m0 = (rem >> 4) * 128;
  const int n0 = (rem & 15) * 128;
  const size_t bo = (size_t)zb * 2048 * 512;

  floatx4 acc[4][4] = {};

  bhalf8 RQh[2], RQl[2], RKh[2], RKl[2];
  auto loadT = [&](int k0){
    #pragma unroll
    for (int it = 0; it < 2; ++it){
      int e = (tid + it*256)*8;
      int r = e >> 5, c = e & 31;
      size_t qo = bo + (size_t)(m0+r)*512 + k0 + c;
      size_t ko = bo + (size_t)(n0+r)*512 + k0 + c;
      RQh[it] = *(const bhalf8*)(Qsh + qo);
      RQl[it] = *(const bhalf8*)(Qsl + qo);
      RKh[it] = *(const bhalf8*)(Ksh + ko);
      RKl[it] = *(const bhalf8*)(Ksl + ko);
    }
  };
  auto writeT = [&](){
    #pragma unroll
    for (int it = 0; it < 2; ++it){
      int e = (tid + it*256)*8;
      int r = e >> 5, c = e & 31;
      *(bhalf8*)&Ah[r][c] = RQh[it];
      *(bhalf8*)&Al[r][c] = RQl[it];
      *(bhalf8*)&Bh[r][c] = RKh[it];
      *(bhalf8*)&Bl[r][c] = RKl[it];
    }
  };

  loadT(0);
  writeT();
  __syncthreads();
  for (int k0 = 0; k0 < 512; k0 += 32){
    if (k0 < 480) loadT(k0 + 32);
    {
      bhalf8 ah[4], al[4], bh[4], bl[4];
      #pragma unroll
      for (int xx=0;xx<4;xx++){
        ah[xx] = *(const bhalf8*)&Ah[wr*64 + xx*16 + l15][lg*8];
        al[xx] = *(const bhalf8*)&Al[wr*64 + xx*16 + l15][lg*8];
        bh[xx] = *(const bhalf8*)&Bh[wc*64 + xx*16 + l15][lg*8];
        bl[xx] = *(const bhalf8*)&Bl[wc*64 + xx*16 + l15][lg*8];
      }
      #pragma unroll
      for (int mi=0;mi<4;mi++)
        #pragma unroll
        for (int ni=0;ni<4;ni++){
          acc[mi][ni] = MFMA16(ah[mi], bh[ni], acc[mi][ni]);
          acc[mi][ni] = MFMA16(ah[mi], bl[ni], acc[mi][ni]);
          acc[mi][ni] = MFMA16(al[mi], bh[ni], acc[mi][ni]);
        }
    }
    __syncthreads();
    if (k0 < 480){
      writeT();
      __syncthreads();
    }
  }

  #pragma unroll
  for (int mi=0;mi<4;mi++)
    #pragma unroll
    for (int i=0;i<4;i++){
      float v1 = -INFINITY, v2 = -INFINITY; int i1 = 0x7fffffff;
      #pragma unroll
      for (int ni=0;ni<4;ni++){
        float v = acc[mi][ni][i];
        int col = n0 + wc*64 + ni*16 + l15;
        if (v > v1 || (v == v1 && col < i1)){ v2 = v1; v1 = v; i1 = col; }
        else v2 = fmaxf(v2, v);
      }
      #pragma unroll
      for (int ms=1; ms<16; ms<<=1){
        float w1 = __shfl_xor(v1, ms, 64);
        int   j1 = __shfl_xor(i1, ms, 64);
        float w2 = __shfl_xor(v2, ms, 64);
        if (w1 > v1 || (w1 == v1 && j1 < i1)){ v2 = fmaxf(v1, w2); v1 = w1; i1 = j1; }
        else { v2 = fmaxf(v2, w1); }
      }
      if (l15 == 0){
        int row = m0 + wr*64 + mi*16 + lg*4 + i;
        size_t gm = (size_t)zb*2048 + row;
        part[gm*32 + ((n0>>7)<<1) + wc] = make_float4(v1, __int_as_float(i1), v2, 0.0f);
      }
    }
}

// ---------------- reduce top2 over 32 col-stripes; flag narrow-gap rows -----------------
__global__ __launch_bounds__(256) void argmax_reduce(const float4* __restrict__ part,
                                                     int* __restrict__ ids,
                                                     int* __restrict__ list1,
                                                     int* __restrict__ cnt){
  int r = blockIdx.x*256 + threadIdx.x;
  if (r >= 16384) return;
  float v1 = -INFINITY, v2 = -INFINITY; int i1 = 0x7fffffff;
  #pragma unroll
  for (int t=0;t<32;t++){
    float4 p = part[(size_t)r*32 + t];
    float w1 = p.x, w2 = p.z; int j1 = __float_as_int(p.y);
    if (w1 > v1 || (w1 == v1 && j1 < i1)){ v2 = fmaxf(v1, w2); v1 = w1; i1 = j1; }
    else { v2 = fmaxf(v2, w1); }
  }
  ids[r] = i1;
  if (v1 - v2 < 0.02f){
    int k = atomicAdd(cnt, 1);
    if (k < 16384) list1[k] = r;
  }
}

// ---------------- exact fix: verified f64-on-f32 argmax for flagged rows -----------------
__global__ __launch_bounds__(256) void argmax_fix(
    const float* __restrict__ Qf, const float* __restrict__ Kf,
    const int* __restrict__ list1, const int* __restrict__ cnt,
    int* __restrict__ ids)
{
  __shared__ float q[512];
  __shared__ double rbest[256];
  __shared__ int ridx[256];
  const int tid = threadIdx.x;
  const int n = *cnt;
  for (int j = blockIdx.x; j < n; j += gridDim.x){
    const int r = list1[j];
    const int b = r >> 11;
    __syncthreads();
    for (int d = tid; d < 512; d += 256) q[d] = Qf[(size_t)r*512 + d];
    __syncthreads();
    double best = -1e300; int bi = 0x7fffffff;
    for (int c = 0; c < 8; ++c){
      int key = tid + c*256;
      const float* kr = Kf + ((size_t)b*2048 + key)*512;
      double acc = 0.0;
      for (int e = 0; e < 512; ++e) acc += (double)q[e]*(double)kr[e];
      if (acc > best || (acc == best && key < bi)){ best = acc; bi = key; }
    }
    rbest[tid] = best; ridx[tid] = bi;
    __syncthreads();
    for (int st=128; st>0; st>>=1){
      if (tid < st){
        double ov = rbest[tid+st]; int oi = ridx[tid+st];
        if (ov > rbest[tid] || (ov == rbest[tid] && oi < ridx[tid])){ rbest[tid]=ov; ridx[tid]=oi; }
      }
      __syncthreads();
    }
    if (tid == 0) ids[r] = ridx[0];
    __syncthreads();
  }
}

// ---------------- K column sums: two-phase deterministic ----------------
__global__ __launch_bounds__(256) void ksum_part(const float* __restrict__ Kf,
                                                 float* __restrict__ kpart){
  const int b = blockIdx.x, chunk = blockIdx.y;
  const int tid = threadIdx.x;
  const float* base = Kf + (size_t)b*2048*512 + (size_t)chunk*128*512;
  #pragma unroll
  for (int h = 0; h < 2; ++h){
    int col = tid + h*256;
    double s = 0.0;
    for (int r = 0; r < 128; ++r) s += (double)base[(size_t)r*512 + col];
    kpart[((size_t)b*16 + chunk)*512 + col] = (float)s;
  }
}
__global__ __launch_bounds__(256) void ksum_final(const float* __restrict__ kpart,
                                                  float* __restrict__ Ksum){
  const int b = blockIdx.x >> 1;
  const int col = (blockIdx.x & 1)*256 + threadIdx.x;
  double s = 0.0;
  #pragma unroll
  for (int c = 0; c < 16; ++c) s += (double)kpart[((size_t)b*16 + c)*512 + col];
  Ksum[b*512 + col] = (float)s;
}

// ---------------- gating: emits gQ hi/lo bf16 (pre-scaled) + f32 gated-V ----------------
__global__ __launch_bounds__(256) void gating_kernel(
    const float* Qf, const float* __restrict__ Kf,
    const u16* __restrict__ V,
    const u16* __restrict__ ttq, const u16* __restrict__ ttv,
    const int* __restrict__ ids, const float* __restrict__ Ksum,
    const float* __restrict__ alphaq, const float* __restrict__ alphav,
    u16* __restrict__ gQh, u16* __restrict__ gQl, float* gVf)
{
  const int m = blockIdx.x;
  const int b = m >> 11, s = m & 2047;
  const int mid = ids[m];
  const float lp = __logf((float)(s+1));
  const float aq = alphaq[s];
  const float pv = 1.0f + sigm(alphav[s])*lp;
  const float qscale = 0.044194173824159220f;
  const size_t ro = (size_t)m*512;
  const size_t ko = ((size_t)b*2048 + mid)*512;
  const int k0 = threadIdx.x*2;

  float2 ks2 = *(const float2*)(Ksum + b*512 + k0);
  float2 q2  = *(const float2*)(Qf + ro + k0);
  float2 km2 = *(const float2*)(Kf + ko + k0);
  ushort2 v2 = *(const ushort2*)(V + ro + k0);
  ushort2 tq2 = *(const ushort2*)(ttq + ro + k0);
  ushort2 tv2 = *(const ushort2*)(ttv + ro + k0);
  ushort2 oqh, oql;
  float2 ov;
  {
    float knob = fabsf(q2.x*(ks2.x - 2048.0f*km2.x));
    float ptq = 1.0f + sigm(aq - knob)*lp;
    float oq = (ptq + bf2f(tq2.x))*q2.x*qscale;
    u16 h = f2bf(oq); oqh.x = h; oql.x = f2bf(oq - bf2f(h));
    ov.x = (pv + bf2f(tv2.x))*bf2f(v2.x);
  }
  {
    float knob = fabsf(q2.y*(ks2.y - 2048.0f*km2.y));
    float ptq = 1.0f + sigm(aq - knob)*lp;
    float oq = (ptq + bf2f(tq2.y))*q2.y*qscale;
    u16 h = f2bf(oq); oqh.y = h; oql.y = f2bf(oq - bf2f(h));
    ov.y = (pv + bf2f(tv2.y))*bf2f(v2.y);
  }
  *(ushort2*)(gQh + ro + k0) = oqh;
  *(ushort2*)(gQl + ro + k0) = oql;
  *(float2*)(gVf + ro + k0) = ov;
}

// ---------------- transpose gV: f32 [b][s][v] -> bf16 [b][v][s] ----------------
__global__ __launch_bounds__(256) void transpose_v(const float* __restrict__ src,
                                                   u16* __restrict__ dst){
  __shared__ __align__(16) u16 t[64][72];
  const int b = blockIdx.z;
  const int s0 = blockIdx.x*64, v0 = blockIdx.y*64;
  const float* S = src + (size_t)b*2048*512;
  u16* D = dst + (size_t)b*512*2048;
  const int tid = threadIdx.x;
  #pragma unroll
  for (int it=0; it<2; ++it){
    int e = (tid + it*256)*8;
    int r = e>>6, c = e&63;
    const float* p = S + (size_t)(s0+r)*512 + v0 + c;
    float4 u0 = *(const float4*)p;
    float4 u1 = *(const float4*)(p+4);
    float vv[8] = {u0.x,u0.y,u0.z,u0.w,u1.x,u1.y,u1.z,u1.w};
    bhalf8 o;
    #pragma unroll
    for (int j=0;j<8;j++) o[j] = (short)f2bf(vv[j]);
    *(bhalf8*)&t[r][c] = o;
  }
  __syncthreads();
  #pragma unroll
  for (int it=0; it<2; ++it){
    int e = (tid + it*256)*8;
    int r = e>>6, c = e&63;
    bhalf8 o;
    #pragma unroll
    for (int j=0;j<8;j++) o[j] = (short)t[c+j][r];
    *(bhalf8*)(D + (size_t)(v0+r)*2048 + s0 + c) = o;
  }
}

// ---------------- flash6: MFMA causal attention, pre-split K, P-hi-only PV --------------
// = flash5 minus the P-lo term in PV (bounded direct perturbation <= 2^-9 * E|gV|).
#define QSW(r,g) ((((g) ^ ((r)&7))) << 3)
__global__ __launch_bounds__(256, 2) void flash6(
    const u16* __restrict__ gQh, const u16* __restrict__ gQl,
    const u16* __restrict__ Khb, const u16* __restrict__ Klb,
    const u16* __restrict__ gVT, float* __restrict__ Out)
{
  const int bx = blockIdx.x;
  const int by = blockIdx.y;
  const int b  = by;
  const int hh = (bx & 1) ? (63 - (bx >> 1)) : (bx >> 1);
  const int qt = (by < 4) ? hh : (63 - hh);
  const int q0 = qt * 32;
  const int tid = threadIdx.x, lane = tid & 63, wid = tid >> 6;
  const int l15 = lane & 15, lg = lane >> 4;
  const int wr = wid >> 1, wc = wid & 1;

  __shared__ __align__(16) char smem[74112];
  u16*   qhs = (u16*)smem;
  u16*   khs = (u16*)(smem + 32768);
  u16*   kls = (u16*)(smem + 40960);
  u16*   vss = (u16*)(smem + 49152);
  float* sf  = (float*)(smem + 49152);
  u16*   phs = (u16*)(smem + 65536);
  float* mstat = (float*)(smem + 73728);
  float* lstat = mstat + 32;
  float* osc   = mstat + 64;

  const u16* Qhb = gQh + ((size_t)b*2048 + q0)*512;
  const u16* Khbb = Khb + (size_t)b*2048*512;
  const u16* Klbb = Klb + (size_t)b*2048*512;
  const u16* Vtb = gVT + (size_t)b*512*2048;

  #pragma unroll
  for (int it=0; it<8; ++it){
    int e = (tid + it*256)*8;
    int r = e >> 9, c = e & 511;
    bhalf8 hv = *(const bhalf8*)(Qhb + (size_t)r*512 + c);
    *(bhalf8*)&qhs[r*512 + QSW(r, c>>3)] = hv;
  }
  bhalf8 qlr[16];
  {
    const u16* Qlb = gQl + ((size_t)b*2048 + q0 + wr*16 + l15)*512;
    #pragma unroll
    for (int c=0;c<8;c++)
      #pragma unroll
      for (int kk=0;kk<2;kk++)
        qlr[c*2+kk] = *(const bhalf8*)(Qlb + c*64 + kk*32 + lg*8);
  }
  if (tid < 32){ mstat[tid] = -INFINITY; lstat[tid] = 0.0f; }

  floatx4 O[4][2][2] = {};
  __syncthreads();

  auto loadK = [&](int kt, int c, bhalf8* dh, bhalf8* dl){
    #pragma unroll
    for (int it=0; it<2; ++it){
      int e = (tid + it*256)*8;
      int r = e>>6, cc = e&63;
      size_t off = (size_t)(kt*64+r)*512 + c*64 + cc;
      dh[it] = *(const bhalf8*)(Khbb + off);
      dl[it] = *(const bhalf8*)(Klbb + off);
    }
  };
  auto writeK = [&](const bhalf8* sh, const bhalf8* sl){
    #pragma unroll
    for (int it=0; it<2; ++it){
      int e = (tid + it*256)*8;
      int r = e>>6, cc = e&63;
      int o = r*64 + QSW(r, cc>>3);
      *(bhalf8*)&khs[o] = sh[it];
      *(bhalf8*)&kls[o] = sl[it];
    }
  };
  auto loadV = [&](int kt, int vc, bhalf8* dst){
    #pragma unroll
    for (int it=0; it<4; ++it){
      int e = (tid + it*256)*8;
      int r = e>>6, cc = e&63;
      dst[it] = *(const bhalf8*)(Vtb + (size_t)(vc*128+r)*2048 + kt*64 + cc);
    }
  };
  auto writeV = [&](const bhalf8* src){
    #pragma unroll
    for (int it=0; it<4; ++it){
      int e = (tid + it*256)*8;
      int r = e>>6, cc = e&63;
      *(bhalf8*)&vss[r*64 + QSW(r, cc>>3)] = src[it];
    }
  };

  const int qrow = wr*16 + l15;
  const int srow = tid >> 3, seg = tid & 7;

  const int nkt = (q0 + 31)/64 + 1;
  for (int kt = 0; kt < nkt; ++kt){
    floatx4 sacc[2] = {};
    bhalf8 kha[2], kla[2];
    loadK(kt, 0, kha, kla);
    writeK(kha, kla);
    __syncthreads();
    for (int c = 0; c < 8; ++c){
      bhalf8 khb2[2], klb2[2];
      if (c < 7) loadK(kt, c+1, khb2, klb2);
      #pragma unroll
      for (int kk=0; kk<2; ++kk){
        bhalf8 ah = *(const bhalf8*)&qhs[qrow*512 + QSW(qrow, c*8 + kk*4 + lg)];
        bhalf8 al = qlr[c*2+kk];
        #pragma unroll
        for (int ni=0; ni<2; ++ni){
          int krow = wc*32 + ni*16 + l15;
          int o = krow*64 + QSW(krow, kk*4 + lg);
          bhalf8 bh = *(const bhalf8*)&khs[o];
          bhalf8 bl = *(const bhalf8*)&kls[o];
          sacc[ni] = MFMA16(ah, bh, sacc[ni]);
          sacc[ni] = MFMA16(ah, bl, sacc[ni]);
          sacc[ni] = MFMA16(al, bh, sacc[ni]);
        }
      }
      __syncthreads();
      if (c < 7){
        writeK(khb2, klb2);
        __syncthreads();
      }
    }
    #pragma unroll
    for (int ni=0; ni<2; ++ni)
      #pragma unroll
      for (int i=0;i<4;i++){
        int row = wr*16 + lg*4 + i;
        int col = wc*32 + ni*16 + l15;
        sf[row*66 + col] = (kt*64 + col <= q0 + row) ? sacc[ni][i] : -INFINITY;
      }
    __syncthreads();
    bhalf8 va[4];
    loadV(kt, 0, va);
    {
      float pv8[8];
      float tmax = -INFINITY;
      #pragma unroll
      for (int jx=0;jx<8;jx++){ pv8[jx] = sf[srow*66 + seg*8 + jx]; tmax = fmaxf(tmax, pv8[jx]); }
      tmax = fmaxf(tmax, __shfl_xor(tmax,1,64));
      tmax = fmaxf(tmax, __shfl_xor(tmax,2,64));
      tmax = fmaxf(tmax, __shfl_xor(tmax,4,64));
      float mo = mstat[srow];
      float mn = fmaxf(mo, tmax);
      float ss = 0.0f;
      bhalf8 h8;
      #pragma unroll
      for (int jx=0;jx<8;jx++){
        float p = __expf(pv8[jx] - mn);
        ss += p;
        h8[jx] = (short)f2bf(p);
      }
      ss += __shfl_xor(ss,1,64);
      ss += __shfl_xor(ss,2,64);
      ss += __shfl_xor(ss,4,64);
      int o = srow*64 + QSW(srow, seg);
      *(bhalf8*)&phs[o] = h8;
      if (seg == 0){
        float sc = __expf(mo - mn);
        lstat[srow] = lstat[srow]*sc + ss;
        mstat[srow] = mn;
        osc[srow] = sc;
      }
    }
    __syncthreads();
    #pragma unroll
    for (int mi=0;mi<2;mi++)
      #pragma unroll
      for (int i=0;i<4;i++){
        float s = osc[mi*16 + lg*4 + i];
        #pragma unroll
        for (int vc=0; vc<4; ++vc)
          #pragma unroll
          for (int ni=0;ni<2;ni++)
            O[vc][mi][ni][i] *= s;
      }
    writeV(va);
    __syncthreads();
    for (int vc = 0; vc < 4; ++vc){
      bhalf8 vb_[4];
      if (vc < 3) loadV(kt, vc+1, vb_);
      #pragma unroll
      for (int kk=0; kk<2; ++kk){
        int gp = kk*4 + lg;
        bhalf8 pah0 = *(const bhalf8*)&phs[l15*64 + QSW(l15, gp)];
        bhalf8 pah1 = *(const bhalf8*)&phs[(16+l15)*64 + QSW(16+l15, gp)];
        #pragma unroll
        for (int ni=0; ni<2; ++ni){
          int vrow = wid*32 + ni*16 + l15;
          bhalf8 bv_ = *(const bhalf8*)&vss[vrow*64 + QSW(vrow, gp)];
          O[vc][0][ni] = MFMA16(pah0, bv_, O[vc][0][ni]);
          O[vc][1][ni] = MFMA16(pah1, bv_, O[vc][1][ni]);
        }
      }
      __syncthreads();
      if (vc < 3){
        writeV(vb_);
        __syncthreads();
      }
    }
  }

  #pragma unroll
  for (int vc=0; vc<4; ++vc)
    #pragma unroll
    for (int mi=0;mi<2;mi++)
      #pragma unroll
      for (int i=0;i<4;i++){
        int r = mi*16 + lg*4 + i;
        float inv = 1.0f / lstat[r];
        #pragma unroll
        for (int ni=0;ni<2;ni++){
          int v = vc*128 + wid*32 + ni*16 + l15;
          Out[((size_t)b*2048 + q0 + r)*512 + v] = O[vc][mi][ni][i] * inv;
        }
      }
}

extern "C" void kernel_launch(void* const* d_in, const int* in_sizes, int n_in,
                              void* d_out, int out_size, void* d_ws, size_t ws_size,
                              hipStream_t stream)
{
  const float* x   = (const float*)d_in[0];
  const float* Wq  = (const float*)d_in[1];
  const float* bq  = (const float*)d_in[2];
  const float* Wk  = (const float*)d_in[3];
  const float* bk  = (const float*)d_in[4];
  const float* Wv  = (const float*)d_in[5];
  const float* bv  = (const float*)d_in[6];
  const float* alphaq = (const float*)d_in[7];
  const float* alphav = (const float*)d_in[8];
  const float* tokq = (const float*)d_in[9];
  const float* tokv = (const float*)d_in[10];
  float* out = (float*)d_out;
  char* ws = (char*)d_ws;

  float* Qf  = (float*)(ws + 0);                 // 32 MB (gVf overlays; Khb/Klb after transpose)
  float* gVf = Qf;
  u16* Khb   = (u16*)(ws + 0);                   // 16.8 MB, written after transpose_v
  u16* Klb   = (u16*)(ws + 16777216);            // 16.8 MB
  float* Kf  = (float*)(ws + 33554432);          // 32 MB
  u16* Vb    = (u16*)(ws + 67108864);            // 16 MB
  u16* ttq   = (u16*)(ws + 83886080);            // 16 MB (xl 1st half; Ksh pre-tanh2; gVT after gating)
  u16* gVT   = ttq;
  u16* Ksh   = (u16*)(ws + 83886080);
  u16* ttv   = (u16*)(ws + 100663296);           // 16 MB (xl 2nd half; Ksl pre-tanh2)
  u16* Ksl   = (u16*)(ws + 100663296);
  u16* xl    = (u16*)(ws + 83886080);            // 32 MB, dead after gemm_qkv
  u16* gQh   = (u16*)(ws + 117440512);           // 16 MB (xh 1st half; Qsh pre-gating)
  u16* Qsh   = (u16*)(ws + 117440512);
  u16* gQl   = (u16*)(ws + 134217728);           // 16 MB (xh 2nd half; Qsl pre-gating)
  u16* Qsl   = (u16*)(ws + 134217728);
  u16* xh    = (u16*)(ws + 117440512);           // 32 MB, dead after gemm_qkv
  u16* tq_b  = (u16*)(ws + 150994944);           // 0.5 MB
  u16* tv_b  = (u16*)(ws + 151519232);           // 0.5 MB
  int* ids   = (int*)(ws + 152043520);           // 64 KB
  float* ksum = (float*)(ws + 152109056);        // 16 KB
  float4* part = (float4*)(ws + 152125440);      // 8 MB [16384][32] (Whh/Whl first)
  u16* Whh   = (u16*)(ws + 152125440);           // 3 MB, dead after gemm_qkv
  u16* Whl   = (u16*)(ws + 155271168);           // 3 MB
  int* list1 = (int*)(ws + 160514048);           // 64 KB
  int* cnt   = (int*)(ws + 160579584);           // 4 B
  float* kpart = (float*)(ws + 160579840);       // 256 KB
  (void)ws_size; (void)in_sizes; (void)n_in; (void)out_size;

  init_counts<<<1,256,0,stream>>>(cnt);
  cvt_f32_bf16<<<256,256,0,stream>>>(tokq, tq_b, 262144);
  cvt_f32_bf16<<<256,256,0,stream>>>(tokv, tv_b, 262144);

  // pre-split x and W into hi/lo bf16
  cvt_split<<<16384,256,0,stream>>>(x,  xh, xl, 16777216);
  cvt_split<<<512,256,0,stream>>>(Wq, Whh,            Whl,            524288);
  cvt_split<<<512,256,0,stream>>>(Wk, Whh + 524288,   Whl + 524288,   524288);
  cvt_split<<<512,256,0,stream>>>(Wv, Whh + 1048576,  Whl + 1048576,  524288);

  // QKV projection with register-prefetch pipeline (split QK blocks, then V blocks)
  gemm_qkvT<1><<<dim3(8,128),256,0,stream>>>(xh, xl, Whh, Whl, bq, bk, bv, Qf, Kf, Vb);
  gemm_qkvT<0><<<dim3(4,128),256,0,stream>>>(xh, xl, Whh, Whl, bq, bk, bv, Qf, Kf, Vb);

  // pre-split Q and K for argmax (xh/xl regions are dead post-qkv; exact fits)
  cvt_split<<<8192,256,0,stream>>>(Qf, Qsh, Qsl, 8388608);
  cvt_split<<<8192,256,0,stream>>>(Kf, Ksh, Ksl, 8388608);

  // argmax screen FIRST (before tanh2 overwrites Ksh/Ksl region with ttq/ttv)
  gemm_argmax<<<dim3(16,16,8),256,0,stream>>>(Qsh, Qsl, Ksh, Ksl, part);

  // token temps: both paths in ONE launch (overwrites Ksh/Ksl — argmax done)
  gemm_tanh2<<<dim3(4,128,2),256,0,stream>>>(Qf, Vb, tq_b, tv_b, ttq, ttv);

  // argmax resolution: flag near-ties -> exact f64 fix
  argmax_reduce<<<64,256,0,stream>>>(part, ids, list1, cnt);
  argmax_fix<<<64,256,0,stream>>>(Qf, Kf, list1, cnt, ids);

  // K column sums (two-phase deterministic)
  ksum_part<<<dim3(8,16),256,0,stream>>>(Kf, kpart);
  ksum_final<<<16,256,0,stream>>>(kpart, ksum);

  // gating: gQ hi/lo bf16 + f32 gated-V (overwrites Qsh/Qsl — argmax done; gVf over Qf)
  gating_kernel<<<16384,256,0,stream>>>(Qf, Kf, Vb, ttq, ttv, ids, ksum,
                                        alphaq, alphav, gQh, gQl, gVf);

  // transpose gV -> bf16 [b][v][s] (over ttq); Qf/gVf region now dead
  transpose_v<<<dim3(32,8,8),256,0,stream>>>(gVf, gVT);

  // pre-split K into hi/lo bf16 (over dead Qf/gVf region)
  cvt_split<<<8192,256,0,stream>>>(Kf, Khb, Klb, 8388608);

  // MFMA causal attention: pure-copy K staging, P-hi-only PV
  flash6<<<dim3(64,8),256,0,stream>>>(gQh, gQl, Khb, Klb, gVT, out);
}

// Round 22
// 855.178 us; speedup vs baseline: 1.1362x; 1.0908x over previous
//
#include <hip/hip_runtime.h>
#include <hip/hip_bf16.h>
#include <math.h>

typedef unsigned short u16;
typedef __attribute__((ext_vector_type(8))) short bhalf8;
typedef __attribute__((ext_vector_type(4))) float floatx4;

#define MFMA16(a,b,c) __builtin_amdgcn_mfma_f32_16x16x32_bf16((a),(b),(c),0,0,0)

__device__ __forceinline__ float bf2f(u16 u){ return __uint_as_float(((unsigned)u)<<16); }
__device__ __forceinline__ u16 f2bf(float f){
  unsigned u = __float_as_uint(f);
  u += 0x7fffu + ((u>>16)&1u);
  return (u16)(u>>16);
}
__device__ __forceinline__ float gelu_f(float x){ return 0.5f*x*(1.0f+erff(x*0.70710678118654752f)); }
__device__ __forceinline__ float sigm(float x){ return 1.0f/(1.0f+__expf(-x)); }

__global__ __launch_bounds__(256) void init_counts(int* cnt){
  if (threadIdx.x == 0 && blockIdx.x == 0) *cnt = 0;
}

__global__ __launch_bounds__(256) void cvt_f32_bf16(const float* __restrict__ src,
                                                    u16* __restrict__ dst, int n){
  int i = (blockIdx.x*256 + threadIdx.x)*4;
  if (i >= n) return;
  const float4 v = *(const float4*)(src + i);
  ushort4 o;
  o.x = f2bf(v.x); o.y = f2bf(v.y); o.z = f2bf(v.z); o.w = f2bf(v.w);
  *(ushort4*)(dst + i) = o;
}

// ---------------- hi/lo split convert: v -> (bf16 hi, bf16 lo) ----------------
__global__ __launch_bounds__(256) void cvt_split(const float* __restrict__ src,
                                                 u16* __restrict__ dsth,
                                                 u16* __restrict__ dstl, int n){
  int i = (blockIdx.x*256 + threadIdx.x)*4;
  if (i >= n) return;
  const float4 v = *(const float4*)(src + i);
  float vv[4] = {v.x, v.y, v.z, v.w};
  ushort4 oh, ol;
  u16 h;
  h = f2bf(vv[0]); oh.x = h; ol.x = f2bf(vv[0] - bf2f(h));
  h = f2bf(vv[1]); oh.y = h; ol.y = f2bf(vv[1] - bf2f(h));
  h = f2bf(vv[2]); oh.z = h; ol.z = f2bf(vv[2] - bf2f(h));
  h = f2bf(vv[3]); oh.w = h; ol.w = f2bf(vv[3] - bf2f(h));
  *(ushort4*)(dsth + i) = oh;
  *(ushort4*)(dstl + i) = ol;
}

// ---------------- QKV projection with register-prefetch pipeline ----------------
template<int SPLIT>
__global__ __launch_bounds__(256) void gemm_qkvT(
    const u16* __restrict__ xh, const u16* __restrict__ xl,
    const u16* __restrict__ Whh, const u16* __restrict__ Whl,
    const float* __restrict__ bq, const float* __restrict__ bk, const float* __restrict__ bv,
    float* __restrict__ Qf, float* __restrict__ Kf, u16* __restrict__ Vb)
{
  __shared__ __align__(16) u16 Ah[128][72];
  __shared__ __align__(16) u16 Bh[128][72];
  __shared__ __align__(16) u16 Al[SPLIT?128:1][72];
  __shared__ __align__(16) u16 Bl[SPLIT?128:1][72];
  const int tid = threadIdx.x;
  const int lane = tid & 63, wid = tid >> 6;
  const int l15 = lane & 15, lg = lane >> 4;
  const int wr = wid >> 1, wc = wid & 1;
  const int m0 = blockIdx.y * 128;
  const int n0 = blockIdx.x * 128 + (SPLIT ? 0 : 1024);
  const int which = n0 >> 9;
  const int nb = n0 & 511;
  const float* bias = (which==0) ? bq : (which==1) ? bk : bv;

  floatx4 acc[4][4] = {};

  bhalf8 RAh[4], RBh[4], RAl[4], RBl[4];
  auto loadT = [&](int k0){
    #pragma unroll
    for (int it = 0; it < 4; ++it){
      int e = (tid + it*256)*8;
      int r = e >> 6, c = e & 63;
      size_t ao = (size_t)(m0+r)*1024 + k0 + c;
      size_t bo = (size_t)(n0+r)*1024 + k0 + c;
      RAh[it] = *(const bhalf8*)(xh + ao);
      RBh[it] = *(const bhalf8*)(Whh + bo);
      if (SPLIT){
        RAl[it] = *(const bhalf8*)(xl + ao);
        RBl[it] = *(const bhalf8*)(Whl + bo);
      }
    }
  };
  auto writeT = [&](){
    #pragma unroll
    for (int it = 0; it < 4; ++it){
      int e = (tid + it*256)*8;
      int r = e >> 6, c = e & 63;
      *(bhalf8*)&Ah[r][c] = RAh[it];
      *(bhalf8*)&Bh[r][c] = RBh[it];
      if (SPLIT){
        *(bhalf8*)&Al[r][c] = RAl[it];
        *(bhalf8*)&Bl[r][c] = RBl[it];
      }
    }
  };

  loadT(0);
  writeT();
  __syncthreads();
  for (int k0 = 0; k0 < 1024; k0 += 64){
    if (k0 < 960) loadT(k0 + 64);
    #pragma unroll
    for (int kk = 0; kk < 2; ++kk){
      bhalf8 ah[4], bh8[4];
      #pragma unroll
      for (int xx=0; xx<4; xx++){
        ah[xx]  = *(const bhalf8*)&Ah[wr*64 + xx*16 + l15][kk*32 + lg*8];
        bh8[xx] = *(const bhalf8*)&Bh[wc*64 + xx*16 + l15][kk*32 + lg*8];
      }
      if (SPLIT){
        bhalf8 al[4], bl8[4];
        #pragma unroll
        for (int xx=0; xx<4; xx++){
          al[xx]  = *(const bhalf8*)&Al[wr*64 + xx*16 + l15][kk*32 + lg*8];
          bl8[xx] = *(const bhalf8*)&Bl[wc*64 + xx*16 + l15][kk*32 + lg*8];
        }
        #pragma unroll
        for (int mi=0;mi<4;mi++)
          #pragma unroll
          for (int ni=0;ni<4;ni++){
            acc[mi][ni] = MFMA16(ah[mi], bh8[ni], acc[mi][ni]);
            acc[mi][ni] = MFMA16(ah[mi], bl8[ni], acc[mi][ni]);
            acc[mi][ni] = MFMA16(al[mi], bh8[ni], acc[mi][ni]);
          }
      } else {
        #pragma unroll
        for (int mi=0;mi<4;mi++)
          #pragma unroll
          for (int ni=0;ni<4;ni++)
            acc[mi][ni] = MFMA16(ah[mi], bh8[ni], acc[mi][ni]);
      }
    }
    __syncthreads();
    if (k0 < 960){
      writeT();
      __syncthreads();
    }
  }

  #pragma unroll
  for (int mi=0;mi<4;mi++)
    #pragma unroll
    for (int ni=0;ni<4;ni++){
      int cc = nb + wc*64 + ni*16 + l15;
      float bias_v = bias[cc];
      #pragma unroll
      for (int i=0;i<4;i++){
        int row = m0 + wr*64 + mi*16 + lg*4 + i;
        float v = acc[mi][ni][i] + bias_v;
        size_t off = (size_t)row*512 + cc;
        if (which==0){ Qf[off] = v; }
        else if (which==1){ Kf[off] = v; }
        else { Vb[off] = f2bf(v); }
      }
    }
}

// ---------------- token-temp GEMM, both paths, register-prefetch pipeline ---------------
__global__ __launch_bounds__(256) void gemm_tanh2(
    const float* __restrict__ Af, const u16* __restrict__ Ab,
    const u16* __restrict__ Bq, const u16* __restrict__ Bv,
    u16* __restrict__ oq, u16* __restrict__ ov)
{
  __shared__ __align__(16) u16 As[128][72];
  __shared__ __align__(16) u16 Bs[128][72];
  const int tid = threadIdx.x;
  const int lane = tid & 63, wid = tid >> 6;
  const int l15 = lane & 15, lg = lane >> 4;
  const int wr = wid >> 1, wc = wid & 1;
  const int m0 = blockIdx.y * 128, n0 = blockIdx.x * 128;
  const int zp = blockIdx.z;
  const u16* B = zp ? Bv : Bq;
  u16* o0 = zp ? ov : oq;

  floatx4 acc[4][4] = {};

  float4 RAf[8]; bhalf8 RAb[4]; bhalf8 RB[4];
  auto loadT = [&](int k0){
    #pragma unroll
    for (int it=0; it<4; ++it){
      int e = (tid + it*256)*8;
      int r = e >> 6, c = e & 63;
      if (zp == 0){
        const float* src = Af + (size_t)(m0+r)*512 + k0 + c;
        RAf[it*2]   = *(const float4*)src;
        RAf[it*2+1] = *(const float4*)(src+4);
      } else {
        RAb[it] = *(const bhalf8*)(Ab + (size_t)(m0+r)*512 + k0 + c);
      }
      RB[it] = *(const bhalf8*)(B + (size_t)(n0+r)*512 + k0 + c);
    }
  };
  auto writeT = [&](){
    #pragma unroll
    for (int it=0; it<4; ++it){
      int e = (tid + it*256)*8;
      int r = e >> 6, c = e & 63;
      bhalf8 g;
      if (zp == 0){
        float vv[8] = {RAf[it*2].x,RAf[it*2].y,RAf[it*2].z,RAf[it*2].w,
                       RAf[it*2+1].x,RAf[it*2+1].y,RAf[it*2+1].z,RAf[it*2+1].w};
        #pragma unroll
        for (int j=0;j<8;j++) g[j] = (short)f2bf(gelu_f(vv[j]));
      } else {
        #pragma unroll
        for (int j=0;j<8;j++) g[j] = (short)f2bf(gelu_f(bf2f((u16)RAb[it][j])));
      }
      *(bhalf8*)&As[r][c] = g;
      *(bhalf8*)&Bs[r][c] = RB[it];
    }
  };

  loadT(0);
  writeT();
  __syncthreads();
  for (int k0 = 0; k0 < 512; k0 += 64){
    if (k0 < 448) loadT(k0 + 64);
    #pragma unroll
    for (int kk = 0; kk < 2; ++kk){
      bhalf8 af[4], bfr[4];
      #pragma unroll
      for (int xx=0;xx<4;xx++) af[xx]  = *(const bhalf8*)&As[wr*64 + xx*16 + l15][kk*32 + lg*8];
      #pragma unroll
      for (int xx=0;xx<4;xx++) bfr[xx] = *(const bhalf8*)&Bs[wc*64 + xx*16 + l15][kk*32 + lg*8];
      #pragma unroll
      for (int mi=0;mi<4;mi++)
        #pragma unroll
        for (int ni=0;ni<4;ni++)
          acc[mi][ni] = MFMA16(af[mi], bfr[ni], acc[mi][ni]);
    }
    __syncthreads();
    if (k0 < 448){
      writeT();
      __syncthreads();
    }
  }

  #pragma unroll
  for (int mi=0;mi<4;mi++)
    #pragma unroll
    for (int ni=0;ni<4;ni++){
      int coln = n0 + wc*64 + ni*16 + l15;
      #pragma unroll
      for (int i=0;i<4;i++){
        int row = m0 + wr*64 + mi*16 + lg*4 + i;
        o0[(size_t)row*512 + coln] = f2bf(tanhf(acc[mi][ni][i]));
      }
    }
}

// ---------------- argmax screen: 3-term split MFMA, PRE-SPLIT Q/K (pure-copy staging) ---
__global__ __launch_bounds__(256) void gemm_argmax(
    const u16* __restrict__ Qsh, const u16* __restrict__ Qsl,
    const u16* __restrict__ Ksh, const u16* __restrict__ Ksl,
    float4* __restrict__ part)
{
  __shared__ __align__(16) u16 Ah[128][40];
  __shared__ __align__(16) u16 Al[128][40];
  __shared__ __align__(16) u16 Bh[128][40];
  __shared__ __align__(16) u16 Bl[128][40];
  const int tid = threadIdx.x;
  const int lane = tid & 63, wid = tid >> 6;
  const int l15 = lane & 15, lg = lane >> 4;
  const int wr = wid >> 1, wc = wid & 1;
  const int lin = blockIdx.x + 16*blockIdx.y + 256*blockIdx.z;
  const int swz = (lin & 7)*256 + (lin >> 3);
  const int zb  = swz >> 8;
  const int rem = swz & 255;
  const int m0 = (rem >> 4) * 128;
  const int n0 = (rem & 15) * 128;
  const size_t bo = (size_t)zb * 2048 * 512;

  floatx4 acc[4][4] = {};

  bhalf8 RQh[2], RQl[2], RKh[2], RKl[2];
  auto loadT = [&](int k0){
    #pragma unroll
    for (int it = 0; it < 2; ++it){
      int e = (tid + it*256)*8;
      int r = e >> 5, c = e & 31;
      size_t qo = bo + (size_t)(m0+r)*512 + k0 + c;
      size_t ko = bo + (size_t)(n0+r)*512 + k0 + c;
      RQh[it] = *(const bhalf8*)(Qsh + qo);
      RQl[it] = *(const bhalf8*)(Qsl + qo);
      RKh[it] = *(const bhalf8*)(Ksh + ko);
      RKl[it] = *(const bhalf8*)(Ksl + ko);
    }
  };
  auto writeT = [&](){
    #pragma unroll
    for (int it = 0; it < 2; ++it){
      int e = (tid + it*256)*8;
      int r = e >> 5, c = e & 31;
      *(bhalf8*)&Ah[r][c] = RQh[it];
      *(bhalf8*)&Al[r][c] = RQl[it];
      *(bhalf8*)&Bh[r][c] = RKh[it];
      *(bhalf8*)&Bl[r][c] = RKl[it];
    }
  };

  loadT(0);
  writeT();
  __syncthreads();
  for (int k0 = 0; k0 < 512; k0 += 32){
    if (k0 < 480) loadT(k0 + 32);
    {
      bhalf8 ah[4], al[4], bh[4], bl[4];
      #pragma unroll
      for (int xx=0;xx<4;xx++){
        ah[xx] = *(const bhalf8*)&Ah[wr*64 + xx*16 + l15][lg*8];
        al[xx] = *(const bhalf8*)&Al[wr*64 + xx*16 + l15][lg*8];
        bh[xx] = *(const bhalf8*)&Bh[wc*64 + xx*16 + l15][lg*8];
        bl[xx] = *(const bhalf8*)&Bl[wc*64 + xx*16 + l15][lg*8];
      }
      #pragma unroll
      for (int mi=0;mi<4;mi++)
        #pragma unroll
        for (int ni=0;ni<4;ni++){
          acc[mi][ni] = MFMA16(ah[mi], bh[ni], acc[mi][ni]);
          acc[mi][ni] = MFMA16(ah[mi], bl[ni], acc[mi][ni]);
          acc[mi][ni] = MFMA16(al[mi], bh[ni], acc[mi][ni]);
        }
    }
    __syncthreads();
    if (k0 < 480){
      writeT();
      __syncthreads();
    }
  }

  #pragma unroll
  for (int mi=0;mi<4;mi++)
    #pragma unroll
    for (int i=0;i<4;i++){
      float v1 = -INFINITY, v2 = -INFINITY; int i1 = 0x7fffffff;
      #pragma unroll
      for (int ni=0;ni<4;ni++){
        float v = acc[mi][ni][i];
        int col = n0 + wc*64 + ni*16 + l15;
        if (v > v1 || (v == v1 && col < i1)){ v2 = v1; v1 = v; i1 = col; }
        else v2 = fmaxf(v2, v);
      }
      #pragma unroll
      for (int ms=1; ms<16; ms<<=1){
        float w1 = __shfl_xor(v1, ms, 64);
        int   j1 = __shfl_xor(i1, ms, 64);
        float w2 = __shfl_xor(v2, ms, 64);
        if (w1 > v1 || (w1 == v1 && j1 < i1)){ v2 = fmaxf(v1, w2); v1 = w1; i1 = j1; }
        else { v2 = fmaxf(v2, w1); }
      }
      if (l15 == 0){
        int row = m0 + wr*64 + mi*16 + lg*4 + i;
        size_t gm = (size_t)zb*2048 + row;
        part[gm*32 + ((n0>>7)<<1) + wc] = make_float4(v1, __int_as_float(i1), v2, 0.0f);
      }
    }
}

// ---------------- reduce top2 over 32 col-stripes; flag narrow-gap rows -----------------
__global__ __launch_bounds__(256) void argmax_reduce(const float4* __restrict__ part,
                                                     int* __restrict__ ids,
                                                     int* __restrict__ list1,
                                                     int* __restrict__ cnt){
  int r = blockIdx.x*256 + threadIdx.x;
  if (r >= 16384) return;
  float v1 = -INFINITY, v2 = -INFINITY; int i1 = 0x7fffffff;
  #pragma unroll
  for (int t=0;t<32;t++){
    float4 p = part[(size_t)r*32 + t];
    float w1 = p.x, w2 = p.z; int j1 = __float_as_int(p.y);
    if (w1 > v1 || (w1 == v1 && j1 < i1)){ v2 = fmaxf(v1, w2); v1 = w1; i1 = j1; }
    else { v2 = fmaxf(v2, w1); }
  }
  ids[r] = i1;
  if (v1 - v2 < 0.02f){
    int k = atomicAdd(cnt, 1);
    if (k < 16384) list1[k] = r;
  }
}

// ---------------- exact fix: verified f64-on-f32 argmax for flagged rows -----------------
__global__ __launch_bounds__(256) void argmax_fix(
    const float* __restrict__ Qf, const float* __restrict__ Kf,
    const int* __restrict__ list1, const int* __restrict__ cnt,
    int* __restrict__ ids)
{
  __shared__ float q[512];
  __shared__ double rbest[256];
  __shared__ int ridx[256];
  const int tid = threadIdx.x;
  const int n = *cnt;
  for (int j = blockIdx.x; j < n; j += gridDim.x){
    const int r = list1[j];
    const int b = r >> 11;
    __syncthreads();
    for (int d = tid; d < 512; d += 256) q[d] = Qf[(size_t)r*512 + d];
    __syncthreads();
    double best = -1e300; int bi = 0x7fffffff;
    for (int c = 0; c < 8; ++c){
      int key = tid + c*256;
      const float* kr = Kf + ((size_t)b*2048 + key)*512;
      double acc = 0.0;
      for (int e = 0; e < 512; ++e) acc += (double)q[e]*(double)kr[e];
      if (acc > best || (acc == best && key < bi)){ best = acc; bi = key; }
    }
    rbest[tid] = best; ridx[tid] = bi;
    __syncthreads();
    for (int st=128; st>0; st>>=1){
      if (tid < st){
        double ov = rbest[tid+st]; int oi = ridx[tid+st];
        if (ov > rbest[tid] || (ov == rbest[tid] && oi < ridx[tid])){ rbest[tid]=ov; ridx[tid]=oi; }
      }
      __syncthreads();
    }
    if (tid == 0) ids[r] = ridx[0];
    __syncthreads();
  }
}

// ---------------- K column sums: two-phase deterministic ----------------
__global__ __launch_bounds__(256) void ksum_part(const float* __restrict__ Kf,
                                                 float* __restrict__ kpart){
  const int b = blockIdx.x, chunk = blockIdx.y;
  const int tid = threadIdx.x;
  const float* base = Kf + (size_t)b*2048*512 + (size_t)chunk*128*512;
  #pragma unroll
  for (int h = 0; h < 2; ++h){
    int col = tid + h*256;
    double s = 0.0;
    for (int r = 0; r < 128; ++r) s += (double)base[(size_t)r*512 + col];
    kpart[((size_t)b*16 + chunk)*512 + col] = (float)s;
  }
}
__global__ __launch_bounds__(256) void ksum_final(const float* __restrict__ kpart,
                                                  float* __restrict__ Ksum){
  const int b = blockIdx.x >> 1;
  const int col = (blockIdx.x & 1)*256 + threadIdx.x;
  double s = 0.0;
  #pragma unroll
  for (int c = 0; c < 16; ++c) s += (double)kpart[((size_t)b*16 + c)*512 + col];
  Ksum[b*512 + col] = (float)s;
}

// ---------------- gating: emits gQ hi/lo bf16 (pre-scaled) + f32 gated-V ----------------
__global__ __launch_bounds__(256) void gating_kernel(
    const float* Qf, const float* __restrict__ Kf,
    const u16* __restrict__ V,
    const u16* __restrict__ ttq, const u16* __restrict__ ttv,
    const int* __restrict__ ids, const float* __restrict__ Ksum,
    const float* __restrict__ alphaq, const float* __restrict__ alphav,
    u16* __restrict__ gQh, u16* __restrict__ gQl, float* gVf)
{
  const int m = blockIdx.x;
  const int b = m >> 11, s = m & 2047;
  const int mid = ids[m];
  const float lp = __logf((float)(s+1));
  const float aq = alphaq[s];
  const float pv = 1.0f + sigm(alphav[s])*lp;
  const float qscale = 0.044194173824159220f;
  const size_t ro = (size_t)m*512;
  const size_t ko = ((size_t)b*2048 + mid)*512;
  const int k0 = threadIdx.x*2;

  float2 ks2 = *(const float2*)(Ksum + b*512 + k0);
  float2 q2  = *(const float2*)(Qf + ro + k0);
  float2 km2 = *(const float2*)(Kf + ko + k0);
  ushort2 v2 = *(const ushort2*)(V + ro + k0);
  ushort2 tq2 = *(const ushort2*)(ttq + ro + k0);
  ushort2 tv2 = *(const ushort2*)(ttv + ro + k0);
  ushort2 oqh, oql;
  float2 ov;
  {
    float knob = fabsf(q2.x*(ks2.x - 2048.0f*km2.x));
    float ptq = 1.0f + sigm(aq - knob)*lp;
    float oq = (ptq + bf2f(tq2.x))*q2.x*qscale;
    u16 h = f2bf(oq); oqh.x = h; oql.x = f2bf(oq - bf2f(h));
    ov.x = (pv + bf2f(tv2.x))*bf2f(v2.x);
  }
  {
    float knob = fabsf(q2.y*(ks2.y - 2048.0f*km2.y));
    float ptq = 1.0f + sigm(aq - knob)*lp;
    float oq = (ptq + bf2f(tq2.y))*q2.y*qscale;
    u16 h = f2bf(oq); oqh.y = h; oql.y = f2bf(oq - bf2f(h));
    ov.y = (pv + bf2f(tv2.y))*bf2f(v2.y);
  }
  *(ushort2*)(gQh + ro + k0) = oqh;
  *(ushort2*)(gQl + ro + k0) = oql;
  *(float2*)(gVf + ro + k0) = ov;
}

// ---------------- transpose gV: f32 [b][s][v] -> bf16 [b][v][s] ----------------
__global__ __launch_bounds__(256) void transpose_v(const float* __restrict__ src,
                                                   u16* __restrict__ dst){
  __shared__ __align__(16) u16 t[64][72];
  const int b = blockIdx.z;
  const int s0 = blockIdx.x*64, v0 = blockIdx.y*64;
  const float* S = src + (size_t)b*2048*512;
  u16* D = dst + (size_t)b*512*2048;
  const int tid = threadIdx.x;
  #pragma unroll
  for (int it=0; it<2; ++it){
    int e = (tid + it*256)*8;
    int r = e>>6, c = e&63;
    const float* p = S + (size_t)(s0+r)*512 + v0 + c;
    float4 u0 = *(const float4*)p;
    float4 u1 = *(const float4*)(p+4);
    float vv[8] = {u0.x,u0.y,u0.z,u0.w,u1.x,u1.y,u1.z,u1.w};
    bhalf8 o;
    #pragma unroll
    for (int j=0;j<8;j++) o[j] = (short)f2bf(vv[j]);
    *(bhalf8*)&t[r][c] = o;
  }
  __syncthreads();
  #pragma unroll
  for (int it=0; it<2; ++it){
    int e = (tid + it*256)*8;
    int r = e>>6, c = e&63;
    bhalf8 o;
    #pragma unroll
    for (int j=0;j<8;j++) o[j] = (short)t[c+j][r];
    *(bhalf8*)(D + (size_t)(v0+r)*2048 + s0 + c) = o;
  }
}

// ---------------- flash7: dbuf-K single-barrier QK, 2-term scores, P-hi PV --------------
// scores = (gQh + gQl) . K_bf16 ; K double-buffered in LDS with ONE barrier per chunk.
// LDS 69.9KB: qhs 32K | khA 8K | khB 8K (sf 8.4K unions khA/B, dead post-QK) |
//             vss 16K | phs 4K | stats 256B.
#define QSW(r,g) ((((g) ^ ((r)&7))) << 3)
__global__ __launch_bounds__(256, 2) void flash7(
    const u16* __restrict__ gQh, const u16* __restrict__ gQl,
    const u16* __restrict__ Khb,
    const u16* __restrict__ gVT, float* __restrict__ Out)
{
  const int bx = blockIdx.x;
  const int by = blockIdx.y;
  const int b  = by;
  const int hh = (bx & 1) ? (63 - (bx >> 1)) : (bx >> 1);
  const int qt = (by < 4) ? hh : (63 - hh);
  const int q0 = qt * 32;
  const int tid = threadIdx.x, lane = tid & 63, wid = tid >> 6;
  const int l15 = lane & 15, lg = lane >> 4;
  const int wr = wid >> 1, wc = wid & 1;

  __shared__ __align__(16) char smem[69888];
  u16*   qhs = (u16*)smem;                 // 32768
  // khA @32768 (8192), khB @40960 (8192); sf unions 32768..41215 (dead overlap OK)
  float* sf  = (float*)(smem + 32768);
  u16*   vss = (u16*)(smem + 49152);       // 16384
  u16*   phs = (u16*)(smem + 65536);       // 4096
  float* mstat = (float*)(smem + 69632);
  float* lstat = mstat + 32;
  float* osc   = mstat + 64;

  const u16* Qhb = gQh + ((size_t)b*2048 + q0)*512;
  const u16* Kbb = Khb + (size_t)b*2048*512;
  const u16* Vtb = gVT + (size_t)b*512*2048;

  #pragma unroll
  for (int it=0; it<8; ++it){
    int e = (tid + it*256)*8;
    int r = e >> 9, c = e & 511;
    bhalf8 hv = *(const bhalf8*)(Qhb + (size_t)r*512 + c);
    *(bhalf8*)&qhs[r*512 + QSW(r, c>>3)] = hv;
  }
  bhalf8 qlr[16];
  {
    const u16* Qlb = gQl + ((size_t)b*2048 + q0 + wr*16 + l15)*512;
    #pragma unroll
    for (int c=0;c<8;c++)
      #pragma unroll
      for (int kk=0;kk<2;kk++)
        qlr[c*2+kk] = *(const bhalf8*)(Qlb + c*64 + kk*32 + lg*8);
  }
  if (tid < 32){ mstat[tid] = -INFINITY; lstat[tid] = 0.0f; }

  floatx4 O[4][2][2] = {};
  __syncthreads();

  bhalf8 RK[2];
  auto loadK = [&](int kt, int c){
    #pragma unroll
    for (int it=0; it<2; ++it){
      int e = (tid + it*256)*8;
      int r = e>>6, cc = e&63;
      RK[it] = *(const bhalf8*)(Kbb + (size_t)(kt*64+r)*512 + c*64 + cc);
    }
  };
  auto writeK = [&](int buf){
    u16* khX = (u16*)(smem + 32768 + buf*8192);
    #pragma unroll
    for (int it=0; it<2; ++it){
      int e = (tid + it*256)*8;
      int r = e>>6, cc = e&63;
      *(bhalf8*)&khX[r*64 + QSW(r, cc>>3)] = RK[it];
    }
  };
  auto loadV = [&](int kt, int vc, bhalf8* dst){
    #pragma unroll
    for (int it=0; it<4; ++it){
      int e = (tid + it*256)*8;
      int r = e>>6, cc = e&63;
      dst[it] = *(const bhalf8*)(Vtb + (size_t)(vc*128+r)*2048 + kt*64 + cc);
    }
  };
  auto writeV = [&](const bhalf8* src){
    #pragma unroll
    for (int it=0; it<4; ++it){
      int e = (tid + it*256)*8;
      int r = e>>6, cc = e&63;
      *(bhalf8*)&vss[r*64 + QSW(r, cc>>3)] = src[it];
    }
  };

  const int qrow = wr*16 + l15;
  const int srow = tid >> 3, seg = tid & 7;

  const int nkt = (q0 + 31)/64 + 1;
  for (int kt = 0; kt < nkt; ++kt){
    // ---- QK^T: dbuf K chunks, ONE barrier per chunk ----
    floatx4 sacc[2] = {};
    loadK(kt, 0); writeK(0); loadK(kt, 1);
    __syncthreads();
    #pragma unroll
    for (int c = 0; c < 8; ++c){
      const int cur = c & 1;
      u16* khX = (u16*)(smem + 32768 + cur*8192);
      #pragma unroll
      for (int kk=0; kk<2; ++kk){
        bhalf8 ah = *(const bhalf8*)&qhs[qrow*512 + QSW(qrow, c*8 + kk*4 + lg)];
        bhalf8 al = qlr[c*2+kk];
        #pragma unroll
        for (int ni=0; ni<2; ++ni){
          int krow = wc*32 + ni*16 + l15;
          bhalf8 bh = *(const bhalf8*)&khX[krow*64 + QSW(krow, kk*4 + lg)];
          sacc[ni] = MFMA16(ah, bh, sacc[ni]);
          sacc[ni] = MFMA16(al, bh, sacc[ni]);
        }
      }
      if (c < 7){
        writeK(cur ^ 1);          // buffer not read this chunk; prior reads done by last barrier
        if (c < 6) loadK(kt, c+2);
      }
      __syncthreads();
    }
    // ---- masked scores -> sf (unions dead kh buffers) ----
    #pragma unroll
    for (int ni=0; ni<2; ++ni)
      #pragma unroll
      for (int i=0;i<4;i++){
        int row = wr*16 + lg*4 + i;
        int col = wc*32 + ni*16 + l15;
        sf[row*66 + col] = (kt*64 + col <= q0 + row) ? sacc[ni][i] : -INFINITY;
      }
    __syncthreads();
    bhalf8 va[4];
    loadV(kt, 0, va);
    {
      float pv8[8];
      float tmax = -INFINITY;
      #pragma unroll
      for (int jx=0;jx<8;jx++){ pv8[jx] = sf[srow*66 + seg*8 + jx]; tmax = fmaxf(tmax, pv8[jx]); }
      tmax = fmaxf(tmax, __shfl_xor(tmax,1,64));
      tmax = fmaxf(tmax, __shfl_xor(tmax,2,64));
      tmax = fmaxf(tmax, __shfl_xor(tmax,4,64));
      float mo = mstat[srow];
      float mn = fmaxf(mo, tmax);
      float ss = 0.0f;
      bhalf8 h8;
      #pragma unroll
      for (int jx=0;jx<8;jx++){
        float p = __expf(pv8[jx] - mn);
        ss += p;
        h8[jx] = (short)f2bf(p);
      }
      ss += __shfl_xor(ss,1,64);
      ss += __shfl_xor(ss,2,64);
      ss += __shfl_xor(ss,4,64);
      int o = srow*64 + QSW(srow, seg);
      *(bhalf8*)&phs[o] = h8;
      if (seg == 0){
        float sc = __expf(mo - mn);
        lstat[srow] = lstat[srow]*sc + ss;
        mstat[srow] = mn;
        osc[srow] = sc;
      }
    }
    __syncthreads();
    #pragma unroll
    for (int mi=0;mi<2;mi++)
      #pragma unroll
      for (int i=0;i<4;i++){
        float s = osc[mi*16 + lg*4 + i];
        #pragma unroll
        for (int vc=0; vc<4; ++vc)
          #pragma unroll
          for (int ni=0;ni<2;ni++)
            O[vc][mi][ni][i] *= s;
      }
    writeV(va);
    __syncthreads();
    for (int vc = 0; vc < 4; ++vc){
      bhalf8 vb_[4];
      if (vc < 3) loadV(kt, vc+1, vb_);
      #pragma unroll
      for (int kk=0; kk<2; ++kk){
        int gp = kk*4 + lg;
        bhalf8 pah0 = *(const bhalf8*)&phs[l15*64 + QSW(l15, gp)];
        bhalf8 pah1 = *(const bhalf8*)&phs[(16+l15)*64 + QSW(16+l15, gp)];
        #pragma unroll
        for (int ni=0; ni<2; ++ni){
          int vrow = wid*32 + ni*16 + l15;
          bhalf8 bv_ = *(const bhalf8*)&vss[vrow*64 + QSW(vrow, gp)];
          O[vc][0][ni] = MFMA16(pah0, bv_, O[vc][0][ni]);
          O[vc][1][ni] = MFMA16(pah1, bv_, O[vc][1][ni]);
        }
      }
      __syncthreads();
      if (vc < 3){
        writeV(vb_);
        __syncthreads();
      }
    }
  }

  #pragma unroll
  for (int vc=0; vc<4; ++vc)
    #pragma unroll
    for (int mi=0;mi<2;mi++)
      #pragma unroll
      for (int i=0;i<4;i++){
        int r = mi*16 + lg*4 + i;
        float inv = 1.0f / lstat[r];
        #pragma unroll
        for (int ni=0;ni<2;ni++){
          int v = vc*128 + wid*32 + ni*16 + l15;
          Out[((size_t)b*2048 + q0 + r)*512 + v] = O[vc][mi][ni][i] * inv;
        }
      }
}

extern "C" void kernel_launch(void* const* d_in, const int* in_sizes, int n_in,
                              void* d_out, int out_size, void* d_ws, size_t ws_size,
                              hipStream_t stream)
{
  const float* x   = (const float*)d_in[0];
  const float* Wq  = (const float*)d_in[1];
  const float* bq  = (const float*)d_in[2];
  const float* Wk  = (const float*)d_in[3];
  const float* bk  = (const float*)d_in[4];
  const float* Wv  = (const float*)d_in[5];
  const float* bv  = (const float*)d_in[6];
  const float* alphaq = (const float*)d_in[7];
  const float* alphav = (const float*)d_in[8];
  const float* tokq = (const float*)d_in[9];
  const float* tokv = (const float*)d_in[10];
  float* out = (float*)d_out;
  char* ws = (char*)d_ws;

  float* Qf  = (float*)(ws + 0);                 // 32 MB (gVf overlays; Khb after transpose)
  float* gVf = Qf;
  u16* Khb   = (u16*)(ws + 0);                   // 16.8 MB, written after transpose_v
  float* Kf  = (float*)(ws + 33554432);          // 32 MB
  u16* Vb    = (u16*)(ws + 67108864);            // 16 MB
  u16* ttq   = (u16*)(ws + 83886080);            // 16 MB (Ksh pre-tanh2; gVT after gating)
  u16* gVT   = ttq;
  u16* Ksh   = (u16*)(ws + 83886080);
  u16* ttv   = (u16*)(ws + 100663296);           // 16 MB (Ksl pre-tanh2)
  u16* Ksl   = (u16*)(ws + 100663296);
  u16* xl    = (u16*)(ws + 83886080);            // 32 MB, dead after gemm_qkv
  u16* gQh   = (u16*)(ws + 117440512);           // 16 MB (Qsh pre-gating)
  u16* Qsh   = (u16*)(ws + 117440512);
  u16* gQl   = (u16*)(ws + 134217728);           // 16 MB (Qsl pre-gating)
  u16* Qsl   = (u16*)(ws + 134217728);
  u16* xh    = (u16*)(ws + 117440512);           // 32 MB, dead after gemm_qkv
  u16* tq_b  = (u16*)(ws + 150994944);           // 0.5 MB
  u16* tv_b  = (u16*)(ws + 151519232);           // 0.5 MB
  int* ids   = (int*)(ws + 152043520);           // 64 KB
  float* ksum = (float*)(ws + 152109056);        // 16 KB
  float4* part = (float4*)(ws + 152125440);      // 8 MB [16384][32] (Whh/Whl first)
  u16* Whh   = (u16*)(ws + 152125440);           // 3 MB, dead after gemm_qkv
  u16* Whl   = (u16*)(ws + 155271168);           // 3 MB
  int* list1 = (int*)(ws + 160514048);           // 64 KB
  int* cnt   = (int*)(ws + 160579584);           // 4 B
  float* kpart = (float*)(ws + 160579840);       // 256 KB
  (void)ws_size; (void)in_sizes; (void)n_in; (void)out_size;

  init_counts<<<1,256,0,stream>>>(cnt);
  cvt_f32_bf16<<<256,256,0,stream>>>(tokq, tq_b, 262144);
  cvt_f32_bf16<<<256,256,0,stream>>>(tokv, tv_b, 262144);

  // pre-split x and W into hi/lo bf16
  cvt_split<<<16384,256,0,stream>>>(x,  xh, xl, 16777216);
  cvt_split<<<512,256,0,stream>>>(Wq, Whh,            Whl,            524288);
  cvt_split<<<512,256,0,stream>>>(Wk, Whh + 524288,   Whl + 524288,   524288);
  cvt_split<<<512,256,0,stream>>>(Wv, Whh + 1048576,  Whl + 1048576,  524288);

  // QKV projection with register-prefetch pipeline (split QK blocks, then V blocks)
  gemm_qkvT<1><<<dim3(8,128),256,0,stream>>>(xh, xl, Whh, Whl, bq, bk, bv, Qf, Kf, Vb);
  gemm_qkvT<0><<<dim3(4,128),256,0,stream>>>(xh, xl, Whh, Whl, bq, bk, bv, Qf, Kf, Vb);

  // pre-split Q and K for argmax (xh/xl regions are dead post-qkv)
  cvt_split<<<8192,256,0,stream>>>(Qf, Qsh, Qsl, 8388608);
  cvt_split<<<8192,256,0,stream>>>(Kf, Ksh, Ksl, 8388608);

  // argmax screen FIRST (before tanh2 overwrites Ksh/Ksl region)
  gemm_argmax<<<dim3(16,16,8),256,0,stream>>>(Qsh, Qsl, Ksh, Ksl, part);

  // token temps: both paths in ONE launch (overwrites Ksh/Ksl — argmax done)
  gemm_tanh2<<<dim3(4,128,2),256,0,stream>>>(Qf, Vb, tq_b, tv_b, ttq, ttv);

  // argmax resolution: flag near-ties -> exact f64 fix
  argmax_reduce<<<64,256,0,stream>>>(part, ids, list1, cnt);
  argmax_fix<<<64,256,0,stream>>>(Qf, Kf, list1, cnt, ids);

  // K column sums (two-phase deterministic)
  ksum_part<<<dim3(8,16),256,0,stream>>>(Kf, kpart);
  ksum_final<<<16,256,0,stream>>>(kpart, ksum);

  // gating: gQ hi/lo bf16 + f32 gated-V (overwrites Qsh/Qsl — argmax done; gVf over Qf)
  gating_kernel<<<16384,256,0,stream>>>(Qf, Kf, Vb, ttq, ttv, ids, ksum,
                                        alphaq, alphav, gQh, gQl, gVf);

  // transpose gV -> bf16 [b][v][s] (over ttq); Qf/gVf region now dead
  transpose_v<<<dim3(32,8,8),256,0,stream>>>(gVf, gVT);

  // K -> plain bf16 (over dead Qf/gVf region)
  cvt_f32_bf16<<<8192,256,0,stream>>>(Kf, Khb, 8388608);

  // MFMA causal attention: dbuf-K single-barrier QK, 2-term scores
  flash7<<<dim3(64,8),256,0,stream>>>(gQh, gQl, Khb, gVT, out);
}

// Round 23
// 825.330 us; speedup vs baseline: 1.1773x; 1.0362x over previous
//
#include <hip/hip_runtime.h>
#include <hip/hip_bf16.h>
#include <math.h>

typedef unsigned short u16;
typedef __attribute__((ext_vector_type(8))) short bhalf8;
typedef __attribute__((ext_vector_type(4))) float floatx4;

#define MFMA16(a,b,c) __builtin_amdgcn_mfma_f32_16x16x32_bf16((a),(b),(c),0,0,0)
#define QSW(r,g) ((((g) ^ ((r)&7))) << 3)

__device__ __forceinline__ float bf2f(u16 u){ return __uint_as_float(((unsigned)u)<<16); }
__device__ __forceinline__ u16 f2bf(float f){
  unsigned u = __float_as_uint(f);
  u += 0x7fffu + ((u>>16)&1u);
  return (u16)(u>>16);
}
__device__ __forceinline__ float gelu_f(float x){ return 0.5f*x*(1.0f+erff(x*0.70710678118654752f)); }
__device__ __forceinline__ float sigm(float x){ return 1.0f/(1.0f+__expf(-x)); }

__global__ __launch_bounds__(256) void init_counts(int* cnt){
  if (threadIdx.x == 0 && blockIdx.x == 0) *cnt = 0;
}

__global__ __launch_bounds__(256) void cvt_f32_bf16(const float* __restrict__ src,
                                                    u16* __restrict__ dst, int n){
  int i = (blockIdx.x*256 + threadIdx.x)*4;
  if (i >= n) return;
  const float4 v = *(const float4*)(src + i);
  ushort4 o;
  o.x = f2bf(v.x); o.y = f2bf(v.y); o.z = f2bf(v.z); o.w = f2bf(v.w);
  *(ushort4*)(dst + i) = o;
}

// ---------------- hi/lo split convert: v -> (bf16 hi, bf16 lo) ----------------
__global__ __launch_bounds__(256) void cvt_split(const float* __restrict__ src,
                                                 u16* __restrict__ dsth,
                                                 u16* __restrict__ dstl, int n){
  int i = (blockIdx.x*256 + threadIdx.x)*4;
  if (i >= n) return;
  const float4 v = *(const float4*)(src + i);
  float vv[4] = {v.x, v.y, v.z, v.w};
  ushort4 oh, ol;
  u16 h;
  h = f2bf(vv[0]); oh.x = h; ol.x = f2bf(vv[0] - bf2f(h));
  h = f2bf(vv[1]); oh.y = h; ol.y = f2bf(vv[1] - bf2f(h));
  h = f2bf(vv[2]); oh.z = h; ol.z = f2bf(vv[2] - bf2f(h));
  h = f2bf(vv[3]); oh.w = h; ol.w = f2bf(vv[3] - bf2f(h));
  *(ushort4*)(dsth + i) = oh;
  *(ushort4*)(dstl + i) = ol;
}

// ---------------- QKV projection: reg-prefetch + QSW LDS + XCD-chunked mapping ----------
// SPLIT=1: Q/K blocks (3-term split MFMA, f32 out), grid 1024 blocks.
// SPLIT=0: V blocks (1-term, bf16 out), grid 512 blocks.
template<int SPLIT>
__global__ __launch_bounds__(256) void gemm_qkvT(
    const u16* __restrict__ xh, const u16* __restrict__ xl,
    const u16* __restrict__ Whh, const u16* __restrict__ Whl,
    const float* __restrict__ bq, const float* __restrict__ bk, const float* __restrict__ bv,
    float* __restrict__ Qf, float* __restrict__ Kf, u16* __restrict__ Vb)
{
  __shared__ __align__(16) u16 Ah[128*64];
  __shared__ __align__(16) u16 Bh[128*64];
  __shared__ __align__(16) u16 Al[SPLIT?128*64:8];
  __shared__ __align__(16) u16 Bl[SPLIT?128*64:8];
  const int tid = threadIdx.x;
  const int lane = tid & 63, wid = tid >> 6;
  const int l15 = lane & 15, lg = lane >> 4;
  const int wr = wid >> 1, wc = wid & 1;
  // XCD-chunked bijective remap: each XCD owns a contiguous m-chunk, n fastest.
  int mblk, nblk;
  if (SPLIT){
    const int lin = blockIdx.x + 8*blockIdx.y;          // 1024 blocks
    const int swz = (lin & 7)*128 + (lin >> 3);
    mblk = swz >> 3;  nblk = swz & 7;
  } else {
    const int lin = blockIdx.x + 4*blockIdx.y;          // 512 blocks
    const int swz = (lin & 7)*64 + (lin >> 3);
    mblk = swz >> 2;  nblk = swz & 3;
  }
  const int m0 = mblk * 128;
  const int n0 = nblk * 128 + (SPLIT ? 0 : 1024);
  const int which = n0 >> 9;
  const int nb = n0 & 511;
  const float* bias = (which==0) ? bq : (which==1) ? bk : bv;

  floatx4 acc[4][4] = {};

  bhalf8 RAh[4], RBh[4], RAl[4], RBl[4];
  auto loadT = [&](int k0){
    #pragma unroll
    for (int it = 0; it < 4; ++it){
      int e = (tid + it*256)*8;
      int r = e >> 6, c = e & 63;
      size_t ao = (size_t)(m0+r)*1024 + k0 + c;
      size_t bo = (size_t)(n0+r)*1024 + k0 + c;
      RAh[it] = *(const bhalf8*)(xh + ao);
      RBh[it] = *(const bhalf8*)(Whh + bo);
      if (SPLIT){
        RAl[it] = *(const bhalf8*)(xl + ao);
        RBl[it] = *(const bhalf8*)(Whl + bo);
      }
    }
  };
  auto writeT = [&](){
    #pragma unroll
    for (int it = 0; it < 4; ++it){
      int e = (tid + it*256)*8;
      int r = e >> 6, c = e & 63;
      int o = r*64 + QSW(r, c>>3);
      *(bhalf8*)&Ah[o] = RAh[it];
      *(bhalf8*)&Bh[o] = RBh[it];
      if (SPLIT){
        *(bhalf8*)&Al[o] = RAl[it];
        *(bhalf8*)&Bl[o] = RBl[it];
      }
    }
  };

  loadT(0);
  writeT();
  __syncthreads();
  for (int k0 = 0; k0 < 1024; k0 += 64){
    if (k0 < 960) loadT(k0 + 64);
    #pragma unroll
    for (int kk = 0; kk < 2; ++kk){
      bhalf8 ah[4], bh8[4];
      #pragma unroll
      for (int xx=0; xx<4; xx++){
        int ra = wr*64 + xx*16 + l15;
        int rb = wc*64 + xx*16 + l15;
        ah[xx]  = *(const bhalf8*)&Ah[ra*64 + QSW(ra, kk*4 + lg)];
        bh8[xx] = *(const bhalf8*)&Bh[rb*64 + QSW(rb, kk*4 + lg)];
      }
      if (SPLIT){
        bhalf8 al[4], bl8[4];
        #pragma unroll
        for (int xx=0; xx<4; xx++){
          int ra = wr*64 + xx*16 + l15;
          int rb = wc*64 + xx*16 + l15;
          al[xx]  = *(const bhalf8*)&Al[ra*64 + QSW(ra, kk*4 + lg)];
          bl8[xx] = *(const bhalf8*)&Bl[rb*64 + QSW(rb, kk*4 + lg)];
        }
        #pragma unroll
        for (int mi=0;mi<4;mi++)
          #pragma unroll
          for (int ni=0;ni<4;ni++){
            acc[mi][ni] = MFMA16(ah[mi], bh8[ni], acc[mi][ni]);
            acc[mi][ni] = MFMA16(ah[mi], bl8[ni], acc[mi][ni]);
            acc[mi][ni] = MFMA16(al[mi], bh8[ni], acc[mi][ni]);
          }
      } else {
        #pragma unroll
        for (int mi=0;mi<4;mi++)
          #pragma unroll
          for (int ni=0;ni<4;ni++)
            acc[mi][ni] = MFMA16(ah[mi], bh8[ni], acc[mi][ni]);
      }
    }
    __syncthreads();
    if (k0 < 960){
      writeT();
      __syncthreads();
    }
  }

  #pragma unroll
  for (int mi=0;mi<4;mi++)
    #pragma unroll
    for (int ni=0;ni<4;ni++){
      int cc = nb + wc*64 + ni*16 + l15;
      float bias_v = bias[cc];
      #pragma unroll
      for (int i=0;i<4;i++){
        int row = m0 + wr*64 + mi*16 + lg*4 + i;
        float v = acc[mi][ni][i] + bias_v;
        size_t off = (size_t)row*512 + cc;
        if (which==0){ Qf[off] = v; }
        else if (which==1){ Kf[off] = v; }
        else { Vb[off] = f2bf(v); }
      }
    }
}

// ---------------- token-temp GEMM, both paths, register-prefetch pipeline ---------------
__global__ __launch_bounds__(256) void gemm_tanh2(
    const float* __restrict__ Af, const u16* __restrict__ Ab,
    const u16* __restrict__ Bq, const u16* __restrict__ Bv,
    u16* __restrict__ oq, u16* __restrict__ ov)
{
  __shared__ __align__(16) u16 As[128][72];
  __shared__ __align__(16) u16 Bs[128][72];
  const int tid = threadIdx.x;
  const int lane = tid & 63, wid = tid >> 6;
  const int l15 = lane & 15, lg = lane >> 4;
  const int wr = wid >> 1, wc = wid & 1;
  const int m0 = blockIdx.y * 128, n0 = blockIdx.x * 128;
  const int zp = blockIdx.z;
  const u16* B = zp ? Bv : Bq;
  u16* o0 = zp ? ov : oq;

  floatx4 acc[4][4] = {};

  float4 RAf[8]; bhalf8 RAb[4]; bhalf8 RB[4];
  auto loadT = [&](int k0){
    #pragma unroll
    for (int it=0; it<4; ++it){
      int e = (tid + it*256)*8;
      int r = e >> 6, c = e & 63;
      if (zp == 0){
        const float* src = Af + (size_t)(m0+r)*512 + k0 + c;
        RAf[it*2]   = *(const float4*)src;
        RAf[it*2+1] = *(const float4*)(src+4);
      } else {
        RAb[it] = *(const bhalf8*)(Ab + (size_t)(m0+r)*512 + k0 + c);
      }
      RB[it] = *(const bhalf8*)(B + (size_t)(n0+r)*512 + k0 + c);
    }
  };
  auto writeT = [&](){
    #pragma unroll
    for (int it=0; it<4; ++it){
      int e = (tid + it*256)*8;
      int r = e >> 6, c = e & 63;
      bhalf8 g;
      if (zp == 0){
        float vv[8] = {RAf[it*2].x,RAf[it*2].y,RAf[it*2].z,RAf[it*2].w,
                       RAf[it*2+1].x,RAf[it*2+1].y,RAf[it*2+1].z,RAf[it*2+1].w};
        #pragma unroll
        for (int j=0;j<8;j++) g[j] = (short)f2bf(gelu_f(vv[j]));
      } else {
        #pragma unroll
        for (int j=0;j<8;j++) g[j] = (short)f2bf(gelu_f(bf2f((u16)RAb[it][j])));
      }
      *(bhalf8*)&As[r][c] = g;
      *(bhalf8*)&Bs[r][c] = RB[it];
    }
  };

  loadT(0);
  writeT();
  __syncthreads();
  for (int k0 = 0; k0 < 512; k0 += 64){
    if (k0 < 448) loadT(k0 + 64);
    #pragma unroll
    for (int kk = 0; kk < 2; ++kk){
      bhalf8 af[4], bfr[4];
      #pragma unroll
      for (int xx=0;xx<4;xx++) af[xx]  = *(const bhalf8*)&As[wr*64 + xx*16 + l15][kk*32 + lg*8];
      #pragma unroll
      for (int xx=0;xx<4;xx++) bfr[xx] = *(const bhalf8*)&Bs[wc*64 + xx*16 + l15][kk*32 + lg*8];
      #pragma unroll
      for (int mi=0;mi<4;mi++)
        #pragma unroll
        for (int ni=0;ni<4;ni++)
          acc[mi][ni] = MFMA16(af[mi], bfr[ni], acc[mi][ni]);
    }
    __syncthreads();
    if (k0 < 448){
      writeT();
      __syncthreads();
    }
  }

  #pragma unroll
  for (int mi=0;mi<4;mi++)
    #pragma unroll
    for (int ni=0;ni<4;ni++){
      int coln = n0 + wc*64 + ni*16 + l15;
      #pragma unroll
      for (int i=0;i<4;i++){
        int row = m0 + wr*64 + mi*16 + lg*4 + i;
        o0[(size_t)row*512 + coln] = f2bf(tanhf(acc[mi][ni][i]));
      }
    }
}

// ---------------- argmax screen: 3-term split MFMA, PRE-SPLIT Q/K (pure-copy staging) ---
__global__ __launch_bounds__(256) void gemm_argmax(
    const u16* __restrict__ Qsh, const u16* __restrict__ Qsl,
    const u16* __restrict__ Ksh, const u16* __restrict__ Ksl,
    float4* __restrict__ part)
{
  __shared__ __align__(16) u16 Ah[128][40];
  __shared__ __align__(16) u16 Al[128][40];
  __shared__ __align__(16) u16 Bh[128][40];
  __shared__ __align__(16) u16 Bl[128][40];
  const int tid = threadIdx.x;
  const int lane = tid & 63, wid = tid >> 6;
  const int l15 = lane & 15, lg = lane >> 4;
  const int wr = wid >> 1, wc = wid & 1;
  const int lin = blockIdx.x + 16*blockIdx.y + 256*blockIdx.z;
  const int swz = (lin & 7)*256 + (lin >> 3);
  const int zb  = swz >> 8;
  const int rem = swz & 255;
  const int m0 = (rem >> 4) * 128;
  const int n0 = (rem & 15) * 128;
  const size_t bo = (size_t)zb * 2048 * 512;

  floatx4 acc[4][4] = {};

  bhalf8 RQh[2], RQl[2], RKh[2], RKl[2];
  auto loadT = [&](int k0){
    #pragma unroll
    for (int it = 0; it < 2; ++it){
      int e = (tid + it*256)*8;
      int r = e >> 5, c = e & 31;
      size_t qo = bo + (size_t)(m0+r)*512 + k0 + c;
      size_t ko = bo + (size_t)(n0+r)*512 + k0 + c;
      RQh[it] = *(const bhalf8*)(Qsh + qo);
      RQl[it] = *(const bhalf8*)(Qsl + qo);
      RKh[it] = *(const bhalf8*)(Ksh + ko);
      RKl[it] = *(const bhalf8*)(Ksl + ko);
    }
  };
  auto writeT = [&](){
    #pragma unroll
    for (int it = 0; it < 2; ++it){
      int e = (tid + it*256)*8;
      int r = e >> 5, c = e & 31;
      *(bhalf8*)&Ah[r][c] = RQh[it];
      *(bhalf8*)&Al[r][c] = RQl[it];
      *(bhalf8*)&Bh[r][c] = RKh[it];
      *(bhalf8*)&Bl[r][c] = RKl[it];
    }
  };

  loadT(0);
  writeT();
  __syncthreads();
  for (int k0 = 0; k0 < 512; k0 += 32){
    if (k0 < 480) loadT(k0 + 32);
    {
      bhalf8 ah[4], al[4], bh[4], bl[4];
      #pragma unroll
      for (int xx=0;xx<4;xx++){
        ah[xx] = *(const bhalf8*)&Ah[wr*64 + xx*16 + l15][lg*8];
        al[xx] = *(const bhalf8*)&Al[wr*64 + xx*16 + l15][lg*8];
        bh[xx] = *(const bhalf8*)&Bh[wc*64 + xx*16 + l15][lg*8];
        bl[xx] = *(const bhalf8*)&Bl[wc*64 + xx*16 + l15][lg*8];
      }
      #pragma unroll
      for (int mi=0;mi<4;mi++)
        #pragma unroll
        for (int ni=0;ni<4;ni++){
          acc[mi][ni] = MFMA16(ah[mi], bh[ni], acc[mi][ni]);
          acc[mi][ni] = MFMA16(ah[mi], bl[ni], acc[mi][ni]);
          acc[mi][ni] = MFMA16(al[mi], bh[ni], acc[mi][ni]);
        }
    }
    __syncthreads();
    if (k0 < 480){
      writeT();
      __syncthreads();
    }
  }

  #pragma unroll
  for (int mi=0;mi<4;mi++)
    #pragma unroll
    for (int i=0;i<4;i++){
      float v1 = -INFINITY, v2 = -INFINITY; int i1 = 0x7fffffff;
      #pragma unroll
      for (int ni=0;ni<4;ni++){
        float v = acc[mi][ni][i];
        int col = n0 + wc*64 + ni*16 + l15;
        if (v > v1 || (v == v1 && col < i1)){ v2 = v1; v1 = v; i1 = col; }
        else v2 = fmaxf(v2, v);
      }
      #pragma unroll
      for (int ms=1; ms<16; ms<<=1){
        float w1 = __shfl_xor(v1, ms, 64);
        int   j1 = __shfl_xor(i1, ms, 64);
        float w2 = __shfl_xor(v2, ms, 64);
        if (w1 > v1 || (w1 == v1 && j1 < i1)){ v2 = fmaxf(v1, w2); v1 = w1; i1 = j1; }
        else { v2 = fmaxf(v2, w1); }
      }
      if (l15 == 0){
        int row = m0 + wr*64 + mi*16 + lg*4 + i;
        size_t gm = (size_t)zb*2048 + row;
        part[gm*32 + ((n0>>7)<<1) + wc] = make_float4(v1, __int_as_float(i1), v2, 0.0f);
      }
    }
}

// ---------------- reduce top2 over 32 col-stripes; flag narrow-gap rows -----------------
__global__ __launch_bounds__(256) void argmax_reduce(const float4* __restrict__ part,
                                                     int* __restrict__ ids,
                                                     int* __restrict__ list1,
                                                     int* __restrict__ cnt){
  int r = blockIdx.x*256 + threadIdx.x;
  if (r >= 16384) return;
  float v1 = -INFINITY, v2 = -INFINITY; int i1 = 0x7fffffff;
  #pragma unroll
  for (int t=0;t<32;t++){
    float4 p = part[(size_t)r*32 + t];
    float w1 = p.x, w2 = p.z; int j1 = __float_as_int(p.y);
    if (w1 > v1 || (w1 == v1 && j1 < i1)){ v2 = fmaxf(v1, w2); v1 = w1; i1 = j1; }
    else { v2 = fmaxf(v2, w1); }
  }
  ids[r] = i1;
  if (v1 - v2 < 0.02f){
    int k = atomicAdd(cnt, 1);
    if (k < 16384) list1[k] = r;
  }
}

// ---------------- exact fix: verified f64-on-f32 argmax for flagged rows -----------------
__global__ __launch_bounds__(256) void argmax_fix(
    const float* __restrict__ Qf, const float* __restrict__ Kf,
    const int* __restrict__ list1, const int* __restrict__ cnt,
    int* __restrict__ ids)
{
  __shared__ float q[512];
  __shared__ double rbest[256];
  __shared__ int ridx[256];
  const int tid = threadIdx.x;
  const int n = *cnt;
  for (int j = blockIdx.x; j < n; j += gridDim.x){
    const int r = list1[j];
    const int b = r >> 11;
    __syncthreads();
    for (int d = tid; d < 512; d += 256) q[d] = Qf[(size_t)r*512 + d];
    __syncthreads();
    double best = -1e300; int bi = 0x7fffffff;
    for (int c = 0; c < 8; ++c){
      int key = tid + c*256;
      const float* kr = Kf + ((size_t)b*2048 + key)*512;
      double acc = 0.0;
      for (int e = 0; e < 512; ++e) acc += (double)q[e]*(double)kr[e];
      if (acc > best || (acc == best && key < bi)){ best = acc; bi = key; }
    }
    rbest[tid] = best; ridx[tid] = bi;
    __syncthreads();
    for (int st=128; st>0; st>>=1){
      if (tid < st){
        double ov = rbest[tid+st]; int oi = ridx[tid+st];
        if (ov > rbest[tid] || (ov == rbest[tid] && oi < ridx[tid])){ rbest[tid]=ov; ridx[tid]=oi; }
      }
      __syncthreads();
    }
    if (tid == 0) ids[r] = ridx[0];
    __syncthreads();
  }
}

// ---------------- K column sums: two-phase deterministic ----------------
__global__ __launch_bounds__(256) void ksum_part(const float* __restrict__ Kf,
                                                 float* __restrict__ kpart){
  const int b = blockIdx.x, chunk = blockIdx.y;
  const int tid = threadIdx.x;
  const float* base = Kf + (size_t)b*2048*512 + (size_t)chunk*128*512;
  #pragma unroll
  for (int h = 0; h < 2; ++h){
    int col = tid + h*256;
    double s = 0.0;
    for (int r = 0; r < 128; ++r) s += (double)base[(size_t)r*512 + col];
    kpart[((size_t)b*16 + chunk)*512 + col] = (float)s;
  }
}
__global__ __launch_bounds__(256) void ksum_final(const float* __restrict__ kpart,
                                                  float* __restrict__ Ksum){
  const int b = blockIdx.x >> 1;
  const int col = (blockIdx.x & 1)*256 + threadIdx.x;
  double s = 0.0;
  #pragma unroll
  for (int c = 0; c < 16; ++c) s += (double)kpart[((size_t)b*16 + c)*512 + col];
  Ksum[b*512 + col] = (float)s;
}

// ---------------- gating: emits gQ hi/lo bf16 (pre-scaled) + f32 gated-V ----------------
__global__ __launch_bounds__(256) void gating_kernel(
    const float* Qf, const float* __restrict__ Kf,
    const u16* __restrict__ V,
    const u16* __restrict__ ttq, const u16* __restrict__ ttv,
    const int* __restrict__ ids, const float* __restrict__ Ksum,
    const float* __restrict__ alphaq, const float* __restrict__ alphav,
    u16* __restrict__ gQh, u16* __restrict__ gQl, float* gVf)
{
  const int m = blockIdx.x;
  const int b = m >> 11, s = m & 2047;
  const int mid = ids[m];
  const float lp = __logf((float)(s+1));
  const float aq = alphaq[s];
  const float pv = 1.0f + sigm(alphav[s])*lp;
  const float qscale = 0.044194173824159220f;
  const size_t ro = (size_t)m*512;
  const size_t ko = ((size_t)b*2048 + mid)*512;
  const int k0 = threadIdx.x*2;

  float2 ks2 = *(const float2*)(Ksum + b*512 + k0);
  float2 q2  = *(const float2*)(Qf + ro + k0);
  float2 km2 = *(const float2*)(Kf + ko + k0);
  ushort2 v2 = *(const ushort2*)(V + ro + k0);
  ushort2 tq2 = *(const ushort2*)(ttq + ro + k0);
  ushort2 tv2 = *(const ushort2*)(ttv + ro + k0);
  ushort2 oqh, oql;
  float2 ov;
  {
    float knob = fabsf(q2.x*(ks2.x - 2048.0f*km2.x));
    float ptq = 1.0f + sigm(aq - knob)*lp;
    float oq = (ptq + bf2f(tq2.x))*q2.x*qscale;
    u16 h = f2bf(oq); oqh.x = h; oql.x = f2bf(oq - bf2f(h));
    ov.x = (pv + bf2f(tv2.x))*bf2f(v2.x);
  }
  {
    float knob = fabsf(q2.y*(ks2.y - 2048.0f*km2.y));
    float ptq = 1.0f + sigm(aq - knob)*lp;
    float oq = (ptq + bf2f(tq2.y))*q2.y*qscale;
    u16 h = f2bf(oq); oqh.y = h; oql.y = f2bf(oq - bf2f(h));
    ov.y = (pv + bf2f(tv2.y))*bf2f(v2.y);
  }
  *(ushort2*)(gQh + ro + k0) = oqh;
  *(ushort2*)(gQl + ro + k0) = oql;
  *(float2*)(gVf + ro + k0) = ov;
}

// ---------------- transpose gV: f32 [b][s][v] -> bf16 [b][v][s] ----------------
__global__ __launch_bounds__(256) void transpose_v(const float* __restrict__ src,
                                                   u16* __restrict__ dst){
  __shared__ __align__(16) u16 t[64][72];
  const int b = blockIdx.z;
  const int s0 = blockIdx.x*64, v0 = blockIdx.y*64;
  const float* S = src + (size_t)b*2048*512;
  u16* D = dst + (size_t)b*512*2048;
  const int tid = threadIdx.x;
  #pragma unroll
  for (int it=0; it<2; ++it){
    int e = (tid + it*256)*8;
    int r = e>>6, c = e&63;
    const float* p = S + (size_t)(s0+r)*512 + v0 + c;
    float4 u0 = *(const float4*)p;
    float4 u1 = *(const float4*)(p+4);
    float vv[8] = {u0.x,u0.y,u0.z,u0.w,u1.x,u1.y,u1.z,u1.w};
    bhalf8 o;
    #pragma unroll
    for (int j=0;j<8;j++) o[j] = (short)f2bf(vv[j]);
    *(bhalf8*)&t[r][c] = o;
  }
  __syncthreads();
  #pragma unroll
  for (int it=0; it<2; ++it){
    int e = (tid + it*256)*8;
    int r = e>>6, c = e&63;
    bhalf8 o;
    #pragma unroll
    for (int j=0;j<8;j++) o[j] = (short)t[c+j][r];
    *(bhalf8*)(D + (size_t)(v0+r)*2048 + s0 + c) = o;
  }
}

// ---------------- flash7: dbuf-K single-barrier QK, 2-term scores, P-hi PV --------------
__global__ __launch_bounds__(256, 2) void flash7(
    const u16* __restrict__ gQh, const u16* __restrict__ gQl,
    const u16* __restrict__ Khb,
    const u16* __restrict__ gVT, float* __restrict__ Out)
{
  const int bx = blockIdx.x;
  const int by = blockIdx.y;
  const int b  = by;
  const int hh = (bx & 1) ? (63 - (bx >> 1)) : (bx >> 1);
  const int qt = (by < 4) ? hh : (63 - hh);
  const int q0 = qt * 32;
  const int tid = threadIdx.x, lane = tid & 63, wid = tid >> 6;
  const int l15 = lane & 15, lg = lane >> 4;
  const int wr = wid >> 1, wc = wid & 1;

  __shared__ __align__(16) char smem[69888];
  u16*   qhs = (u16*)smem;                 // 32768
  float* sf  = (float*)(smem + 32768);
  u16*   vss = (u16*)(smem + 49152);       // 16384
  u16*   phs = (u16*)(smem + 65536);       // 4096
  float* mstat = (float*)(smem + 69632);
  float* lstat = mstat + 32;
  float* osc   = mstat + 64;

  const u16* Qhb = gQh + ((size_t)b*2048 + q0)*512;
  const u16* Kbb = Khb + (size_t)b*2048*512;
  const u16* Vtb = gVT + (size_t)b*512*2048;

  #pragma unroll
  for (int it=0; it<8; ++it){
    int e = (tid + it*256)*8;
    int r = e >> 9, c = e & 511;
    bhalf8 hv = *(const bhalf8*)(Qhb + (size_t)r*512 + c);
    *(bhalf8*)&qhs[r*512 + QSW(r, c>>3)] = hv;
  }
  bhalf8 qlr[16];
  {
    const u16* Qlb = gQl + ((size_t)b*2048 + q0 + wr*16 + l15)*512;
    #pragma unroll
    for (int c=0;c<8;c++)
      #pragma unroll
      for (int kk=0;kk<2;kk++)
        qlr[c*2+kk] = *(const bhalf8*)(Qlb + c*64 + kk*32 + lg*8);
  }
  if (tid < 32){ mstat[tid] = -INFINITY; lstat[tid] = 0.0f; }

  floatx4 O[4][2][2] = {};
  __syncthreads();

  bhalf8 RK[2];
  auto loadK = [&](int kt, int c){
    #pragma unroll
    for (int it=0; it<2; ++it){
      int e = (tid + it*256)*8;
      int r = e>>6, cc = e&63;
      RK[it] = *(const bhalf8*)(Kbb + (size_t)(kt*64+r)*512 + c*64 + cc);
    }
  };
  auto writeK = [&](int buf){
    u16* khX = (u16*)(smem + 32768 + buf*8192);
    #pragma unroll
    for (int it=0; it<2; ++it){
      int e = (tid + it*256)*8;
      int r = e>>6, cc = e&63;
      *(bhalf8*)&khX[r*64 + QSW(r, cc>>3)] = RK[it];
    }
  };
  auto loadV = [&](int kt, int vc, bhalf8* dst){
    #pragma unroll
    for (int it=0; it<4; ++it){
      int e = (tid + it*256)*8;
      int r = e>>6, cc = e&63;
      dst[it] = *(const bhalf8*)(Vtb + (size_t)(vc*128+r)*2048 + kt*64 + cc);
    }
  };
  auto writeV = [&](const bhalf8* src){
    #pragma unroll
    for (int it=0; it<4; ++it){
      int e = (tid + it*256)*8;
      int r = e>>6, cc = e&63;
      *(bhalf8*)&vss[r*64 + QSW(r, cc>>3)] = src[it];
    }
  };

  const int qrow = wr*16 + l15;
  const int srow = tid >> 3, seg = tid & 7;

  const int nkt = (q0 + 31)/64 + 1;
  for (int kt = 0; kt < nkt; ++kt){
    floatx4 sacc[2] = {};
    loadK(kt, 0); writeK(0); loadK(kt, 1);
    __syncthreads();
    #pragma unroll
    for (int c = 0; c < 8; ++c){
      const int cur = c & 1;
      u16* khX = (u16*)(smem + 32768 + cur*8192);
      #pragma unroll
      for (int kk=0; kk<2; ++kk){
        bhalf8 ah = *(const bhalf8*)&qhs[qrow*512 + QSW(qrow, c*8 + kk*4 + lg)];
        bhalf8 al = qlr[c*2+kk];
        #pragma unroll
        for (int ni=0; ni<2; ++ni){
          int krow = wc*32 + ni*16 + l15;
          bhalf8 bh = *(const bhalf8*)&khX[krow*64 + QSW(krow, kk*4 + lg)];
          sacc[ni] = MFMA16(ah, bh, sacc[ni]);
          sacc[ni] = MFMA16(al, bh, sacc[ni]);
        }
      }
      if (c < 7){
        writeK(cur ^ 1);
        if (c < 6) loadK(kt, c+2);
      }
      __syncthreads();
    }
    #pragma unroll
    for (int ni=0; ni<2; ++ni)
      #pragma unroll
      for (int i=0;i<4;i++){
        int row = wr*16 + lg*4 + i;
        int col = wc*32 + ni*16 + l15;
        sf[row*66 + col] = (kt*64 + col <= q0 + row) ? sacc[ni][i] : -INFINITY;
      }
    __syncthreads();
    bhalf8 va[4];
    loadV(kt, 0, va);
    {
      float pv8[8];
      float tmax = -INFINITY;
      #pragma unroll
      for (int jx=0;jx<8;jx++){ pv8[jx] = sf[srow*66 + seg*8 + jx]; tmax = fmaxf(tmax, pv8[jx]); }
      tmax = fmaxf(tmax, __shfl_xor(tmax,1,64));
      tmax = fmaxf(tmax, __shfl_xor(tmax,2,64));
      tmax = fmaxf(tmax, __shfl_xor(tmax,4,64));
      float mo = mstat[srow];
      float mn = fmaxf(mo, tmax);
      float ss = 0.0f;
      bhalf8 h8;
      #pragma unroll
      for (int jx=0;jx<8;jx++){
        float p = __expf(pv8[jx] - mn);
        ss += p;
        h8[jx] = (short)f2bf(p);
      }
      ss += __shfl_xor(ss,1,64);
      ss += __shfl_xor(ss,2,64);
      ss += __shfl_xor(ss,4,64);
      int o = srow*64 + QSW(srow, seg);
      *(bhalf8*)&phs[o] = h8;
      if (seg == 0){
        float sc = __expf(mo - mn);
        lstat[srow] = lstat[srow]*sc + ss;
        mstat[srow] = mn;
        osc[srow] = sc;
      }
    }
    __syncthreads();
    #pragma unroll
    for (int mi=0;mi<2;mi++)
      #pragma unroll
      for (int i=0;i<4;i++){
        float s = osc[mi*16 + lg*4 + i];
        #pragma unroll
        for (int vc=0; vc<4; ++vc)
          #pragma unroll
          for (int ni=0;ni<2;ni++)
            O[vc][mi][ni][i] *= s;
      }
    writeV(va);
    __syncthreads();
    for (int vc = 0; vc < 4; ++vc){
      bhalf8 vb_[4];
      if (vc < 3) loadV(kt, vc+1, vb_);
      #pragma unroll
      for (int kk=0; kk<2; ++kk){
        int gp = kk*4 + lg;
        bhalf8 pah0 = *(const bhalf8*)&phs[l15*64 + QSW(l15, gp)];
        bhalf8 pah1 = *(const bhalf8*)&phs[(16+l15)*64 + QSW(16+l15, gp)];
        #pragma unroll
        for (int ni=0; ni<2; ++ni){
          int vrow = wid*32 + ni*16 + l15;
          bhalf8 bv_ = *(const bhalf8*)&vss[vrow*64 + QSW(vrow, gp)];
          O[vc][0][ni] = MFMA16(pah0, bv_, O[vc][0][ni]);
          O[vc][1][ni] = MFMA16(pah1, bv_, O[vc][1][ni]);
        }
      }
      __syncthreads();
      if (vc < 3){
        writeV(vb_);
        __syncthreads();
      }
    }
  }

  #pragma unroll
  for (int vc=0; vc<4; ++vc)
    #pragma unroll
    for (int mi=0;mi<2;mi++)
      #pragma unroll
      for (int i=0;i<4;i++){
        int r = mi*16 + lg*4 + i;
        float inv = 1.0f / lstat[r];
        #pragma unroll
        for (int ni=0;ni<2;ni++){
          int v = vc*128 + wid*32 + ni*16 + l15;
          Out[((size_t)b*2048 + q0 + r)*512 + v] = O[vc][mi][ni][i] * inv;
        }
      }
}

extern "C" void kernel_launch(void* const* d_in, const int* in_sizes, int n_in,
                              void* d_out, int out_size, void* d_ws, size_t ws_size,
                              hipStream_t stream)
{
  const float* x   = (const float*)d_in[0];
  const float* Wq  = (const float*)d_in[1];
  const float* bq  = (const float*)d_in[2];
  const float* Wk  = (const float*)d_in[3];
  const float* bk  = (const float*)d_in[4];
  const float* Wv  = (const float*)d_in[5];
  const float* bv  = (const float*)d_in[6];
  const float* alphaq = (const float*)d_in[7];
  const float* alphav = (const float*)d_in[8];
  const float* tokq = (const float*)d_in[9];
  const float* tokv = (const float*)d_in[10];
  float* out = (float*)d_out;
  char* ws = (char*)d_ws;

  float* Qf  = (float*)(ws + 0);                 // 32 MB (gVf overlays; Khb after transpose)
  float* gVf = Qf;
  u16* Khb   = (u16*)(ws + 0);                   // 16.8 MB, written after transpose_v
  float* Kf  = (float*)(ws + 33554432);          // 32 MB
  u16* Vb    = (u16*)(ws + 67108864);            // 16 MB
  u16* ttq   = (u16*)(ws + 83886080);            // 16 MB (Ksh pre-tanh2; gVT after gating)
  u16* gVT   = ttq;
  u16* Ksh   = (u16*)(ws + 83886080);
  u16* ttv   = (u16*)(ws + 100663296);           // 16 MB (Ksl pre-tanh2)
  u16* Ksl   = (u16*)(ws + 100663296);
  u16* xl    = (u16*)(ws + 83886080);            // 32 MB, dead after gemm_qkv
  u16* gQh   = (u16*)(ws + 117440512);           // 16 MB (Qsh pre-gating)
  u16* Qsh   = (u16*)(ws + 117440512);
  u16* gQl   = (u16*)(ws + 134217728);           // 16 MB (Qsl pre-gating)
  u16* Qsl   = (u16*)(ws + 134217728);
  u16* xh    = (u16*)(ws + 117440512);           // 32 MB, dead after gemm_qkv
  u16* tq_b  = (u16*)(ws + 150994944);           // 0.5 MB
  u16* tv_b  = (u16*)(ws + 151519232);           // 0.5 MB
  int* ids   = (int*)(ws + 152043520);           // 64 KB
  float* ksum = (float*)(ws + 152109056);        // 16 KB
  float4* part = (float4*)(ws + 152125440);      // 8 MB [16384][32] (Whh/Whl first)
  u16* Whh   = (u16*)(ws + 152125440);           // 3 MB, dead after gemm_qkv
  u16* Whl   = (u16*)(ws + 155271168);           // 3 MB
  int* list1 = (int*)(ws + 160514048);           // 64 KB
  int* cnt   = (int*)(ws + 160579584);           // 4 B
  float* kpart = (float*)(ws + 160579840);       // 256 KB
  (void)ws_size; (void)in_sizes; (void)n_in; (void)out_size;

  init_counts<<<1,256,0,stream>>>(cnt);
  cvt_f32_bf16<<<256,256,0,stream>>>(tokq, tq_b, 262144);
  cvt_f32_bf16<<<256,256,0,stream>>>(tokv, tv_b, 262144);

  // pre-split x and W into hi/lo bf16
  cvt_split<<<16384,256,0,stream>>>(x,  xh, xl, 16777216);
  cvt_split<<<512,256,0,stream>>>(Wq, Whh,            Whl,            524288);
  cvt_split<<<512,256,0,stream>>>(Wk, Whh + 524288,   Whl + 524288,   524288);
  cvt_split<<<512,256,0,stream>>>(Wv, Whh + 1048576,  Whl + 1048576,  524288);

  // QKV projection: reg-prefetch + QSW LDS + XCD-chunked mapping
  gemm_qkvT<1><<<dim3(8,128),256,0,stream>>>(xh, xl, Whh, Whl, bq, bk, bv, Qf, Kf, Vb);
  gemm_qkvT<0><<<dim3(4,128),256,0,stream>>>(xh, xl, Whh, Whl, bq, bk, bv, Qf, Kf, Vb);

  // pre-split Q and K for argmax (xh/xl regions are dead post-qkv)
  cvt_split<<<8192,256,0,stream>>>(Qf, Qsh, Qsl, 8388608);
  cvt_split<<<8192,256,0,stream>>>(Kf, Ksh, Ksl, 8388608);

  // argmax screen FIRST (before tanh2 overwrites Ksh/Ksl region)
  gemm_argmax<<<dim3(16,16,8),256,0,stream>>>(Qsh, Qsl, Ksh, Ksl, part);

  // token temps: both paths in ONE launch (overwrites Ksh/Ksl — argmax done)
  gemm_tanh2<<<dim3(4,128,2),256,0,stream>>>(Qf, Vb, tq_b, tv_b, ttq, ttv);

  // argmax resolution: flag near-ties -> exact f64 fix
  argmax_reduce<<<64,256,0,stream>>>(part, ids, list1, cnt);
  argmax_fix<<<64,256,0,stream>>>(Qf, Kf, list1, cnt, ids);

  // K column sums (two-phase deterministic)
  ksum_part<<<dim3(8,16),256,0,stream>>>(Kf, kpart);
  ksum_final<<<16,256,0,stream>>>(kpart, ksum);

  // gating: gQ hi/lo bf16 + f32 gated-V (overwrites Qsh/Qsl — argmax done; gVf over Qf)
  gating_kernel<<<16384,256,0,stream>>>(Qf, Kf, Vb, ttq, ttv, ids, ksum,
                                        alphaq, alphav, gQh, gQl, gVf);

  // transpose gV -> bf16 [b][v][s] (over ttq); Qf/gVf region now dead
  transpose_v<<<dim3(32,8,8),256,0,stream>>>(gVf, gVT);

  // K -> plain bf16 (over dead Qf/gVf region)
  cvt_f32_bf16<<<8192,256,0,stream>>>(Kf, Khb, 8388608);

  // MFMA causal attention: dbuf-K single-barrier QK, 2-term scores
  flash7<<<dim3(64,8),256,0,stream>>>(gQh, gQl, Khb, gVT, out);
}